// Round 1
// baseline (1340.753 us; speedup 1.0000x reference)
//
#include <hip/hip_runtime.h>
#include <math.h>

#define NEG_SLOPE 0.2f

// ---- ordered-uint encoding for float atomicMax ----
__device__ __forceinline__ unsigned enc_f(float f) {
  unsigned u = __float_as_uint(f);
  return (u & 0x80000000u) ? ~u : (u | 0x80000000u);
}
__device__ __forceinline__ float dec_f(unsigned k) {
  unsigned u = (k & 0x80000000u) ? (k ^ 0x80000000u) : ~k;
  return __uint_as_float(u);
}

// ---- tiled fp32 GEMM: C[M,Ncol] = A[M,K] @ B[K,Ncol]; 64x64 tile, K-tile 16 ----
__global__ __launch_bounds__(256) void gemm_tiled(const float* __restrict__ A,
    const float* __restrict__ B, float* __restrict__ C, int M, int K, int Ncol) {
  __shared__ float As[16][65];
  __shared__ float Bs[16][65];
  const int tid = threadIdx.x;
  const int tx = tid & 15, ty = tid >> 4;
  const int row0 = blockIdx.y * 64, col0 = blockIdx.x * 64;
  float acc[4][4] = {};
  for (int k0 = 0; k0 < K; k0 += 16) {
#pragma unroll
    for (int i = 0; i < 4; i++) {
      int idx = tid + i * 256;            // 0..1023
      int m = idx >> 4, kk = idx & 15;    // A tile: 64 rows x 16 k
      int gr = row0 + m;
      As[kk][m] = (gr < M) ? A[(size_t)gr * K + k0 + kk] : 0.f;
      int kb = idx >> 6, nb = idx & 63;   // B tile: 16 k x 64 cols
      Bs[kb][nb] = B[(size_t)(k0 + kb) * Ncol + col0 + nb];
    }
    __syncthreads();
#pragma unroll
    for (int kk = 0; kk < 16; kk++) {
      float a[4], b[4];
#pragma unroll
      for (int i = 0; i < 4; i++) a[i] = As[kk][ty * 4 + i];
#pragma unroll
      for (int j = 0; j < 4; j++) b[j] = Bs[kk][tx * 4 + j];
#pragma unroll
      for (int i = 0; i < 4; i++)
#pragma unroll
        for (int j = 0; j < 4; j++)
          acc[i][j] = fmaf(a[i], b[j], acc[i][j]);
    }
    __syncthreads();
  }
#pragma unroll
  for (int i = 0; i < 4; i++) {
    int gr = row0 + ty * 4 + i;
    if (gr < M) {
#pragma unroll
      for (int j = 0; j < 4; j++)
        C[(size_t)gr * Ncol + col0 + tx * 4 + j] = acc[i][j];
    }
  }
}

// ---- per-(node,head) attention coefficients; C=64, one wave per (n,h) ----
template <int H>
__global__ __launch_bounds__(256) void alpha_kernel(const float* __restrict__ h,
    const float* __restrict__ att_s, const float* __restrict__ att_d,
    float* __restrict__ as_, float* __restrict__ ad_, int Nn) {
  int wave = (blockIdx.x * blockDim.x + threadIdx.x) >> 6;
  int lane = threadIdx.x & 63;
  if (wave >= Nn * H) return;
  int n = wave / H, hh = wave % H;
  float hv = h[(size_t)n * (H * 64) + hh * 64 + lane];
  float vs = hv * att_s[hh * 64 + lane];
  float vd = hv * att_d[hh * 64 + lane];
  for (int off = 32; off; off >>= 1) {
    vs += __shfl_down(vs, off);
    vd += __shfl_down(vd, off);
  }
  if (lane == 0) { as_[wave] = vs; ad_[wave] = vd; }
}

// ---- edge pass 1: segment max over dst (ordered-uint atomicMax) ----
template <int H>
__global__ __launch_bounds__(256) void edge_max_kernel(const int* __restrict__ ei,
    const float* __restrict__ as_, const float* __restrict__ ad_,
    unsigned* __restrict__ emaxk, int E0, int Etot) {
  int idx = blockIdx.x * blockDim.x + threadIdx.x;
  if (idx >= Etot * H) return;
  int e = idx / H, hh = idx % H;
  int src, dst;
  if (e < E0) { src = ei[e]; dst = ei[E0 + e]; } else { src = e - E0; dst = src; }
  float a = as_[src * H + hh] + ad_[dst * H + hh];
  float v = a >= 0.f ? a : NEG_SLOPE * a;
  atomicMax(&emaxk[dst * H + hh], enc_f(v));
}

__global__ __launch_bounds__(256) void decode_kernel(const unsigned* __restrict__ k,
    float* __restrict__ f, int n) {
  int i = blockIdx.x * blockDim.x + threadIdx.x;
  if (i < n) f[i] = dec_f(k[i]);
}

// ---- edge pass 2: segment sum of exp(e - max) ----
template <int H>
__global__ __launch_bounds__(256) void edge_sum_kernel(const int* __restrict__ ei,
    const float* __restrict__ as_, const float* __restrict__ ad_,
    const float* __restrict__ emaxf, float* __restrict__ esum, int E0, int Etot) {
  int idx = blockIdx.x * blockDim.x + threadIdx.x;
  if (idx >= Etot * H) return;
  int e = idx / H, hh = idx % H;
  int src, dst;
  if (e < E0) { src = ei[e]; dst = ei[E0 + e]; } else { src = e - E0; dst = src; }
  float a = as_[src * H + hh] + ad_[dst * H + hh];
  float v = a >= 0.f ? a : NEG_SLOPE * a;
  atomicAdd(&esum[dst * H + hh], __expf(v - emaxf[dst * H + hh]));
}

// ---- edge pass 3: weighted scatter aggregate; one wave per edge, C=64 ----
template <int H>
__global__ __launch_bounds__(256) void edge_aggr_kernel(const int* __restrict__ ei,
    const float* __restrict__ as_, const float* __restrict__ ad_,
    const float* __restrict__ emaxf, const float* __restrict__ esum,
    const float* __restrict__ h, float* __restrict__ out, int E0, int Etot) {
  int wave = (blockIdx.x * blockDim.x + threadIdx.x) >> 6;
  int lane = threadIdx.x & 63;
  if (wave >= Etot) return;
  int src, dst;
  if (wave < E0) { src = ei[wave]; dst = ei[E0 + wave]; } else { src = wave - E0; dst = src; }
#pragma unroll
  for (int hh = 0; hh < H; hh++) {
    float a = as_[src * H + hh] + ad_[dst * H + hh];
    float v = a >= 0.f ? a : NEG_SLOPE * a;
    float w = __expf(v - emaxf[dst * H + hh]) / (esum[dst * H + hh] + 1e-16f);
    atomicAdd(&out[(size_t)dst * (H * 64) + hh * 64 + lane],
              h[(size_t)src * (H * 64) + hh * 64 + lane] * w);
  }
}

// ---- bias + relu in place (cols must be power of 2) ----
__global__ __launch_bounds__(256) void bias_relu_kernel(float* __restrict__ x,
    const float* __restrict__ b, size_t total, int colmask) {
  size_t i = blockIdx.x * (size_t)blockDim.x + threadIdx.x;
  if (i < total) {
    float v = x[i] + b[i & colmask];
    x[i] = v > 0.f ? v : 0.f;
  }
}

// ---- fused bias+relu+column-sum pooling for layer-2 output (C=64) ----
__global__ __launch_bounds__(256) void pool_kernel(const float* __restrict__ out2,
    const float* __restrict__ b2, float* __restrict__ pooled, int Nn) {
  int c = threadIdx.x & 63;
  int sub = threadIdx.x >> 6;  // 0..3
  float acc = 0.f;
  for (int n = blockIdx.x * 4 + sub; n < Nn; n += gridDim.x * 4) {
    float v = out2[(size_t)n * 64 + c] + b2[c];
    acc += v > 0.f ? v : 0.f;
  }
  __shared__ float s[256];
  s[threadIdx.x] = acc;
  __syncthreads();
  if (threadIdx.x < 64) {
    atomicAdd(&pooled[threadIdx.x],
              s[threadIdx.x] + s[threadIdx.x + 64] + s[threadIdx.x + 128] + s[threadIdx.x + 192]);
  }
}

// ---- final fc + log_softmax; single block of 64 threads ----
__global__ void head_kernel(const float* __restrict__ pooled, const float* __restrict__ fc_w,
    const float* __restrict__ fc_b, float* __restrict__ out, float invN) {
  __shared__ float p[64];
  __shared__ float lg[40];
  __shared__ float lse;
  int t = threadIdx.x;
  p[t] = pooled[t] * invN;
  __syncthreads();
  if (t < 40) {
    float s = fc_b[t];
    for (int c = 0; c < 64; c++) s = fmaf(p[c], fc_w[c * 40 + t], s);
    lg[t] = s;
  }
  __syncthreads();
  if (t == 0) {
    float m = -1e30f;
    for (int j = 0; j < 40; j++) m = fmaxf(m, lg[j]);
    float sum = 0.f;
    for (int j = 0; j < 40; j++) sum += expf(lg[j] - m);
    lse = m + logf(sum);
  }
  __syncthreads();
  if (t < 40) out[t] = lg[t] - lse;
}

extern "C" void kernel_launch(void* const* d_in, const int* in_sizes, int n_in,
                              void* d_out, int out_size, void* d_ws, size_t ws_size,
                              hipStream_t stream) {
  const float* x        = (const float*)d_in[0];
  const int*   ei       = (const int*)d_in[1];
  const float* W1       = (const float*)d_in[2];
  const float* att_src1 = (const float*)d_in[3];
  const float* att_dst1 = (const float*)d_in[4];
  const float* b1       = (const float*)d_in[5];
  const float* W2       = (const float*)d_in[6];
  const float* att_src2 = (const float*)d_in[7];
  const float* att_dst2 = (const float*)d_in[8];
  const float* b2       = (const float*)d_in[9];
  const float* fc_w     = (const float*)d_in[10];
  const float* fc_b     = (const float*)d_in[11];
  float* out = (float*)d_out;

  const int N    = in_sizes[0] / 128;  // 50000
  const int E0   = in_sizes[1] / 2;    // 800000
  const int Etot = E0 + N;             // + self loops

  float* ws = (float*)d_ws;
  size_t o = 0;
  float* h1   = ws + o; o += (size_t)N * 256;
  float* out1 = ws + o; o += (size_t)N * 256;
  float* h2   = h1;                    // reuse: h1 dead after layer-1 aggregation
  float* out2 = h1 + (size_t)N * 64;   // fits inside h1 region
  float* as1 = ws + o; o += (size_t)N * 4;
  float* ad1 = ws + o; o += (size_t)N * 4;
  unsigned* emax1k = (unsigned*)(ws + o); o += (size_t)N * 4;
  float* emax1f = ws + o; o += (size_t)N * 4;
  float* esum1  = ws + o; o += (size_t)N * 4;
  float* as2 = ws + o; o += N;
  float* ad2 = ws + o; o += N;
  unsigned* emax2k = (unsigned*)(ws + o); o += N;
  float* emax2f = ws + o; o += N;
  float* esum2  = ws + o; o += N;
  float* pooled = ws + o; o += 64;

  dim3 blk(256);

  // ---- layer 1 ----
  hipMemsetAsync(out1, 0, (size_t)N * 256 * 4, stream);
  hipMemsetAsync(emax1k, 0, (size_t)N * 4 * 4, stream);
  hipMemsetAsync(esum1, 0, (size_t)N * 4 * 4, stream);
  hipMemsetAsync(pooled, 0, 64 * 4, stream);

  gemm_tiled<<<dim3(256 / 64, (N + 63) / 64), blk, 0, stream>>>(x, W1, h1, N, 128, 256);
  alpha_kernel<4><<<N, blk, 0, stream>>>(h1, att_src1, att_dst1, as1, ad1, N);
  edge_max_kernel<4><<<(Etot * 4 + 255) / 256, blk, 0, stream>>>(ei, as1, ad1, emax1k, E0, Etot);
  decode_kernel<<<(N * 4 + 255) / 256, blk, 0, stream>>>(emax1k, emax1f, N * 4);
  edge_sum_kernel<4><<<(Etot * 4 + 255) / 256, blk, 0, stream>>>(ei, as1, ad1, emax1f, esum1, E0, Etot);
  edge_aggr_kernel<4><<<(Etot + 3) / 4, blk, 0, stream>>>(ei, as1, ad1, emax1f, esum1, h1, out1, E0, Etot);
  bias_relu_kernel<<<(int)(((size_t)N * 256 + 255) / 256), blk, 0, stream>>>(out1, b1, (size_t)N * 256, 255);

  // ---- layer 2 (h2/out2 reuse h1 region; all stream-ordered after aggr1) ----
  hipMemsetAsync(emax2k, 0, (size_t)N * 4, stream);
  hipMemsetAsync(esum2, 0, (size_t)N * 4, stream);
  gemm_tiled<<<dim3(1, (N + 63) / 64), blk, 0, stream>>>(out1, W2, h2, N, 256, 64);
  hipMemsetAsync(out2, 0, (size_t)N * 64 * 4, stream);
  alpha_kernel<1><<<(N + 3) / 4, blk, 0, stream>>>(h2, att_src2, att_dst2, as2, ad2, N);
  edge_max_kernel<1><<<(Etot + 255) / 256, blk, 0, stream>>>(ei, as2, ad2, emax2k, E0, Etot);
  decode_kernel<<<(N + 255) / 256, blk, 0, stream>>>(emax2k, emax2f, N);
  edge_sum_kernel<1><<<(Etot + 255) / 256, blk, 0, stream>>>(ei, as2, ad2, emax2f, esum2, E0, Etot);
  edge_aggr_kernel<1><<<(Etot + 3) / 4, blk, 0, stream>>>(ei, as2, ad2, emax2f, esum2, h2, out2, E0, Etot);

  // ---- epilogue ----
  pool_kernel<<<512, blk, 0, stream>>>(out2, b2, pooled, N);
  head_kernel<<<1, 64, 0, stream>>>(pooled, fc_w, fc_b, out, 1.0f / (float)N);
}

// Round 2
// 727.283 us; speedup vs baseline: 1.8435x; 1.8435x over previous
//
#include <hip/hip_runtime.h>
#include <math.h>

#define NEG_SLOPE 0.2f

__device__ __forceinline__ float lrelu(float a) { return a >= 0.f ? a : NEG_SLOPE * a; }

// ---- tiled fp32 GEMM: C[M,Ncol] = A[M,K] @ B[K,Ncol]; 64x64 tile, K-tile 16 ----
__global__ __launch_bounds__(256) void gemm_tiled(const float* __restrict__ A,
    const float* __restrict__ B, float* __restrict__ C, int M, int K, int Ncol) {
  __shared__ float As[16][65];
  __shared__ float Bs[16][65];
  const int tid = threadIdx.x;
  const int tx = tid & 15, ty = tid >> 4;
  const int row0 = blockIdx.y * 64, col0 = blockIdx.x * 64;
  float acc[4][4] = {};
  for (int k0 = 0; k0 < K; k0 += 16) {
#pragma unroll
    for (int i = 0; i < 4; i++) {
      int idx = tid + i * 256;
      int m = idx >> 4, kk = idx & 15;
      int gr = row0 + m;
      As[kk][m] = (gr < M) ? A[(size_t)gr * K + k0 + kk] : 0.f;
      int kb = idx >> 6, nb = idx & 63;
      Bs[kb][nb] = B[(size_t)(k0 + kb) * Ncol + col0 + nb];
    }
    __syncthreads();
#pragma unroll
    for (int kk = 0; kk < 16; kk++) {
      float a[4], b[4];
#pragma unroll
      for (int i = 0; i < 4; i++) a[i] = As[kk][ty * 4 + i];
#pragma unroll
      for (int j = 0; j < 4; j++) b[j] = Bs[kk][tx * 4 + j];
#pragma unroll
      for (int i = 0; i < 4; i++)
#pragma unroll
        for (int j = 0; j < 4; j++)
          acc[i][j] = fmaf(a[i], b[j], acc[i][j]);
    }
    __syncthreads();
  }
#pragma unroll
  for (int i = 0; i < 4; i++) {
    int gr = row0 + ty * 4 + i;
    if (gr < M) {
#pragma unroll
      for (int j = 0; j < 4; j++)
        C[(size_t)gr * Ncol + col0 + tx * 4 + j] = acc[i][j];
    }
  }
}

// ---- CSR build ----
__global__ __launch_bounds__(256) void deg_init_kernel(int* __restrict__ deg, int N) {
  int i = blockIdx.x * blockDim.x + threadIdx.x;
  if (i < N) deg[i] = 1;  // self-loop
}

__global__ __launch_bounds__(256) void deg_count_kernel(const int* __restrict__ ei,
    int* __restrict__ deg, int E0) {
  int e = blockIdx.x * blockDim.x + threadIdx.x;
  if (e < E0) atomicAdd(&deg[ei[E0 + e]], 1);
}

// single-block exclusive scan over N<=50176 via 1024 threads
__global__ __launch_bounds__(1024) void scan_kernel(const int* __restrict__ deg,
    int* __restrict__ rowptr, int N) {
  __shared__ int sums[1024];
  int t = threadIdx.x;
  int chunk = (N + 1023) / 1024;
  int start = t * chunk, end = start + chunk < N ? start + chunk : N;
  int s = 0;
  for (int i = start; i < end; i++) s += deg[i];
  sums[t] = s;
  __syncthreads();
  for (int off = 1; off < 1024; off <<= 1) {
    int v = (t >= off) ? sums[t - off] : 0;
    __syncthreads();
    sums[t] += v;
    __syncthreads();
  }
  int prefix = (t == 0) ? 0 : sums[t - 1];
  for (int i = start; i < end; i++) { rowptr[i] = prefix; prefix += deg[i]; }
  if (t == 1023) rowptr[N] = prefix;
}

__global__ __launch_bounds__(256) void scatter_kernel(const int* __restrict__ ei,
    int* __restrict__ cursor, int* __restrict__ csr_src, int E0, int Etot) {
  int e = blockIdx.x * blockDim.x + threadIdx.x;
  if (e >= Etot) return;
  int src, dst;
  if (e < E0) { src = ei[e]; dst = ei[E0 + e]; } else { src = e - E0; dst = src; }
  int pos = atomicAdd(&cursor[dst], 1);
  csr_src[pos] = src;
}

// ---- per-(node,head) attention coefficients; C=64, one wave per (n,h) ----
template <int H>
__global__ __launch_bounds__(256) void alpha_kernel(const float* __restrict__ h,
    const float* __restrict__ att_s, const float* __restrict__ att_d,
    float* __restrict__ as_, float* __restrict__ ad_, int Nn) {
  int wave = (blockIdx.x * blockDim.x + threadIdx.x) >> 6;
  int lane = threadIdx.x & 63;
  if (wave >= Nn * H) return;
  int n = wave / H, hh = wave % H;
  float hv = h[(size_t)n * (H * 64) + hh * 64 + lane];
  float vs = hv * att_s[hh * 64 + lane];
  float vd = hv * att_d[hh * 64 + lane];
  for (int off = 32; off; off >>= 1) {
    vs += __shfl_down(vs, off);
    vd += __shfl_down(vd, off);
  }
  if (lane == 0) { as_[wave] = vs; ad_[wave] = vd; }
}

// ---- per-node softmax stats (max + 1/denom), no atomics; one wave per (n,h) ----
template <int H>
__global__ __launch_bounds__(256) void softmax_stats_kernel(const int* __restrict__ rowptr,
    const int* __restrict__ csr_src, const float* __restrict__ as_,
    const float* __restrict__ ad_, float* __restrict__ emax, float* __restrict__ inv_esum,
    int Nn) {
  int wave = (blockIdx.x * blockDim.x + threadIdx.x) >> 6;
  int lane = threadIdx.x & 63;
  if (wave >= Nn * H) return;
  int n = wave / H, hh = wave % H;
  int row = rowptr[n], deg = rowptr[n + 1] - row;
  float adv = ad_[n * H + hh];
  float m = -1e30f;
  for (int s = lane; s < deg; s += 64) {
    int src = csr_src[row + s];
    m = fmaxf(m, lrelu(as_[src * H + hh] + adv));
  }
#pragma unroll
  for (int off = 32; off; off >>= 1) m = fmaxf(m, __shfl_xor(m, off));
  float sum = 0.f;
  for (int s = lane; s < deg; s += 64) {
    int src = csr_src[row + s];
    sum += __expf(lrelu(as_[src * H + hh] + adv) - m);
  }
#pragma unroll
  for (int off = 32; off; off >>= 1) sum += __shfl_xor(sum, off);
  if (lane == 0) {
    emax[n * H + hh] = m;
    inv_esum[n * H + hh] = 1.f / (sum + 1e-16f);
  }
}

// ---- layer-1 aggregate: block(256)=4 waves per node, wave=head, lane=channel ----
__global__ __launch_bounds__(256) void aggr1_kernel(const int* __restrict__ rowptr,
    const int* __restrict__ csr_src, const float* __restrict__ as_,
    const float* __restrict__ ad_, const float* __restrict__ emax,
    const float* __restrict__ inv_esum, const float* __restrict__ h1,
    const float* __restrict__ b1, float* __restrict__ out1, int Nn) {
  int n = blockIdx.x;
  if (n >= Nn) return;
  int hh = threadIdx.x >> 6, lane = threadIdx.x & 63;
  int row = rowptr[n], deg = rowptr[n + 1] - row;
  float m = emax[n * 4 + hh], inv = inv_esum[n * 4 + hh], adv = ad_[n * 4 + hh];
  float acc = 0.f;
  int s = 0;
  for (; s + 2 <= deg; s += 2) {
    int s0 = csr_src[row + s], s1 = csr_src[row + s + 1];
    float a0 = as_[s0 * 4 + hh], a1 = as_[s1 * 4 + hh];
    float x0 = h1[(size_t)s0 * 256 + hh * 64 + lane];
    float x1 = h1[(size_t)s1 * 256 + hh * 64 + lane];
    float w0 = __expf(lrelu(a0 + adv) - m) * inv;
    float w1 = __expf(lrelu(a1 + adv) - m) * inv;
    acc = fmaf(w0, x0, acc);
    acc = fmaf(w1, x1, acc);
  }
  if (s < deg) {
    int s0 = csr_src[row + s];
    float w0 = __expf(lrelu(as_[s0 * 4 + hh] + adv) - m) * inv;
    acc = fmaf(w0, h1[(size_t)s0 * 256 + hh * 64 + lane], acc);
  }
  float v = acc + b1[hh * 64 + lane];
  out1[(size_t)n * 256 + hh * 64 + lane] = v > 0.f ? v : 0.f;
}

// ---- layer-2 aggregate + relu + global mean pool; grid-stride, 4 nodes/block ----
__global__ __launch_bounds__(256) void aggr2_pool_kernel(const int* __restrict__ rowptr,
    const int* __restrict__ csr_src, const float* __restrict__ as_,
    const float* __restrict__ ad_, const float* __restrict__ emax,
    const float* __restrict__ inv_esum, const float* __restrict__ h2,
    const float* __restrict__ b2, float* __restrict__ pooled, int Nn) {
  int wv = threadIdx.x >> 6, lane = threadIdx.x & 63;
  float pacc = 0.f;
  for (int n = blockIdx.x * 4 + wv; n < Nn; n += gridDim.x * 4) {
    int row = rowptr[n], deg = rowptr[n + 1] - row;
    float m = emax[n], inv = inv_esum[n], adv = ad_[n];
    float acc = 0.f;
    int s = 0;
    for (; s + 2 <= deg; s += 2) {
      int s0 = csr_src[row + s], s1 = csr_src[row + s + 1];
      float a0 = as_[s0], a1 = as_[s1];
      float x0 = h2[(size_t)s0 * 64 + lane];
      float x1 = h2[(size_t)s1 * 64 + lane];
      float w0 = __expf(lrelu(a0 + adv) - m) * inv;
      float w1 = __expf(lrelu(a1 + adv) - m) * inv;
      acc = fmaf(w0, x0, acc);
      acc = fmaf(w1, x1, acc);
    }
    if (s < deg) {
      int s0 = csr_src[row + s];
      float w0 = __expf(lrelu(as_[s0] + adv) - m) * inv;
      acc = fmaf(w0, h2[(size_t)s0 * 64 + lane], acc);
    }
    float v = acc + b2[lane];
    pacc += v > 0.f ? v : 0.f;
  }
  __shared__ float sred[256];
  sred[threadIdx.x] = pacc;
  __syncthreads();
  if (threadIdx.x < 64)
    atomicAdd(&pooled[threadIdx.x],
              sred[threadIdx.x] + sred[threadIdx.x + 64] + sred[threadIdx.x + 128] +
                  sred[threadIdx.x + 192]);
}

// ---- final fc + log_softmax; single block of 64 threads ----
__global__ void head_kernel(const float* __restrict__ pooled, const float* __restrict__ fc_w,
    const float* __restrict__ fc_b, float* __restrict__ out, float invN) {
  __shared__ float p[64];
  __shared__ float lg[40];
  __shared__ float lse;
  int t = threadIdx.x;
  p[t] = pooled[t] * invN;
  __syncthreads();
  if (t < 40) {
    float s = fc_b[t];
    for (int c = 0; c < 64; c++) s = fmaf(p[c], fc_w[c * 40 + t], s);
    lg[t] = s;
  }
  __syncthreads();
  if (t == 0) {
    float m = -1e30f;
    for (int j = 0; j < 40; j++) m = fmaxf(m, lg[j]);
    float sum = 0.f;
    for (int j = 0; j < 40; j++) sum += expf(lg[j] - m);
    lse = m + logf(sum);
  }
  __syncthreads();
  if (t < 40) out[t] = lg[t] - lse;
}

extern "C" void kernel_launch(void* const* d_in, const int* in_sizes, int n_in,
                              void* d_out, int out_size, void* d_ws, size_t ws_size,
                              hipStream_t stream) {
  const float* x        = (const float*)d_in[0];
  const int*   ei       = (const int*)d_in[1];
  const float* W1       = (const float*)d_in[2];
  const float* att_src1 = (const float*)d_in[3];
  const float* att_dst1 = (const float*)d_in[4];
  const float* b1       = (const float*)d_in[5];
  const float* W2       = (const float*)d_in[6];
  const float* att_src2 = (const float*)d_in[7];
  const float* att_dst2 = (const float*)d_in[8];
  const float* b2       = (const float*)d_in[9];
  const float* fc_w     = (const float*)d_in[10];
  const float* fc_b     = (const float*)d_in[11];
  float* out = (float*)d_out;

  const int N    = in_sizes[0] / 128;  // 50000
  const int E0   = in_sizes[1] / 2;    // 800000
  const int Etot = E0 + N;

  float* ws = (float*)d_ws;
  size_t o = 0;
  float* h1   = ws + o; o += (size_t)N * 256;   // also reused as h2
  float* out1 = ws + o; o += (size_t)N * 256;
  float* h2   = h1;
  float* as1  = ws + o; o += (size_t)N * 4;
  float* ad1  = ws + o; o += (size_t)N * 4;
  float* emax1 = ws + o; o += (size_t)N * 4;
  float* inv1  = ws + o; o += (size_t)N * 4;
  float* as2  = ws + o; o += N;
  float* ad2  = ws + o; o += N;
  float* emax2 = ws + o; o += N;
  float* inv2  = ws + o; o += N;
  int* degcur = (int*)(ws + o); o += N;        // deg during build, then cursor
  int* rowptr = (int*)(ws + o); o += N + 1;
  int* csr_src = (int*)(ws + o); o += Etot;
  float* pooled = ws + o; o += 64;

  dim3 blk(256);

  // ---- CSR build (edge data identical every call; ws re-poisoned, so rebuild) ----
  deg_init_kernel<<<(N + 255) / 256, blk, 0, stream>>>(degcur, N);
  deg_count_kernel<<<(E0 + 255) / 256, blk, 0, stream>>>(ei, degcur, E0);
  scan_kernel<<<1, 1024, 0, stream>>>(degcur, rowptr, N);
  hipMemcpyAsync(degcur, rowptr, (size_t)N * sizeof(int), hipMemcpyDeviceToDevice, stream);
  scatter_kernel<<<(Etot + 255) / 256, blk, 0, stream>>>(ei, degcur, csr_src, E0, Etot);

  hipMemsetAsync(pooled, 0, 64 * sizeof(float), stream);

  // ---- layer 1 ----
  gemm_tiled<<<dim3(256 / 64, (N + 63) / 64), blk, 0, stream>>>(x, W1, h1, N, 128, 256);
  alpha_kernel<4><<<N, blk, 0, stream>>>(h1, att_src1, att_dst1, as1, ad1, N);
  softmax_stats_kernel<4><<<N, blk, 0, stream>>>(rowptr, csr_src, as1, ad1, emax1, inv1, N);
  aggr1_kernel<<<N, blk, 0, stream>>>(rowptr, csr_src, as1, ad1, emax1, inv1, h1, b1, out1, N);

  // ---- layer 2 (h2 reuses h1 region; stream-ordered after aggr1) ----
  gemm_tiled<<<dim3(1, (N + 63) / 64), blk, 0, stream>>>(out1, W2, h2, N, 256, 64);
  alpha_kernel<1><<<(N + 3) / 4, blk, 0, stream>>>(h2, att_src2, att_dst2, as2, ad2, N);
  softmax_stats_kernel<1><<<(N + 3) / 4, blk, 0, stream>>>(rowptr, csr_src, as2, ad2, emax2, inv2, N);
  aggr2_pool_kernel<<<1024, blk, 0, stream>>>(rowptr, csr_src, as2, ad2, emax2, inv2, h2, b2,
                                              pooled, N);

  // ---- epilogue ----
  head_kernel<<<1, 64, 0, stream>>>(pooled, fc_w, fc_b, out, 1.0f / (float)N);
}

// Round 3
// 673.605 us; speedup vs baseline: 1.9904x; 1.0797x over previous
//
#include <hip/hip_runtime.h>
#include <hip/hip_bf16.h>
#include <math.h>

#define NEG_SLOPE 0.2f

__device__ __forceinline__ float lrelu(float a) { return a >= 0.f ? a : NEG_SLOPE * a; }
__device__ __forceinline__ void st_c(float* p, float v) { *p = v; }
__device__ __forceinline__ void st_c(__hip_bfloat16* p, float v) { *p = __float2bfloat16(v); }

// ---- tiled fp32 GEMM: C[M,Ncol] = A[M,K] @ B[K,Ncol]; 64x64 tile, K-tile 16 ----
template <typename OT>
__global__ __launch_bounds__(256) void gemm_tiled(const float* __restrict__ A,
    const float* __restrict__ B, OT* __restrict__ C, int M, int K, int Ncol) {
  __shared__ float As[16][65];
  __shared__ float Bs[16][65];
  const int tid = threadIdx.x;
  const int tx = tid & 15, ty = tid >> 4;
  const int row0 = blockIdx.y * 64, col0 = blockIdx.x * 64;
  float acc[4][4] = {};
  for (int k0 = 0; k0 < K; k0 += 16) {
#pragma unroll
    for (int i = 0; i < 4; i++) {
      int idx = tid + i * 256;
      int m = idx >> 4, kk = idx & 15;
      int gr = row0 + m;
      As[kk][m] = (gr < M) ? A[(size_t)gr * K + k0 + kk] : 0.f;
      int kb = idx >> 6, nb = idx & 63;
      Bs[kb][nb] = B[(size_t)(k0 + kb) * Ncol + col0 + nb];
    }
    __syncthreads();
#pragma unroll
    for (int kk = 0; kk < 16; kk++) {
      float a[4], b[4];
#pragma unroll
      for (int i = 0; i < 4; i++) a[i] = As[kk][ty * 4 + i];
#pragma unroll
      for (int j = 0; j < 4; j++) b[j] = Bs[kk][tx * 4 + j];
#pragma unroll
      for (int i = 0; i < 4; i++)
#pragma unroll
        for (int j = 0; j < 4; j++)
          acc[i][j] = fmaf(a[i], b[j], acc[i][j]);
    }
    __syncthreads();
  }
#pragma unroll
  for (int i = 0; i < 4; i++) {
    int gr = row0 + ty * 4 + i;
    if (gr < M) {
#pragma unroll
      for (int j = 0; j < 4; j++)
        st_c(&C[(size_t)gr * Ncol + col0 + tx * 4 + j], acc[i][j]);
    }
  }
}

// ---- CSR build ----
__global__ __launch_bounds__(256) void deg_init_kernel(int* __restrict__ deg, int N) {
  int i = blockIdx.x * blockDim.x + threadIdx.x;
  if (i < N) deg[i] = 1;  // self-loop
}

__global__ __launch_bounds__(256) void deg_count_kernel(const int* __restrict__ ei,
    int* __restrict__ deg, int E0) {
  int e = blockIdx.x * blockDim.x + threadIdx.x;
  if (e < E0) atomicAdd(&deg[ei[E0 + e]], 1);
}

// single-block exclusive scan over N<=50176 via 1024 threads
__global__ __launch_bounds__(1024) void scan_kernel(const int* __restrict__ deg,
    int* __restrict__ rowptr, int N) {
  __shared__ int sums[1024];
  int t = threadIdx.x;
  int chunk = (N + 1023) / 1024;
  int start = t * chunk, end = start + chunk < N ? start + chunk : N;
  int s = 0;
  for (int i = start; i < end; i++) s += deg[i];
  sums[t] = s;
  __syncthreads();
  for (int off = 1; off < 1024; off <<= 1) {
    int v = (t >= off) ? sums[t - off] : 0;
    __syncthreads();
    sums[t] += v;
    __syncthreads();
  }
  int prefix = (t == 0) ? 0 : sums[t - 1];
  for (int i = start; i < end; i++) { rowptr[i] = prefix; prefix += deg[i]; }
  if (t == 1023) rowptr[N] = prefix;
}

__global__ __launch_bounds__(256) void scatter_kernel(const int* __restrict__ ei,
    int* __restrict__ cursor, int* __restrict__ csr_src, int E0, int Etot) {
  int e = blockIdx.x * blockDim.x + threadIdx.x;
  if (e >= Etot) return;
  int src, dst;
  if (e < E0) { src = ei[e]; dst = ei[E0 + e]; } else { src = e - E0; dst = src; }
  int pos = atomicAdd(&cursor[dst], 1);
  csr_src[pos] = src;
}

// ---- per-(node,head) attention coefficients (bf16 h); one wave per (n,h) ----
template <int H>
__global__ __launch_bounds__(256) void alpha_kernel(const __hip_bfloat16* __restrict__ h,
    const float* __restrict__ att_s, const float* __restrict__ att_d,
    float* __restrict__ as_, float* __restrict__ ad_, int Nn) {
  int wave = (blockIdx.x * blockDim.x + threadIdx.x) >> 6;
  int lane = threadIdx.x & 63;
  if (wave >= Nn * H) return;
  int n = wave / H, hh = wave % H;
  float hv = __bfloat162float(h[(size_t)n * (H * 64) + hh * 64 + lane]);
  float vs = hv * att_s[hh * 64 + lane];
  float vd = hv * att_d[hh * 64 + lane];
  for (int off = 32; off; off >>= 1) {
    vs += __shfl_down(vs, off);
    vd += __shfl_down(vd, off);
  }
  if (lane == 0) { as_[wave] = vs; ad_[wave] = vd; }
}

// ---- layer-1 softmax stats + edge weights (unnormalized p, per-node inv) ----
// one wave per node, lane per edge, all 4 heads via float4
__global__ __launch_bounds__(256) void stats1_kernel(const int* __restrict__ rowptr,
    const int* __restrict__ csr_src, const float4* __restrict__ as4,
    const float4* __restrict__ ad4, float4* __restrict__ w4,
    float4* __restrict__ inv4, int Nn) {
  int wave = (blockIdx.x * blockDim.x + threadIdx.x) >> 6;
  int lane = threadIdx.x & 63;
  if (wave >= Nn) return;
  int n = wave;
  int row = rowptr[n], deg = rowptr[n + 1] - row;
  float4 adv = ad4[n];
  float m0 = -1e30f, m1 = -1e30f, m2 = -1e30f, m3 = -1e30f;
  for (int s = lane; s < deg; s += 64) {
    int src = csr_src[row + s];
    float4 a = as4[src];
    m0 = fmaxf(m0, lrelu(a.x + adv.x));
    m1 = fmaxf(m1, lrelu(a.y + adv.y));
    m2 = fmaxf(m2, lrelu(a.z + adv.z));
    m3 = fmaxf(m3, lrelu(a.w + adv.w));
  }
#pragma unroll
  for (int off = 32; off; off >>= 1) {
    m0 = fmaxf(m0, __shfl_xor(m0, off));
    m1 = fmaxf(m1, __shfl_xor(m1, off));
    m2 = fmaxf(m2, __shfl_xor(m2, off));
    m3 = fmaxf(m3, __shfl_xor(m3, off));
  }
  float s0 = 0.f, s1 = 0.f, s2 = 0.f, s3 = 0.f;
  for (int s = lane; s < deg; s += 64) {
    int src = csr_src[row + s];
    float4 a = as4[src];
    float p0 = __expf(lrelu(a.x + adv.x) - m0);
    float p1 = __expf(lrelu(a.y + adv.y) - m1);
    float p2 = __expf(lrelu(a.z + adv.z) - m2);
    float p3 = __expf(lrelu(a.w + adv.w) - m3);
    s0 += p0; s1 += p1; s2 += p2; s3 += p3;
    w4[row + s] = make_float4(p0, p1, p2, p3);
  }
#pragma unroll
  for (int off = 32; off; off >>= 1) {
    s0 += __shfl_xor(s0, off);
    s1 += __shfl_xor(s1, off);
    s2 += __shfl_xor(s2, off);
    s3 += __shfl_xor(s3, off);
  }
  if (lane == 0)
    inv4[n] = make_float4(1.f / (s0 + 1e-16f), 1.f / (s1 + 1e-16f),
                          1.f / (s2 + 1e-16f), 1.f / (s3 + 1e-16f));
}

// ---- layer-2 stats (H=1), scalar version ----
__global__ __launch_bounds__(256) void stats2_kernel(const int* __restrict__ rowptr,
    const int* __restrict__ csr_src, const float* __restrict__ as_,
    const float* __restrict__ ad_, float* __restrict__ w, float* __restrict__ inv,
    int Nn) {
  int wave = (blockIdx.x * blockDim.x + threadIdx.x) >> 6;
  int lane = threadIdx.x & 63;
  if (wave >= Nn) return;
  int n = wave;
  int row = rowptr[n], deg = rowptr[n + 1] - row;
  float adv = ad_[n];
  float m = -1e30f;
  for (int s = lane; s < deg; s += 64) m = fmaxf(m, lrelu(as_[csr_src[row + s]] + adv));
#pragma unroll
  for (int off = 32; off; off >>= 1) m = fmaxf(m, __shfl_xor(m, off));
  float sum = 0.f;
  for (int s = lane; s < deg; s += 64) {
    float p = __expf(lrelu(as_[csr_src[row + s]] + adv) - m);
    sum += p;
    w[row + s] = p;
  }
#pragma unroll
  for (int off = 32; off; off >>= 1) sum += __shfl_xor(sum, off);
  if (lane == 0) inv[n] = 1.f / (sum + 1e-16f);
}

// ---- layer-1 aggregate: block=4 waves per node, wave=head, lane=channel ----
__global__ __launch_bounds__(256) void aggr1_kernel(const int* __restrict__ rowptr,
    const int* __restrict__ csr_src, const float* __restrict__ w,
    const float* __restrict__ inv, const __hip_bfloat16* __restrict__ h1,
    const float* __restrict__ b1, float* __restrict__ out1, int Nn) {
  int n = blockIdx.x;
  if (n >= Nn) return;
  int hh = threadIdx.x >> 6, lane = threadIdx.x & 63;
  int row = rowptr[n], deg = rowptr[n + 1] - row;
  const __hip_bfloat16* hbase = h1 + hh * 64 + lane;
  float acc0 = 0.f, acc1 = 0.f;
  int s = 0;
  for (; s + 2 <= deg; s += 2) {
    int i0 = csr_src[row + s], i1 = csr_src[row + s + 1];
    float w0 = w[(size_t)(row + s) * 4 + hh];
    float w1 = w[(size_t)(row + s + 1) * 4 + hh];
    float x0 = __bfloat162float(hbase[(size_t)i0 * 256]);
    float x1 = __bfloat162float(hbase[(size_t)i1 * 256]);
    acc0 = fmaf(w0, x0, acc0);
    acc1 = fmaf(w1, x1, acc1);
  }
  if (s < deg) {
    int i0 = csr_src[row + s];
    acc0 = fmaf(w[(size_t)(row + s) * 4 + hh], __bfloat162float(hbase[(size_t)i0 * 256]), acc0);
  }
  float v = (acc0 + acc1) * inv[n * 4 + hh] + b1[hh * 64 + lane];
  out1[(size_t)n * 256 + hh * 64 + lane] = v > 0.f ? v : 0.f;
}

// ---- layer-2 aggregate + relu + global mean pool; grid-stride, 4 nodes/block ----
__global__ __launch_bounds__(256) void aggr2_pool_kernel(const int* __restrict__ rowptr,
    const int* __restrict__ csr_src, const float* __restrict__ w,
    const float* __restrict__ inv, const __hip_bfloat16* __restrict__ h2,
    const float* __restrict__ b2, float* __restrict__ pooled, int Nn) {
  int wv = threadIdx.x >> 6, lane = threadIdx.x & 63;
  const __hip_bfloat16* hbase = h2 + lane;
  float pacc = 0.f;
  for (int n = blockIdx.x * 4 + wv; n < Nn; n += gridDim.x * 4) {
    int row = rowptr[n], deg = rowptr[n + 1] - row;
    float acc0 = 0.f, acc1 = 0.f;
    int s = 0;
    for (; s + 2 <= deg; s += 2) {
      int i0 = csr_src[row + s], i1 = csr_src[row + s + 1];
      float w0 = w[row + s], w1 = w[row + s + 1];
      float x0 = __bfloat162float(hbase[(size_t)i0 * 64]);
      float x1 = __bfloat162float(hbase[(size_t)i1 * 64]);
      acc0 = fmaf(w0, x0, acc0);
      acc1 = fmaf(w1, x1, acc1);
    }
    if (s < deg) {
      int i0 = csr_src[row + s];
      acc0 = fmaf(w[row + s], __bfloat162float(hbase[(size_t)i0 * 64]), acc0);
    }
    float v = (acc0 + acc1) * inv[n] + b2[lane];
    pacc += v > 0.f ? v : 0.f;
  }
  __shared__ float sred[256];
  sred[threadIdx.x] = pacc;
  __syncthreads();
  if (threadIdx.x < 64)
    atomicAdd(&pooled[threadIdx.x],
              sred[threadIdx.x] + sred[threadIdx.x + 64] + sred[threadIdx.x + 128] +
                  sred[threadIdx.x + 192]);
}

// ---- final fc + log_softmax; single block of 64 threads ----
__global__ void head_kernel(const float* __restrict__ pooled, const float* __restrict__ fc_w,
    const float* __restrict__ fc_b, float* __restrict__ out, float invN) {
  __shared__ float p[64];
  __shared__ float lg[40];
  __shared__ float lse;
  int t = threadIdx.x;
  p[t] = pooled[t] * invN;
  __syncthreads();
  if (t < 40) {
    float s = fc_b[t];
    for (int c = 0; c < 64; c++) s = fmaf(p[c], fc_w[c * 40 + t], s);
    lg[t] = s;
  }
  __syncthreads();
  if (t == 0) {
    float m = -1e30f;
    for (int j = 0; j < 40; j++) m = fmaxf(m, lg[j]);
    float sum = 0.f;
    for (int j = 0; j < 40; j++) sum += expf(lg[j] - m);
    lse = m + logf(sum);
  }
  __syncthreads();
  if (t < 40) out[t] = lg[t] - lse;
}

extern "C" void kernel_launch(void* const* d_in, const int* in_sizes, int n_in,
                              void* d_out, int out_size, void* d_ws, size_t ws_size,
                              hipStream_t stream) {
  const float* x        = (const float*)d_in[0];
  const int*   ei       = (const int*)d_in[1];
  const float* W1       = (const float*)d_in[2];
  const float* att_src1 = (const float*)d_in[3];
  const float* att_dst1 = (const float*)d_in[4];
  const float* b1       = (const float*)d_in[5];
  const float* W2       = (const float*)d_in[6];
  const float* att_src2 = (const float*)d_in[7];
  const float* att_dst2 = (const float*)d_in[8];
  const float* b2       = (const float*)d_in[9];
  const float* fc_w     = (const float*)d_in[10];
  const float* fc_b     = (const float*)d_in[11];
  float* out = (float*)d_out;

  const int N    = in_sizes[0] / 128;  // 50000
  const int E0   = in_sizes[1] / 2;    // 800000
  const int Etot = E0 + N;

  float* ws = (float*)d_ws;
  size_t o = 0;
  __hip_bfloat16* h1 = (__hip_bfloat16*)(ws + o); o += (size_t)N * 128;  // bf16, reused as h2
  __hip_bfloat16* h2 = h1;
  float* out1 = ws + o; o += (size_t)N * 256;
  float* as1  = ws + o; o += (size_t)N * 4;
  float* ad1  = ws + o; o += (size_t)N * 4;
  float* inv1 = ws + o; o += (size_t)N * 4;
  float* w1   = ws + o; o += (size_t)Etot * 4;
  float* as2  = ws + o; o += N;
  float* ad2  = ws + o; o += N;
  float* inv2 = ws + o; o += N;
  float* w2   = ws + o; o += Etot;
  int* degcur = (int*)(ws + o); o += N;
  int* rowptr = (int*)(ws + o); o += N + 1;
  o = (o + 3) & ~(size_t)3;
  int* csr_src = (int*)(ws + o); o += Etot;
  float* pooled = ws + o; o += 64;

  dim3 blk(256);

  // ---- CSR build ----
  deg_init_kernel<<<(N + 255) / 256, blk, 0, stream>>>(degcur, N);
  deg_count_kernel<<<(E0 + 255) / 256, blk, 0, stream>>>(ei, degcur, E0);
  scan_kernel<<<1, 1024, 0, stream>>>(degcur, rowptr, N);
  hipMemcpyAsync(degcur, rowptr, (size_t)N * sizeof(int), hipMemcpyDeviceToDevice, stream);
  scatter_kernel<<<(Etot + 255) / 256, blk, 0, stream>>>(ei, degcur, csr_src, E0, Etot);

  hipMemsetAsync(pooled, 0, 64 * sizeof(float), stream);

  // ---- layer 1 ----
  gemm_tiled<<<dim3(256 / 64, (N + 63) / 64), blk, 0, stream>>>(x, W1, h1, N, 128, 256);
  alpha_kernel<4><<<N, blk, 0, stream>>>(h1, att_src1, att_dst1, as1, ad1, N);
  stats1_kernel<<<(N + 3) / 4, blk, 0, stream>>>(rowptr, csr_src, (const float4*)as1,
                                                 (const float4*)ad1, (float4*)w1,
                                                 (float4*)inv1, N);
  aggr1_kernel<<<N, blk, 0, stream>>>(rowptr, csr_src, w1, inv1, h1, b1, out1, N);

  // ---- layer 2 (h2 reuses h1 region; stream-ordered after aggr1) ----
  gemm_tiled<<<dim3(1, (N + 63) / 64), blk, 0, stream>>>(out1, W2, h2, N, 256, 64);
  alpha_kernel<1><<<(N + 3) / 4, blk, 0, stream>>>(h2, att_src2, att_dst2, as2, ad2, N);
  stats2_kernel<<<(N + 3) / 4, blk, 0, stream>>>(rowptr, csr_src, as2, ad2, w2, inv2, N);
  aggr2_pool_kernel<<<1024, blk, 0, stream>>>(rowptr, csr_src, w2, inv2, h2, b2, pooled, N);

  // ---- epilogue ----
  head_kernel<<<1, 64, 0, stream>>>(pooled, fc_w, fc_b, out, 1.0f / (float)N);
}

// Round 4
// 554.899 us; speedup vs baseline: 2.4162x; 1.2139x over previous
//
#include <hip/hip_runtime.h>
#include <hip/hip_bf16.h>
#include <math.h>

#define NEG_SLOPE 0.2f

__device__ __forceinline__ float lrelu(float a) { return a >= 0.f ? a : NEG_SLOPE * a; }
__device__ __forceinline__ float b2f(unsigned short u) {
  return __uint_as_float(((unsigned)u) << 16);
}
__device__ __forceinline__ void st_c(float* p, float v) { *p = v; }
__device__ __forceinline__ void st_c(__hip_bfloat16* p, float v) { *p = __float2bfloat16(v); }

// ---- tiled fp32 GEMM: C[M,Ncol] = A[M,K] @ B[K,Ncol]; 64x64 tile, K-tile 16 ----
template <typename OT>
__global__ __launch_bounds__(256) void gemm_tiled(const float* __restrict__ A,
    const float* __restrict__ B, OT* __restrict__ C, int M, int K, int Ncol) {
  __shared__ float As[16][68];   // 68: keeps 16B alignment for b128 fragment reads
  __shared__ float Bs[16][68];
  const int tid = threadIdx.x;
  const int tx = tid & 15, ty = tid >> 4;
  const int row0 = blockIdx.y * 64, col0 = blockIdx.x * 64;
  float acc[4][4] = {};
  for (int k0 = 0; k0 < K; k0 += 16) {
#pragma unroll
    for (int i = 0; i < 4; i++) {
      int idx = tid + i * 256;
      int m = idx >> 4, kk = idx & 15;
      int gr = row0 + m;
      As[kk][m] = (gr < M) ? A[(size_t)gr * K + k0 + kk] : 0.f;
      int kb = idx >> 6, nb = idx & 63;
      Bs[kb][nb] = B[(size_t)(k0 + kb) * Ncol + col0 + nb];
    }
    __syncthreads();
#pragma unroll
    for (int kk = 0; kk < 16; kk++) {
      float a[4], b[4];
#pragma unroll
      for (int i = 0; i < 4; i++) a[i] = As[kk][ty * 4 + i];
#pragma unroll
      for (int j = 0; j < 4; j++) b[j] = Bs[kk][tx * 4 + j];
#pragma unroll
      for (int i = 0; i < 4; i++)
#pragma unroll
        for (int j = 0; j < 4; j++)
          acc[i][j] = fmaf(a[i], b[j], acc[i][j]);
    }
    __syncthreads();
  }
#pragma unroll
  for (int i = 0; i < 4; i++) {
    int gr = row0 + ty * 4 + i;
    if (gr < M) {
#pragma unroll
      for (int j = 0; j < 4; j++)
        st_c(&C[(size_t)gr * Ncol + col0 + tx * 4 + j], acc[i][j]);
    }
  }
}

// ---- CSR build ----
__global__ __launch_bounds__(256) void deg_init_kernel(int* __restrict__ deg, int N) {
  int i = blockIdx.x * blockDim.x + threadIdx.x;
  if (i < N) deg[i] = 1;  // self-loop
}

__global__ __launch_bounds__(256) void deg_count_kernel(const int* __restrict__ ei,
    int* __restrict__ deg, int E0) {
  int e = blockIdx.x * blockDim.x + threadIdx.x;
  if (e < E0) atomicAdd(&deg[ei[E0 + e]], 1);
}

// single-block exclusive scan over N<=50176 via 1024 threads
__global__ __launch_bounds__(1024) void scan_kernel(const int* __restrict__ deg,
    int* __restrict__ rowptr, int N) {
  __shared__ int sums[1024];
  int t = threadIdx.x;
  int chunk = (N + 1023) / 1024;
  int start = t * chunk, end = start + chunk < N ? start + chunk : N;
  int s = 0;
  for (int i = start; i < end; i++) s += deg[i];
  sums[t] = s;
  __syncthreads();
  for (int off = 1; off < 1024; off <<= 1) {
    int v = (t >= off) ? sums[t - off] : 0;
    __syncthreads();
    sums[t] += v;
    __syncthreads();
  }
  int prefix = (t == 0) ? 0 : sums[t - 1];
  for (int i = start; i < end; i++) { rowptr[i] = prefix; prefix += deg[i]; }
  if (t == 1023) rowptr[N] = prefix;
}

__global__ __launch_bounds__(256) void scatter_kernel(const int* __restrict__ ei,
    int* __restrict__ cursor, int* __restrict__ csr_src, int E0, int Etot) {
  int e = blockIdx.x * blockDim.x + threadIdx.x;
  if (e >= Etot) return;
  int src, dst;
  if (e < E0) { src = ei[e]; dst = ei[E0 + e]; } else { src = e - E0; dst = src; }
  int pos = atomicAdd(&cursor[dst], 1);
  csr_src[pos] = src;
}

// ---- per-(node,head) attention coefficients (bf16 h); one wave per (n,h) ----
template <int H>
__global__ __launch_bounds__(256) void alpha_kernel(const __hip_bfloat16* __restrict__ h,
    const float* __restrict__ att_s, const float* __restrict__ att_d,
    float* __restrict__ as_, float* __restrict__ ad_, int Nn) {
  int wave = (blockIdx.x * blockDim.x + threadIdx.x) >> 6;
  int lane = threadIdx.x & 63;
  if (wave >= Nn * H) return;
  int n = wave / H, hh = wave % H;
  float hv = __bfloat162float(h[(size_t)n * (H * 64) + hh * 64 + lane]);
  float vs = hv * att_s[hh * 64 + lane];
  float vd = hv * att_d[hh * 64 + lane];
  for (int off = 32; off; off >>= 1) {
    vs += __shfl_down(vs, off);
    vd += __shfl_down(vd, off);
  }
  if (lane == 0) { as_[wave] = vs; ad_[wave] = vd; }
}

// ---- layer-1 softmax stats + edge weights (unnormalized p, per-node inv) ----
__global__ __launch_bounds__(256) void stats1_kernel(const int* __restrict__ rowptr,
    const int* __restrict__ csr_src, const float4* __restrict__ as4,
    const float4* __restrict__ ad4, float4* __restrict__ w4,
    float4* __restrict__ inv4, int Nn) {
  int wave = (blockIdx.x * blockDim.x + threadIdx.x) >> 6;
  int lane = threadIdx.x & 63;
  if (wave >= Nn) return;
  int n = wave;
  int row = rowptr[n], deg = rowptr[n + 1] - row;
  float4 adv = ad4[n];
  float m0 = -1e30f, m1 = -1e30f, m2 = -1e30f, m3 = -1e30f;
  for (int s = lane; s < deg; s += 64) {
    int src = csr_src[row + s];
    float4 a = as4[src];
    m0 = fmaxf(m0, lrelu(a.x + adv.x));
    m1 = fmaxf(m1, lrelu(a.y + adv.y));
    m2 = fmaxf(m2, lrelu(a.z + adv.z));
    m3 = fmaxf(m3, lrelu(a.w + adv.w));
  }
#pragma unroll
  for (int off = 32; off; off >>= 1) {
    m0 = fmaxf(m0, __shfl_xor(m0, off));
    m1 = fmaxf(m1, __shfl_xor(m1, off));
    m2 = fmaxf(m2, __shfl_xor(m2, off));
    m3 = fmaxf(m3, __shfl_xor(m3, off));
  }
  float s0 = 0.f, s1 = 0.f, s2 = 0.f, s3 = 0.f;
  for (int s = lane; s < deg; s += 64) {
    int src = csr_src[row + s];
    float4 a = as4[src];
    float p0 = __expf(lrelu(a.x + adv.x) - m0);
    float p1 = __expf(lrelu(a.y + adv.y) - m1);
    float p2 = __expf(lrelu(a.z + adv.z) - m2);
    float p3 = __expf(lrelu(a.w + adv.w) - m3);
    s0 += p0; s1 += p1; s2 += p2; s3 += p3;
    w4[row + s] = make_float4(p0, p1, p2, p3);
  }
#pragma unroll
  for (int off = 32; off; off >>= 1) {
    s0 += __shfl_xor(s0, off);
    s1 += __shfl_xor(s1, off);
    s2 += __shfl_xor(s2, off);
    s3 += __shfl_xor(s3, off);
  }
  if (lane == 0)
    inv4[n] = make_float4(1.f / (s0 + 1e-16f), 1.f / (s1 + 1e-16f),
                          1.f / (s2 + 1e-16f), 1.f / (s3 + 1e-16f));
}

// ---- layer-2 stats (H=1), scalar version ----
__global__ __launch_bounds__(256) void stats2_kernel(const int* __restrict__ rowptr,
    const int* __restrict__ csr_src, const float* __restrict__ as_,
    const float* __restrict__ ad_, float* __restrict__ w, float* __restrict__ inv,
    int Nn) {
  int wave = (blockIdx.x * blockDim.x + threadIdx.x) >> 6;
  int lane = threadIdx.x & 63;
  if (wave >= Nn) return;
  int n = wave;
  int row = rowptr[n], deg = rowptr[n + 1] - row;
  float adv = ad_[n];
  float m = -1e30f;
  for (int s = lane; s < deg; s += 64) m = fmaxf(m, lrelu(as_[csr_src[row + s]] + adv));
#pragma unroll
  for (int off = 32; off; off >>= 1) m = fmaxf(m, __shfl_xor(m, off));
  float sum = 0.f;
  for (int s = lane; s < deg; s += 64) {
    float p = __expf(lrelu(as_[csr_src[row + s]] + adv) - m);
    sum += p;
    w[row + s] = p;
  }
#pragma unroll
  for (int off = 32; off; off >>= 1) sum += __shfl_xor(sum, off);
  if (lane == 0) inv[n] = 1.f / (sum + 1e-16f);
}

// ---- layer-1 aggregate: one wave per node, lane owns channels 4l..4l+3 ----
// gathers the full 512B src row per edge per wave; unroll 4 for MLP
__global__ __launch_bounds__(256) void aggr1_kernel(const int* __restrict__ rowptr,
    const int* __restrict__ csr_src, const float* __restrict__ w,
    const float* __restrict__ inv, const __hip_bfloat16* __restrict__ h1,
    const float* __restrict__ b1, float* __restrict__ out1, int Nn) {
  int wv = threadIdx.x >> 6, lane = threadIdx.x & 63;
  int n = blockIdx.x * 4 + wv;
  if (n >= Nn) return;
  int row = rowptr[n], deg = rowptr[n + 1] - row;
  int hh = lane >> 4;       // head of this lane's 4 channels
  int c0 = lane * 4;        // first channel
  const unsigned short* hb = (const unsigned short*)h1;
  float a0 = 0.f, a1 = 0.f, a2 = 0.f, a3 = 0.f;
  int s = 0;
  for (; s + 4 <= deg; s += 4) {
    int i0 = csr_src[row + s], i1 = csr_src[row + s + 1];
    int i2 = csr_src[row + s + 2], i3 = csr_src[row + s + 3];
    float w0 = w[(size_t)(row + s) * 4 + hh];
    float w1 = w[(size_t)(row + s + 1) * 4 + hh];
    float w2 = w[(size_t)(row + s + 2) * 4 + hh];
    float w3 = w[(size_t)(row + s + 3) * 4 + hh];
    ushort4 x0 = *(const ushort4*)(hb + (size_t)i0 * 256 + c0);
    ushort4 x1 = *(const ushort4*)(hb + (size_t)i1 * 256 + c0);
    ushort4 x2 = *(const ushort4*)(hb + (size_t)i2 * 256 + c0);
    ushort4 x3 = *(const ushort4*)(hb + (size_t)i3 * 256 + c0);
    a0 = fmaf(w0, b2f(x0.x), a0); a1 = fmaf(w0, b2f(x0.y), a1);
    a2 = fmaf(w0, b2f(x0.z), a2); a3 = fmaf(w0, b2f(x0.w), a3);
    a0 = fmaf(w1, b2f(x1.x), a0); a1 = fmaf(w1, b2f(x1.y), a1);
    a2 = fmaf(w1, b2f(x1.z), a2); a3 = fmaf(w1, b2f(x1.w), a3);
    a0 = fmaf(w2, b2f(x2.x), a0); a1 = fmaf(w2, b2f(x2.y), a1);
    a2 = fmaf(w2, b2f(x2.z), a2); a3 = fmaf(w2, b2f(x2.w), a3);
    a0 = fmaf(w3, b2f(x3.x), a0); a1 = fmaf(w3, b2f(x3.y), a1);
    a2 = fmaf(w3, b2f(x3.z), a2); a3 = fmaf(w3, b2f(x3.w), a3);
  }
  for (; s < deg; s++) {
    int i0 = csr_src[row + s];
    float w0 = w[(size_t)(row + s) * 4 + hh];
    ushort4 x0 = *(const ushort4*)(hb + (size_t)i0 * 256 + c0);
    a0 = fmaf(w0, b2f(x0.x), a0); a1 = fmaf(w0, b2f(x0.y), a1);
    a2 = fmaf(w0, b2f(x0.z), a2); a3 = fmaf(w0, b2f(x0.w), a3);
  }
  float vinv = inv[n * 4 + hh];
  float4 bb = *(const float4*)(b1 + c0);
  float4 r;
  r.x = fmaf(a0, vinv, bb.x); r.y = fmaf(a1, vinv, bb.y);
  r.z = fmaf(a2, vinv, bb.z); r.w = fmaf(a3, vinv, bb.w);
  r.x = r.x > 0.f ? r.x : 0.f; r.y = r.y > 0.f ? r.y : 0.f;
  r.z = r.z > 0.f ? r.z : 0.f; r.w = r.w > 0.f ? r.w : 0.f;
  *(float4*)(out1 + (size_t)n * 256 + c0) = r;
}

// ---- layer-2 aggregate + relu + global mean pool; grid-stride, unroll 4 ----
__global__ __launch_bounds__(256) void aggr2_pool_kernel(const int* __restrict__ rowptr,
    const int* __restrict__ csr_src, const float* __restrict__ w,
    const float* __restrict__ inv, const __hip_bfloat16* __restrict__ h2,
    const float* __restrict__ b2, float* __restrict__ pooled, int Nn) {
  int wv = threadIdx.x >> 6, lane = threadIdx.x & 63;
  const unsigned short* hb = (const unsigned short*)h2 + lane;
  float pacc = 0.f;
  for (int n = blockIdx.x * 4 + wv; n < Nn; n += gridDim.x * 4) {
    int row = rowptr[n], deg = rowptr[n + 1] - row;
    float a0 = 0.f, a1 = 0.f;
    int s = 0;
    for (; s + 4 <= deg; s += 4) {
      int i0 = csr_src[row + s], i1 = csr_src[row + s + 1];
      int i2 = csr_src[row + s + 2], i3 = csr_src[row + s + 3];
      float w0 = w[row + s], w1 = w[row + s + 1];
      float w2 = w[row + s + 2], w3 = w[row + s + 3];
      float x0 = b2f(hb[(size_t)i0 * 64]);
      float x1 = b2f(hb[(size_t)i1 * 64]);
      float x2 = b2f(hb[(size_t)i2 * 64]);
      float x3 = b2f(hb[(size_t)i3 * 64]);
      a0 = fmaf(w0, x0, a0); a1 = fmaf(w1, x1, a1);
      a0 = fmaf(w2, x2, a0); a1 = fmaf(w3, x3, a1);
    }
    for (; s < deg; s++) {
      a0 = fmaf(w[row + s], b2f(hb[(size_t)csr_src[row + s] * 64]), a0);
    }
    float v = (a0 + a1) * inv[n] + b2[lane];
    pacc += v > 0.f ? v : 0.f;
  }
  __shared__ float sred[256];
  sred[threadIdx.x] = pacc;
  __syncthreads();
  if (threadIdx.x < 64)
    atomicAdd(&pooled[threadIdx.x],
              sred[threadIdx.x] + sred[threadIdx.x + 64] + sred[threadIdx.x + 128] +
                  sred[threadIdx.x + 192]);
}

// ---- final fc + log_softmax; single block of 64 threads ----
__global__ void head_kernel(const float* __restrict__ pooled, const float* __restrict__ fc_w,
    const float* __restrict__ fc_b, float* __restrict__ out, float invN) {
  __shared__ float p[64];
  __shared__ float lg[40];
  __shared__ float lse;
  int t = threadIdx.x;
  p[t] = pooled[t] * invN;
  __syncthreads();
  if (t < 40) {
    float s = fc_b[t];
    for (int c = 0; c < 64; c++) s = fmaf(p[c], fc_w[c * 40 + t], s);
    lg[t] = s;
  }
  __syncthreads();
  if (t == 0) {
    float m = -1e30f;
    for (int j = 0; j < 40; j++) m = fmaxf(m, lg[j]);
    float sum = 0.f;
    for (int j = 0; j < 40; j++) sum += expf(lg[j] - m);
    lse = m + logf(sum);
  }
  __syncthreads();
  if (t < 40) out[t] = lg[t] - lse;
}

extern "C" void kernel_launch(void* const* d_in, const int* in_sizes, int n_in,
                              void* d_out, int out_size, void* d_ws, size_t ws_size,
                              hipStream_t stream) {
  const float* x        = (const float*)d_in[0];
  const int*   ei       = (const int*)d_in[1];
  const float* W1       = (const float*)d_in[2];
  const float* att_src1 = (const float*)d_in[3];
  const float* att_dst1 = (const float*)d_in[4];
  const float* b1       = (const float*)d_in[5];
  const float* W2       = (const float*)d_in[6];
  const float* att_src2 = (const float*)d_in[7];
  const float* att_dst2 = (const float*)d_in[8];
  const float* b2       = (const float*)d_in[9];
  const float* fc_w     = (const float*)d_in[10];
  const float* fc_b     = (const float*)d_in[11];
  float* out = (float*)d_out;

  const int N    = in_sizes[0] / 128;  // 50000
  const int E0   = in_sizes[1] / 2;    // 800000
  const int Etot = E0 + N;

  float* ws = (float*)d_ws;
  size_t o = 0;
  __hip_bfloat16* h1 = (__hip_bfloat16*)(ws + o); o += (size_t)N * 128;  // bf16, reused as h2
  __hip_bfloat16* h2 = h1;
  float* out1 = ws + o; o += (size_t)N * 256;
  float* as1  = ws + o; o += (size_t)N * 4;
  float* ad1  = ws + o; o += (size_t)N * 4;
  float* inv1 = ws + o; o += (size_t)N * 4;
  float* w1   = ws + o; o += (size_t)Etot * 4;
  float* as2  = ws + o; o += N;
  float* ad2  = ws + o; o += N;
  float* inv2 = ws + o; o += N;
  float* w2   = ws + o; o += Etot;
  int* degcur = (int*)(ws + o); o += N;
  int* rowptr = (int*)(ws + o); o += N + 1;
  o = (o + 3) & ~(size_t)3;
  int* csr_src = (int*)(ws + o); o += Etot;
  float* pooled = ws + o; o += 64;

  dim3 blk(256);

  // ---- CSR build ----
  deg_init_kernel<<<(N + 255) / 256, blk, 0, stream>>>(degcur, N);
  deg_count_kernel<<<(E0 + 255) / 256, blk, 0, stream>>>(ei, degcur, E0);
  scan_kernel<<<1, 1024, 0, stream>>>(degcur, rowptr, N);
  hipMemcpyAsync(degcur, rowptr, (size_t)N * sizeof(int), hipMemcpyDeviceToDevice, stream);
  scatter_kernel<<<(Etot + 255) / 256, blk, 0, stream>>>(ei, degcur, csr_src, E0, Etot);

  hipMemsetAsync(pooled, 0, 64 * sizeof(float), stream);

  // ---- layer 1 ----
  gemm_tiled<<<dim3(256 / 64, (N + 63) / 64), blk, 0, stream>>>(x, W1, h1, N, 128, 256);
  alpha_kernel<4><<<N, blk, 0, stream>>>(h1, att_src1, att_dst1, as1, ad1, N);
  stats1_kernel<<<(N + 3) / 4, blk, 0, stream>>>(rowptr, csr_src, (const float4*)as1,
                                                 (const float4*)ad1, (float4*)w1,
                                                 (float4*)inv1, N);
  aggr1_kernel<<<(N + 3) / 4, blk, 0, stream>>>(rowptr, csr_src, w1, inv1, h1, b1, out1, N);

  // ---- layer 2 (h2 reuses h1 region; stream-ordered after aggr1) ----
  gemm_tiled<<<dim3(1, (N + 63) / 64), blk, 0, stream>>>(out1, W2, h2, N, 256, 64);
  alpha_kernel<1><<<(N + 3) / 4, blk, 0, stream>>>(h2, att_src2, att_dst2, as2, ad2, N);
  stats2_kernel<<<(N + 3) / 4, blk, 0, stream>>>(rowptr, csr_src, as2, ad2, w2, inv2, N);
  aggr2_pool_kernel<<<1024, blk, 0, stream>>>(rowptr, csr_src, w2, inv2, h2, b2, pooled, N);

  // ---- epilogue ----
  head_kernel<<<1, 64, 0, stream>>>(pooled, fc_w, fc_b, out, 1.0f / (float)N);
}

// Round 5
// 441.892 us; speedup vs baseline: 3.0341x; 1.2557x over previous
//
#include <hip/hip_runtime.h>
#include <hip/hip_bf16.h>
#include <math.h>

#define NEG_SLOPE 0.2f

typedef __attribute__((ext_vector_type(8))) short bf16x8;
typedef __attribute__((ext_vector_type(4))) float f32x4;

__device__ __forceinline__ float lrelu(float a) { return a >= 0.f ? a : NEG_SLOPE * a; }
__device__ __forceinline__ float b2f(unsigned short u) {
  return __uint_as_float(((unsigned)u) << 16);
}
__device__ __forceinline__ unsigned short f2bu(float v) {
  unsigned u = __float_as_uint(v);
  u += 0x7fffu + ((u >> 16) & 1u);  // RNE
  return (unsigned short)(u >> 16);
}

// ---- fused bf16 cast of x, W1, W2 (all sizes divisible by 4) ----
__global__ __launch_bounds__(256) void cast3_kernel(
    const float4* __restrict__ a0, ushort4* __restrict__ d0, int n0,
    const float4* __restrict__ a1, ushort4* __restrict__ d1, int n1,
    const float4* __restrict__ a2, ushort4* __restrict__ d2, int n2) {
  int total = n0 + n1 + n2;
  for (int i = blockIdx.x * blockDim.x + threadIdx.x; i < total; i += gridDim.x * blockDim.x) {
    const float4* s;
    ushort4* d;
    int j = i;
    if (j < n0) { s = a0; d = d0; }
    else if (j < n0 + n1) { j -= n0; s = a1; d = d1; }
    else { j -= n0 + n1; s = a2; d = d2; }
    float4 v = s[j];
    d[j] = make_ushort4(f2bu(v.x), f2bu(v.y), f2bu(v.z), f2bu(v.w));
  }
}

// ---- bf16 MFMA GEMM: C[M,N] = A[M,K] @ B[K,N]; 64x64 tile, K-chunk 32 ----
// A,B,C bf16 bits. K%32==0, N%64==0, M%16==0. Block=256 (4 waves, 2x2 quadrants).
__global__ __launch_bounds__(256) void gemm_mfma(const unsigned short* __restrict__ A,
    const unsigned short* __restrict__ B, unsigned short* __restrict__ C,
    int M, int K, int Ncol) {
  __shared__ unsigned short Al[64][40];  // [m][k], +8 pad: 80B stride, 16B-aligned
  __shared__ unsigned short Bt[64][40];  // [n][k] transposed
  const int tid = threadIdx.x;
  const int row0 = blockIdx.y * 64, col0 = blockIdx.x * 64;
  const int lane = tid & 63, wave = tid >> 6;
  const int wm = wave >> 1, wn = wave & 1;
  const int l15 = lane & 15, q = lane >> 4;

  f32x4 acc[2][2] = {};

  const int am = tid >> 2, ac = (tid & 3) * 8;        // A stage: 64 rows x 4x8 cols
  const int bk = tid >> 3, bn = (tid & 7) * 8;        // B stage: 32 k x 8x8 n

  for (int k0 = 0; k0 < K; k0 += 32) {
    // stage A (zero-fill rows >= M)
    ushort4 av0 = make_ushort4(0, 0, 0, 0), av1 = av0;
    if (row0 + am < M) {
      const ushort4* ap = (const ushort4*)(A + (size_t)(row0 + am) * K + k0 + ac);
      av0 = ap[0]; av1 = ap[1];
    }
    *(ushort4*)&Al[am][ac] = av0;
    *(ushort4*)&Al[am][ac + 4] = av1;
    // stage B transposed
    {
      const ushort4* bp = (const ushort4*)(B + (size_t)(k0 + bk) * Ncol + col0 + bn);
      ushort4 b0 = bp[0], b1 = bp[1];
      Bt[bn + 0][bk] = b0.x; Bt[bn + 1][bk] = b0.y;
      Bt[bn + 2][bk] = b0.z; Bt[bn + 3][bk] = b0.w;
      Bt[bn + 4][bk] = b1.x; Bt[bn + 5][bk] = b1.y;
      Bt[bn + 6][bk] = b1.z; Bt[bn + 7][bk] = b1.w;
    }
    __syncthreads();
    bf16x8 af[2], bf[2];
#pragma unroll
    for (int mi = 0; mi < 2; mi++)
      af[mi] = *(const bf16x8*)&Al[wm * 32 + mi * 16 + l15][q * 8];
#pragma unroll
    for (int ni = 0; ni < 2; ni++)
      bf[ni] = *(const bf16x8*)&Bt[wn * 32 + ni * 16 + l15][q * 8];
#pragma unroll
    for (int mi = 0; mi < 2; mi++)
#pragma unroll
      for (int ni = 0; ni < 2; ni++)
        acc[mi][ni] = __builtin_amdgcn_mfma_f32_16x16x32_bf16(af[mi], bf[ni], acc[mi][ni], 0, 0, 0);
    __syncthreads();
  }
  // epilogue: C row=(lane>>4)*4+r, col=lane&15 within each 16x16
#pragma unroll
  for (int mi = 0; mi < 2; mi++) {
#pragma unroll
    for (int r = 0; r < 4; r++) {
      int grow = row0 + wm * 32 + mi * 16 + q * 4 + r;
      if (grow < M) {
#pragma unroll
        for (int ni = 0; ni < 2; ni++) {
          int gcol = col0 + wn * 32 + ni * 16 + l15;
          C[(size_t)grow * Ncol + gcol] = f2bu(acc[mi][ni][r]);
        }
      }
    }
  }
}

// ---- CSR build ----
__global__ __launch_bounds__(256) void deg_init_kernel(int* __restrict__ deg, int N) {
  int i = blockIdx.x * blockDim.x + threadIdx.x;
  if (i < N) deg[i] = 1;  // self-loop
}

__global__ __launch_bounds__(256) void deg_count_kernel(const int* __restrict__ ei,
    int* __restrict__ deg, int E0) {
  int e = blockIdx.x * blockDim.x + threadIdx.x;
  if (e < E0) atomicAdd(&deg[ei[E0 + e]], 1);
}

// hierarchical scan: per-block partial sums
__global__ __launch_bounds__(256) void scan_partial_kernel(const int* __restrict__ deg,
    int* __restrict__ bsum, int N) {
  __shared__ int s[256];
  int t = threadIdx.x;
  int i = blockIdx.x * 256 + t;
  s[t] = (i < N) ? deg[i] : 0;
  __syncthreads();
  for (int off = 128; off; off >>= 1) {
    if (t < off) s[t] += s[t + off];
    __syncthreads();
  }
  if (t == 0) bsum[blockIdx.x] = s[0];
}

// single-block scan of <=256 partials; writes exclusive offsets + total
__global__ __launch_bounds__(256) void scan_top_kernel(const int* __restrict__ bsum,
    int* __restrict__ boff, int* __restrict__ rowptrN, int NB) {
  __shared__ int s[256];
  int t = threadIdx.x;
  int v = (t < NB) ? bsum[t] : 0;
  s[t] = v;
  __syncthreads();
  for (int off = 1; off < 256; off <<= 1) {
    int u = (t >= off) ? s[t - off] : 0;
    __syncthreads();
    s[t] += u;
    __syncthreads();
  }
  if (t < NB) boff[t] = s[t] - v;
  if (t == 255) *rowptrN = s[255];
}

// final rowptr: in-block exclusive scan + block offset
__global__ __launch_bounds__(256) void scan_final_kernel(const int* __restrict__ deg,
    const int* __restrict__ boff, int* __restrict__ rowptr, int N) {
  __shared__ int s[256];
  int t = threadIdx.x;
  int i = blockIdx.x * 256 + t;
  int v = (i < N) ? deg[i] : 0;
  s[t] = v;
  __syncthreads();
  for (int off = 1; off < 256; off <<= 1) {
    int u = (t >= off) ? s[t - off] : 0;
    __syncthreads();
    s[t] += u;
    __syncthreads();
  }
  if (i < N) rowptr[i] = boff[blockIdx.x] + s[t] - v;
}

__global__ __launch_bounds__(256) void scatter_kernel(const int* __restrict__ ei,
    int* __restrict__ cursor, int* __restrict__ csr_src, int E0, int Etot) {
  int e = blockIdx.x * blockDim.x + threadIdx.x;
  if (e >= Etot) return;
  int src, dst;
  if (e < E0) { src = ei[e]; dst = ei[E0 + e]; } else { src = e - E0; dst = src; }
  int pos = atomicAdd(&cursor[dst], 1);
  csr_src[pos] = src;
}

// ---- per-(node,head) attention coefficients (bf16 h); one wave per (n,h) ----
template <int H>
__global__ __launch_bounds__(256) void alpha_kernel(const __hip_bfloat16* __restrict__ h,
    const float* __restrict__ att_s, const float* __restrict__ att_d,
    float* __restrict__ as_, float* __restrict__ ad_, int Nn) {
  int wave = (blockIdx.x * blockDim.x + threadIdx.x) >> 6;
  int lane = threadIdx.x & 63;
  if (wave >= Nn * H) return;
  int n = wave / H, hh = wave % H;
  float hv = __bfloat162float(h[(size_t)n * (H * 64) + hh * 64 + lane]);
  float vs = hv * att_s[hh * 64 + lane];
  float vd = hv * att_d[hh * 64 + lane];
  for (int off = 32; off; off >>= 1) {
    vs += __shfl_down(vs, off);
    vd += __shfl_down(vd, off);
  }
  if (lane == 0) { as_[wave] = vs; ad_[wave] = vd; }
}

// ---- layer-1 softmax stats + edge weights (unnormalized p, per-node inv) ----
__global__ __launch_bounds__(256) void stats1_kernel(const int* __restrict__ rowptr,
    const int* __restrict__ csr_src, const float4* __restrict__ as4,
    const float4* __restrict__ ad4, float4* __restrict__ w4,
    float4* __restrict__ inv4, int Nn) {
  int wave = (blockIdx.x * blockDim.x + threadIdx.x) >> 6;
  int lane = threadIdx.x & 63;
  if (wave >= Nn) return;
  int n = wave;
  int row = rowptr[n], deg = rowptr[n + 1] - row;
  float4 adv = ad4[n];
  float m0 = -1e30f, m1 = -1e30f, m2 = -1e30f, m3 = -1e30f;
  for (int s = lane; s < deg; s += 64) {
    int src = csr_src[row + s];
    float4 a = as4[src];
    m0 = fmaxf(m0, lrelu(a.x + adv.x));
    m1 = fmaxf(m1, lrelu(a.y + adv.y));
    m2 = fmaxf(m2, lrelu(a.z + adv.z));
    m3 = fmaxf(m3, lrelu(a.w + adv.w));
  }
#pragma unroll
  for (int off = 32; off; off >>= 1) {
    m0 = fmaxf(m0, __shfl_xor(m0, off));
    m1 = fmaxf(m1, __shfl_xor(m1, off));
    m2 = fmaxf(m2, __shfl_xor(m2, off));
    m3 = fmaxf(m3, __shfl_xor(m3, off));
  }
  float s0 = 0.f, s1 = 0.f, s2 = 0.f, s3 = 0.f;
  for (int s = lane; s < deg; s += 64) {
    int src = csr_src[row + s];
    float4 a = as4[src];
    float p0 = __expf(lrelu(a.x + adv.x) - m0);
    float p1 = __expf(lrelu(a.y + adv.y) - m1);
    float p2 = __expf(lrelu(a.z + adv.z) - m2);
    float p3 = __expf(lrelu(a.w + adv.w) - m3);
    s0 += p0; s1 += p1; s2 += p2; s3 += p3;
    w4[row + s] = make_float4(p0, p1, p2, p3);
  }
#pragma unroll
  for (int off = 32; off; off >>= 1) {
    s0 += __shfl_xor(s0, off);
    s1 += __shfl_xor(s1, off);
    s2 += __shfl_xor(s2, off);
    s3 += __shfl_xor(s3, off);
  }
  if (lane == 0)
    inv4[n] = make_float4(1.f / (s0 + 1e-16f), 1.f / (s1 + 1e-16f),
                          1.f / (s2 + 1e-16f), 1.f / (s3 + 1e-16f));
}

// ---- layer-2 stats (H=1), scalar version ----
__global__ __launch_bounds__(256) void stats2_kernel(const int* __restrict__ rowptr,
    const int* __restrict__ csr_src, const float* __restrict__ as_,
    const float* __restrict__ ad_, float* __restrict__ w, float* __restrict__ inv,
    int Nn) {
  int wave = (blockIdx.x * blockDim.x + threadIdx.x) >> 6;
  int lane = threadIdx.x & 63;
  if (wave >= Nn) return;
  int n = wave;
  int row = rowptr[n], deg = rowptr[n + 1] - row;
  float adv = ad_[n];
  float m = -1e30f;
  for (int s = lane; s < deg; s += 64) m = fmaxf(m, lrelu(as_[csr_src[row + s]] + adv));
#pragma unroll
  for (int off = 32; off; off >>= 1) m = fmaxf(m, __shfl_xor(m, off));
  float sum = 0.f;
  for (int s = lane; s < deg; s += 64) {
    float p = __expf(lrelu(as_[csr_src[row + s]] + adv) - m);
    sum += p;
    w[row + s] = p;
  }
#pragma unroll
  for (int off = 32; off; off >>= 1) sum += __shfl_xor(sum, off);
  if (lane == 0) inv[n] = 1.f / (sum + 1e-16f);
}

// ---- layer-1 aggregate: one wave per node, lane owns channels 4l..4l+3 ----
// bf16 output (feeds gemm_mfma for layer 2)
__global__ __launch_bounds__(256) void aggr1_kernel(const int* __restrict__ rowptr,
    const int* __restrict__ csr_src, const float* __restrict__ w,
    const float* __restrict__ inv, const __hip_bfloat16* __restrict__ h1,
    const float* __restrict__ b1, unsigned short* __restrict__ out1, int Nn) {
  int wv = threadIdx.x >> 6, lane = threadIdx.x & 63;
  int n = blockIdx.x * 4 + wv;
  if (n >= Nn) return;
  int row = rowptr[n], deg = rowptr[n + 1] - row;
  int hh = lane >> 4;
  int c0 = lane * 4;
  const unsigned short* hb = (const unsigned short*)h1;
  float a0 = 0.f, a1 = 0.f, a2 = 0.f, a3 = 0.f;
  int s = 0;
  for (; s + 4 <= deg; s += 4) {
    int i0 = csr_src[row + s], i1 = csr_src[row + s + 1];
    int i2 = csr_src[row + s + 2], i3 = csr_src[row + s + 3];
    float w0 = w[(size_t)(row + s) * 4 + hh];
    float w1 = w[(size_t)(row + s + 1) * 4 + hh];
    float w2 = w[(size_t)(row + s + 2) * 4 + hh];
    float w3 = w[(size_t)(row + s + 3) * 4 + hh];
    ushort4 x0 = *(const ushort4*)(hb + (size_t)i0 * 256 + c0);
    ushort4 x1 = *(const ushort4*)(hb + (size_t)i1 * 256 + c0);
    ushort4 x2 = *(const ushort4*)(hb + (size_t)i2 * 256 + c0);
    ushort4 x3 = *(const ushort4*)(hb + (size_t)i3 * 256 + c0);
    a0 = fmaf(w0, b2f(x0.x), a0); a1 = fmaf(w0, b2f(x0.y), a1);
    a2 = fmaf(w0, b2f(x0.z), a2); a3 = fmaf(w0, b2f(x0.w), a3);
    a0 = fmaf(w1, b2f(x1.x), a0); a1 = fmaf(w1, b2f(x1.y), a1);
    a2 = fmaf(w1, b2f(x1.z), a2); a3 = fmaf(w1, b2f(x1.w), a3);
    a0 = fmaf(w2, b2f(x2.x), a0); a1 = fmaf(w2, b2f(x2.y), a1);
    a2 = fmaf(w2, b2f(x2.z), a2); a3 = fmaf(w2, b2f(x2.w), a3);
    a0 = fmaf(w3, b2f(x3.x), a0); a1 = fmaf(w3, b2f(x3.y), a1);
    a2 = fmaf(w3, b2f(x3.z), a2); a3 = fmaf(w3, b2f(x3.w), a3);
  }
  for (; s < deg; s++) {
    int i0 = csr_src[row + s];
    float w0 = w[(size_t)(row + s) * 4 + hh];
    ushort4 x0 = *(const ushort4*)(hb + (size_t)i0 * 256 + c0);
    a0 = fmaf(w0, b2f(x0.x), a0); a1 = fmaf(w0, b2f(x0.y), a1);
    a2 = fmaf(w0, b2f(x0.z), a2); a3 = fmaf(w0, b2f(x0.w), a3);
  }
  float vinv = inv[n * 4 + hh];
  float4 bb = *(const float4*)(b1 + c0);
  float rx = fmaf(a0, vinv, bb.x), ry = fmaf(a1, vinv, bb.y);
  float rz = fmaf(a2, vinv, bb.z), rw = fmaf(a3, vinv, bb.w);
  rx = rx > 0.f ? rx : 0.f; ry = ry > 0.f ? ry : 0.f;
  rz = rz > 0.f ? rz : 0.f; rw = rw > 0.f ? rw : 0.f;
  *(ushort4*)(out1 + (size_t)n * 256 + c0) =
      make_ushort4(f2bu(rx), f2bu(ry), f2bu(rz), f2bu(rw));
}

// ---- layer-2 aggregate + relu + global mean pool; grid-stride, unroll 4 ----
__global__ __launch_bounds__(256) void aggr2_pool_kernel(const int* __restrict__ rowptr,
    const int* __restrict__ csr_src, const float* __restrict__ w,
    const float* __restrict__ inv, const __hip_bfloat16* __restrict__ h2,
    const float* __restrict__ b2, float* __restrict__ pooled, int Nn) {
  int wv = threadIdx.x >> 6, lane = threadIdx.x & 63;
  const unsigned short* hb = (const unsigned short*)h2 + lane;
  float pacc = 0.f;
  for (int n = blockIdx.x * 4 + wv; n < Nn; n += gridDim.x * 4) {
    int row = rowptr[n], deg = rowptr[n + 1] - row;
    float a0 = 0.f, a1 = 0.f;
    int s = 0;
    for (; s + 4 <= deg; s += 4) {
      int i0 = csr_src[row + s], i1 = csr_src[row + s + 1];
      int i2 = csr_src[row + s + 2], i3 = csr_src[row + s + 3];
      float w0 = w[row + s], w1 = w[row + s + 1];
      float w2 = w[row + s + 2], w3 = w[row + s + 3];
      float x0 = b2f(hb[(size_t)i0 * 64]);
      float x1 = b2f(hb[(size_t)i1 * 64]);
      float x2 = b2f(hb[(size_t)i2 * 64]);
      float x3 = b2f(hb[(size_t)i3 * 64]);
      a0 = fmaf(w0, x0, a0); a1 = fmaf(w1, x1, a1);
      a0 = fmaf(w2, x2, a0); a1 = fmaf(w3, x3, a1);
    }
    for (; s < deg; s++) {
      a0 = fmaf(w[row + s], b2f(hb[(size_t)csr_src[row + s] * 64]), a0);
    }
    float v = (a0 + a1) * inv[n] + b2[lane];
    pacc += v > 0.f ? v : 0.f;
  }
  __shared__ float sred[256];
  sred[threadIdx.x] = pacc;
  __syncthreads();
  if (threadIdx.x < 64)
    atomicAdd(&pooled[threadIdx.x],
              sred[threadIdx.x] + sred[threadIdx.x + 64] + sred[threadIdx.x + 128] +
                  sred[threadIdx.x + 192]);
}

// ---- final fc + log_softmax; single block of 64 threads ----
__global__ void head_kernel(const float* __restrict__ pooled, const float* __restrict__ fc_w,
    const float* __restrict__ fc_b, float* __restrict__ out, float invN) {
  __shared__ float p[64];
  __shared__ float lg[40];
  __shared__ float lse;
  int t = threadIdx.x;
  p[t] = pooled[t] * invN;
  __syncthreads();
  if (t < 40) {
    float s = fc_b[t];
    for (int c = 0; c < 64; c++) s = fmaf(p[c], fc_w[c * 40 + t], s);
    lg[t] = s;
  }
  __syncthreads();
  if (t == 0) {
    float m = -1e30f;
    for (int j = 0; j < 40; j++) m = fmaxf(m, lg[j]);
    float sum = 0.f;
    for (int j = 0; j < 40; j++) sum += expf(lg[j] - m);
    lse = m + logf(sum);
  }
  __syncthreads();
  if (t < 40) out[t] = lg[t] - lse;
}

extern "C" void kernel_launch(void* const* d_in, const int* in_sizes, int n_in,
                              void* d_out, int out_size, void* d_ws, size_t ws_size,
                              hipStream_t stream) {
  const float* x        = (const float*)d_in[0];
  const int*   ei       = (const int*)d_in[1];
  const float* W1       = (const float*)d_in[2];
  const float* att_src1 = (const float*)d_in[3];
  const float* att_dst1 = (const float*)d_in[4];
  const float* b1       = (const float*)d_in[5];
  const float* W2       = (const float*)d_in[6];
  const float* att_src2 = (const float*)d_in[7];
  const float* att_dst2 = (const float*)d_in[8];
  const float* b2       = (const float*)d_in[9];
  const float* fc_w     = (const float*)d_in[10];
  const float* fc_b     = (const float*)d_in[11];
  float* out = (float*)d_out;

  const int N    = in_sizes[0] / 128;  // 50000
  const int E0   = in_sizes[1] / 2;    // 800000
  const int Etot = E0 + N;
  const int NB   = (N + 255) / 256;    // scan blocks

  char* wsb = (char*)d_ws;
  size_t o = 0;
  auto alloc = [&](size_t bytes) { char* p = wsb + o; o += (bytes + 15) & ~(size_t)15; return p; };
  unsigned short* xb   = (unsigned short*)alloc((size_t)N * 128 * 2);
  unsigned short* w1b  = (unsigned short*)alloc(128 * 256 * 2);
  unsigned short* w2b  = (unsigned short*)alloc(256 * 64 * 2);
  unsigned short* h1   = (unsigned short*)alloc((size_t)N * 256 * 2);  // bf16; reused as h2
  unsigned short* h2   = h1;
  unsigned short* out1 = (unsigned short*)alloc((size_t)N * 256 * 2);  // bf16
  float* as1  = (float*)alloc((size_t)N * 4 * 4);
  float* ad1  = (float*)alloc((size_t)N * 4 * 4);
  float* inv1 = (float*)alloc((size_t)N * 4 * 4);
  float* w1e  = (float*)alloc((size_t)Etot * 4 * 4);
  float* as2  = (float*)alloc((size_t)N * 4);
  float* ad2  = (float*)alloc((size_t)N * 4);
  float* inv2 = (float*)alloc((size_t)N * 4);
  float* w2e  = (float*)alloc((size_t)Etot * 4);
  int* degcur = (int*)alloc((size_t)N * 4);
  int* rowptr = (int*)alloc((size_t)(N + 1) * 4);
  int* bsum   = (int*)alloc(256 * 4);
  int* boff   = (int*)alloc(256 * 4);
  int* csr_src = (int*)alloc((size_t)Etot * 4);
  float* pooled = (float*)alloc(64 * 4);

  dim3 blk(256);

  // ---- bf16 casts ----
  cast3_kernel<<<512, blk, 0, stream>>>(
      (const float4*)x, (ushort4*)xb, N * 128 / 4,
      (const float4*)W1, (ushort4*)w1b, 128 * 256 / 4,
      (const float4*)W2, (ushort4*)w2b, 256 * 64 / 4);

  // ---- CSR build ----
  deg_init_kernel<<<(N + 255) / 256, blk, 0, stream>>>(degcur, N);
  deg_count_kernel<<<(E0 + 255) / 256, blk, 0, stream>>>(ei, degcur, E0);
  scan_partial_kernel<<<NB, blk, 0, stream>>>(degcur, bsum, N);
  scan_top_kernel<<<1, blk, 0, stream>>>(bsum, boff, rowptr + N, NB);
  scan_final_kernel<<<NB, blk, 0, stream>>>(degcur, boff, rowptr, N);
  hipMemcpyAsync(degcur, rowptr, (size_t)N * sizeof(int), hipMemcpyDeviceToDevice, stream);
  scatter_kernel<<<(Etot + 255) / 256, blk, 0, stream>>>(ei, degcur, csr_src, E0, Etot);

  hipMemsetAsync(pooled, 0, 64 * sizeof(float), stream);

  // ---- layer 1 ----
  gemm_mfma<<<dim3(4, (N + 63) / 64), blk, 0, stream>>>(xb, w1b, h1, N, 128, 256);
  alpha_kernel<4><<<N, blk, 0, stream>>>((const __hip_bfloat16*)h1, att_src1, att_dst1, as1, ad1, N);
  stats1_kernel<<<(N + 3) / 4, blk, 0, stream>>>(rowptr, csr_src, (const float4*)as1,
                                                 (const float4*)ad1, (float4*)w1e,
                                                 (float4*)inv1, N);
  aggr1_kernel<<<(N + 3) / 4, blk, 0, stream>>>(rowptr, csr_src, w1e, inv1,
                                                (const __hip_bfloat16*)h1, b1, out1, N);

  // ---- layer 2 (h2 reuses h1 region; stream-ordered after aggr1) ----
  gemm_mfma<<<dim3(1, (N + 63) / 64), blk, 0, stream>>>(out1, w2b, h2, N, 256, 64);
  alpha_kernel<1><<<(N + 3) / 4, blk, 0, stream>>>((const __hip_bfloat16*)h2, att_src2, att_dst2,
                                                   as2, ad2, N);
  stats2_kernel<<<(N + 3) / 4, blk, 0, stream>>>(rowptr, csr_src, as2, ad2, w2e, inv2, N);
  aggr2_pool_kernel<<<1024, blk, 0, stream>>>(rowptr, csr_src, w2e, inv2,
                                              (const __hip_bfloat16*)h2, b2, pooled, N);

  // ---- epilogue ----
  head_kernel<<<1, 64, 0, stream>>>(pooled, fc_w, fc_b, out, 1.0f / (float)N);
}

// Round 6
// 431.072 us; speedup vs baseline: 3.1103x; 1.0251x over previous
//
#include <hip/hip_runtime.h>
#include <hip/hip_bf16.h>
#include <math.h>

#define NEG_SLOPE 0.2f

typedef __attribute__((ext_vector_type(8))) short bf16x8;
typedef __attribute__((ext_vector_type(4))) float f32x4;

__device__ __forceinline__ float lrelu(float a) { return a >= 0.f ? a : NEG_SLOPE * a; }
__device__ __forceinline__ float b2f(unsigned short u) {
  return __uint_as_float(((unsigned)u) << 16);
}
__device__ __forceinline__ unsigned short f2bu(float v) {
  unsigned u = __float_as_uint(v);
  u += 0x7fffu + ((u >> 16) & 1u);  // RNE
  return (unsigned short)(u >> 16);
}

// ---- fused bf16 cast of x, W1, W2 (all sizes divisible by 4) ----
__global__ __launch_bounds__(256) void cast3_kernel(
    const float4* __restrict__ a0, ushort4* __restrict__ d0, int n0,
    const float4* __restrict__ a1, ushort4* __restrict__ d1, int n1,
    const float4* __restrict__ a2, ushort4* __restrict__ d2, int n2) {
  int total = n0 + n1 + n2;
  for (int i = blockIdx.x * blockDim.x + threadIdx.x; i < total; i += gridDim.x * blockDim.x) {
    const float4* s;
    ushort4* d;
    int j = i;
    if (j < n0) { s = a0; d = d0; }
    else if (j < n0 + n1) { j -= n0; s = a1; d = d1; }
    else { j -= n0 + n1; s = a2; d = d2; }
    float4 v = s[j];
    d[j] = make_ushort4(f2bu(v.x), f2bu(v.y), f2bu(v.z), f2bu(v.w));
  }
}

// ---- bf16 MFMA GEMM: C[M,N] = A[M,K] @ B[K,N]; 64x64 tile, K-chunk 32 ----
__global__ __launch_bounds__(256) void gemm_mfma(const unsigned short* __restrict__ A,
    const unsigned short* __restrict__ B, unsigned short* __restrict__ C,
    int M, int K, int Ncol) {
  __shared__ unsigned short Al[64][40];
  __shared__ unsigned short Bt[64][40];
  const int tid = threadIdx.x;
  const int row0 = blockIdx.y * 64, col0 = blockIdx.x * 64;
  const int lane = tid & 63, wave = tid >> 6;
  const int wm = wave >> 1, wn = wave & 1;
  const int l15 = lane & 15, q = lane >> 4;

  f32x4 acc[2][2] = {};

  const int am = tid >> 2, ac = (tid & 3) * 8;
  const int bk = tid >> 3, bn = (tid & 7) * 8;

  for (int k0 = 0; k0 < K; k0 += 32) {
    ushort4 av0 = make_ushort4(0, 0, 0, 0), av1 = av0;
    if (row0 + am < M) {
      const ushort4* ap = (const ushort4*)(A + (size_t)(row0 + am) * K + k0 + ac);
      av0 = ap[0]; av1 = ap[1];
    }
    *(ushort4*)&Al[am][ac] = av0;
    *(ushort4*)&Al[am][ac + 4] = av1;
    {
      const ushort4* bp = (const ushort4*)(B + (size_t)(k0 + bk) * Ncol + col0 + bn);
      ushort4 b0 = bp[0], b1 = bp[1];
      Bt[bn + 0][bk] = b0.x; Bt[bn + 1][bk] = b0.y;
      Bt[bn + 2][bk] = b0.z; Bt[bn + 3][bk] = b0.w;
      Bt[bn + 4][bk] = b1.x; Bt[bn + 5][bk] = b1.y;
      Bt[bn + 6][bk] = b1.z; Bt[bn + 7][bk] = b1.w;
    }
    __syncthreads();
    bf16x8 af[2], bf[2];
#pragma unroll
    for (int mi = 0; mi < 2; mi++)
      af[mi] = *(const bf16x8*)&Al[wm * 32 + mi * 16 + l15][q * 8];
#pragma unroll
    for (int ni = 0; ni < 2; ni++)
      bf[ni] = *(const bf16x8*)&Bt[wn * 32 + ni * 16 + l15][q * 8];
#pragma unroll
    for (int mi = 0; mi < 2; mi++)
#pragma unroll
      for (int ni = 0; ni < 2; ni++)
        acc[mi][ni] = __builtin_amdgcn_mfma_f32_16x16x32_bf16(af[mi], bf[ni], acc[mi][ni], 0, 0, 0);
    __syncthreads();
  }
#pragma unroll
  for (int mi = 0; mi < 2; mi++) {
#pragma unroll
    for (int r = 0; r < 4; r++) {
      int grow = row0 + wm * 32 + mi * 16 + q * 4 + r;
      if (grow < M) {
#pragma unroll
        for (int ni = 0; ni < 2; ni++) {
          int gcol = col0 + wn * 32 + ni * 16 + l15;
          C[(size_t)grow * Ncol + gcol] = f2bu(acc[mi][ni][r]);
        }
      }
    }
  }
}

// ---- CSR build ----
__global__ __launch_bounds__(256) void deg_init_kernel(int* __restrict__ deg, int N) {
  int i = blockIdx.x * blockDim.x + threadIdx.x;
  if (i < N) deg[i] = 1;  // self-loop
}

__global__ __launch_bounds__(256) void deg_count_kernel(const int* __restrict__ ei,
    int* __restrict__ deg, int E0) {
  int e = blockIdx.x * blockDim.x + threadIdx.x;
  if (e < E0) atomicAdd(&deg[ei[E0 + e]], 1);
}

__global__ __launch_bounds__(256) void scan_partial_kernel(const int* __restrict__ deg,
    int* __restrict__ bsum, int N) {
  __shared__ int s[256];
  int t = threadIdx.x;
  int i = blockIdx.x * 256 + t;
  s[t] = (i < N) ? deg[i] : 0;
  __syncthreads();
  for (int off = 128; off; off >>= 1) {
    if (t < off) s[t] += s[t + off];
    __syncthreads();
  }
  if (t == 0) bsum[blockIdx.x] = s[0];
}

__global__ __launch_bounds__(256) void scan_top_kernel(const int* __restrict__ bsum,
    int* __restrict__ boff, int* __restrict__ rowptrN, int NB) {
  __shared__ int s[256];
  int t = threadIdx.x;
  int v = (t < NB) ? bsum[t] : 0;
  s[t] = v;
  __syncthreads();
  for (int off = 1; off < 256; off <<= 1) {
    int u = (t >= off) ? s[t - off] : 0;
    __syncthreads();
    s[t] += u;
    __syncthreads();
  }
  if (t < NB) boff[t] = s[t] - v;
  if (t == 255) *rowptrN = s[255];
}

__global__ __launch_bounds__(256) void scan_final_kernel(const int* __restrict__ deg,
    const int* __restrict__ boff, int* __restrict__ rowptr, int N) {
  __shared__ int s[256];
  int t = threadIdx.x;
  int i = blockIdx.x * 256 + t;
  int v = (i < N) ? deg[i] : 0;
  s[t] = v;
  __syncthreads();
  for (int off = 1; off < 256; off <<= 1) {
    int u = (t >= off) ? s[t - off] : 0;
    __syncthreads();
    s[t] += u;
    __syncthreads();
  }
  if (i < N) rowptr[i] = boff[blockIdx.x] + s[t] - v;
}

__global__ __launch_bounds__(256) void scatter_kernel(const int* __restrict__ ei,
    int* __restrict__ cursor, int* __restrict__ csr_src, int E0, int Etot) {
  int e = blockIdx.x * blockDim.x + threadIdx.x;
  if (e >= Etot) return;
  int src, dst;
  if (e < E0) { src = ei[e]; dst = ei[E0 + e]; } else { src = e - E0; dst = src; }
  int pos = atomicAdd(&cursor[dst], 1);
  csr_src[pos] = src;
}

// ---- per-(node,head) attention coefficients (bf16 h); one wave per (n,h) ----
template <int H>
__global__ __launch_bounds__(256) void alpha_kernel(const __hip_bfloat16* __restrict__ h,
    const float* __restrict__ att_s, const float* __restrict__ att_d,
    float* __restrict__ as_, float* __restrict__ ad_, int Nn) {
  int wave = (blockIdx.x * blockDim.x + threadIdx.x) >> 6;
  int lane = threadIdx.x & 63;
  if (wave >= Nn * H) return;
  int n = wave / H, hh = wave % H;
  float hv = __bfloat162float(h[(size_t)n * (H * 64) + hh * 64 + lane]);
  float vs = hv * att_s[hh * 64 + lane];
  float vd = hv * att_d[hh * 64 + lane];
  for (int off = 32; off; off >>= 1) {
    vs += __shfl_down(vs, off);
    vd += __shfl_down(vd, off);
  }
  if (lane == 0) { as_[wave] = vs; ad_[wave] = vd; }
}

// ---- layer-1 softmax stats + edge weights ----
__global__ __launch_bounds__(256) void stats1_kernel(const int* __restrict__ rowptr,
    const int* __restrict__ csr_src, const float4* __restrict__ as4,
    const float4* __restrict__ ad4, float4* __restrict__ w4,
    float4* __restrict__ inv4, int Nn) {
  int wave = (blockIdx.x * blockDim.x + threadIdx.x) >> 6;
  int lane = threadIdx.x & 63;
  if (wave >= Nn) return;
  int n = wave;
  int row = rowptr[n], deg = rowptr[n + 1] - row;
  float4 adv = ad4[n];
  float m0 = -1e30f, m1 = -1e30f, m2 = -1e30f, m3 = -1e30f;
  for (int s = lane; s < deg; s += 64) {
    int src = csr_src[row + s];
    float4 a = as4[src];
    m0 = fmaxf(m0, lrelu(a.x + adv.x));
    m1 = fmaxf(m1, lrelu(a.y + adv.y));
    m2 = fmaxf(m2, lrelu(a.z + adv.z));
    m3 = fmaxf(m3, lrelu(a.w + adv.w));
  }
#pragma unroll
  for (int off = 32; off; off >>= 1) {
    m0 = fmaxf(m0, __shfl_xor(m0, off));
    m1 = fmaxf(m1, __shfl_xor(m1, off));
    m2 = fmaxf(m2, __shfl_xor(m2, off));
    m3 = fmaxf(m3, __shfl_xor(m3, off));
  }
  float s0 = 0.f, s1 = 0.f, s2 = 0.f, s3 = 0.f;
  for (int s = lane; s < deg; s += 64) {
    int src = csr_src[row + s];
    float4 a = as4[src];
    float p0 = __expf(lrelu(a.x + adv.x) - m0);
    float p1 = __expf(lrelu(a.y + adv.y) - m1);
    float p2 = __expf(lrelu(a.z + adv.z) - m2);
    float p3 = __expf(lrelu(a.w + adv.w) - m3);
    s0 += p0; s1 += p1; s2 += p2; s3 += p3;
    w4[row + s] = make_float4(p0, p1, p2, p3);
  }
#pragma unroll
  for (int off = 32; off; off >>= 1) {
    s0 += __shfl_xor(s0, off);
    s1 += __shfl_xor(s1, off);
    s2 += __shfl_xor(s2, off);
    s3 += __shfl_xor(s3, off);
  }
  if (lane == 0)
    inv4[n] = make_float4(1.f / (s0 + 1e-16f), 1.f / (s1 + 1e-16f),
                          1.f / (s2 + 1e-16f), 1.f / (s3 + 1e-16f));
}

// ---- layer-2 stats (H=1) ----
__global__ __launch_bounds__(256) void stats2_kernel(const int* __restrict__ rowptr,
    const int* __restrict__ csr_src, const float* __restrict__ as_,
    const float* __restrict__ ad_, float* __restrict__ w, float* __restrict__ inv,
    int Nn) {
  int wave = (blockIdx.x * blockDim.x + threadIdx.x) >> 6;
  int lane = threadIdx.x & 63;
  if (wave >= Nn) return;
  int n = wave;
  int row = rowptr[n], deg = rowptr[n + 1] - row;
  float adv = ad_[n];
  float m = -1e30f;
  for (int s = lane; s < deg; s += 64) m = fmaxf(m, lrelu(as_[csr_src[row + s]] + adv));
#pragma unroll
  for (int off = 32; off; off >>= 1) m = fmaxf(m, __shfl_xor(m, off));
  float sum = 0.f;
  for (int s = lane; s < deg; s += 64) {
    float p = __expf(lrelu(as_[csr_src[row + s]] + adv) - m);
    sum += p;
    w[row + s] = p;
  }
#pragma unroll
  for (int off = 32; off; off >>= 1) sum += __shfl_xor(sum, off);
  if (lane == 0) inv[n] = 1.f / (sum + 1e-16f);
}

// ---- layer-1 aggregate: one wave per node, lane owns channels 4l..4l+3 ----
__global__ __launch_bounds__(256) void aggr1_kernel(const int* __restrict__ rowptr,
    const int* __restrict__ csr_src, const float* __restrict__ w,
    const float* __restrict__ inv, const __hip_bfloat16* __restrict__ h1,
    const float* __restrict__ b1, unsigned short* __restrict__ out1, int Nn) {
  int wv = threadIdx.x >> 6, lane = threadIdx.x & 63;
  int n = blockIdx.x * 4 + wv;
  if (n >= Nn) return;
  int row = rowptr[n], deg = rowptr[n + 1] - row;
  int hh = lane >> 4;
  int c0 = lane * 4;
  const unsigned short* hb = (const unsigned short*)h1;
  float a0 = 0.f, a1 = 0.f, a2 = 0.f, a3 = 0.f;
  int s = 0;
  for (; s + 4 <= deg; s += 4) {
    int i0 = csr_src[row + s], i1 = csr_src[row + s + 1];
    int i2 = csr_src[row + s + 2], i3 = csr_src[row + s + 3];
    float w0 = w[(size_t)(row + s) * 4 + hh];
    float w1 = w[(size_t)(row + s + 1) * 4 + hh];
    float w2 = w[(size_t)(row + s + 2) * 4 + hh];
    float w3 = w[(size_t)(row + s + 3) * 4 + hh];
    ushort4 x0 = *(const ushort4*)(hb + (size_t)i0 * 256 + c0);
    ushort4 x1 = *(const ushort4*)(hb + (size_t)i1 * 256 + c0);
    ushort4 x2 = *(const ushort4*)(hb + (size_t)i2 * 256 + c0);
    ushort4 x3 = *(const ushort4*)(hb + (size_t)i3 * 256 + c0);
    a0 = fmaf(w0, b2f(x0.x), a0); a1 = fmaf(w0, b2f(x0.y), a1);
    a2 = fmaf(w0, b2f(x0.z), a2); a3 = fmaf(w0, b2f(x0.w), a3);
    a0 = fmaf(w1, b2f(x1.x), a0); a1 = fmaf(w1, b2f(x1.y), a1);
    a2 = fmaf(w1, b2f(x1.z), a2); a3 = fmaf(w1, b2f(x1.w), a3);
    a0 = fmaf(w2, b2f(x2.x), a0); a1 = fmaf(w2, b2f(x2.y), a1);
    a2 = fmaf(w2, b2f(x2.z), a2); a3 = fmaf(w2, b2f(x2.w), a3);
    a0 = fmaf(w3, b2f(x3.x), a0); a1 = fmaf(w3, b2f(x3.y), a1);
    a2 = fmaf(w3, b2f(x3.z), a2); a3 = fmaf(w3, b2f(x3.w), a3);
  }
  for (; s < deg; s++) {
    int i0 = csr_src[row + s];
    float w0 = w[(size_t)(row + s) * 4 + hh];
    ushort4 x0 = *(const ushort4*)(hb + (size_t)i0 * 256 + c0);
    a0 = fmaf(w0, b2f(x0.x), a0); a1 = fmaf(w0, b2f(x0.y), a1);
    a2 = fmaf(w0, b2f(x0.z), a2); a3 = fmaf(w0, b2f(x0.w), a3);
  }
  float vinv = inv[n * 4 + hh];
  float4 bb = *(const float4*)(b1 + c0);
  float rx = fmaf(a0, vinv, bb.x), ry = fmaf(a1, vinv, bb.y);
  float rz = fmaf(a2, vinv, bb.z), rw = fmaf(a3, vinv, bb.w);
  rx = rx > 0.f ? rx : 0.f; ry = ry > 0.f ? ry : 0.f;
  rz = rz > 0.f ? rz : 0.f; rw = rw > 0.f ? rw : 0.f;
  *(ushort4*)(out1 + (size_t)n * 256 + c0) =
      make_ushort4(f2bu(rx), f2bu(ry), f2bu(rz), f2bu(rw));
}

// ---- layer-2 aggregate + relu + pool partials ----
// quarter-wave per node: lane l15 owns channels 4*l15..4*l15+3 (ushort4 gather);
// 4 quarters/wave x 4 waves/block = 16 node streams per block.
__global__ __launch_bounds__(256) void aggr2_pool_kernel(const int* __restrict__ rowptr,
    const int* __restrict__ csr_src, const float* __restrict__ w,
    const float* __restrict__ inv, const unsigned short* __restrict__ h2,
    const float* __restrict__ b2, float4* __restrict__ partial, int Nn) {
  int lane = threadIdx.x & 63, wv = threadIdx.x >> 6;
  int q = lane >> 4, l15 = lane & 15;
  int c0 = l15 * 4;
  const unsigned short* hb = h2 + c0;
  float p0 = 0.f, p1 = 0.f, p2 = 0.f, p3 = 0.f;
  int stream = (blockIdx.x * 4 + wv) * 4 + q;
  int nstreams = gridDim.x * 16;
  for (int n = stream; n < Nn; n += nstreams) {
    int row = rowptr[n], deg = rowptr[n + 1] - row;
    float a0 = 0.f, a1 = 0.f, a2 = 0.f, a3 = 0.f;
    int s = 0;
    for (; s + 4 <= deg; s += 4) {
      int i0 = csr_src[row + s], i1 = csr_src[row + s + 1];
      int i2 = csr_src[row + s + 2], i3 = csr_src[row + s + 3];
      float w0 = w[row + s], w1 = w[row + s + 1];
      float w2v = w[row + s + 2], w3v = w[row + s + 3];
      ushort4 x0 = *(const ushort4*)(hb + (size_t)i0 * 64);
      ushort4 x1 = *(const ushort4*)(hb + (size_t)i1 * 64);
      ushort4 x2 = *(const ushort4*)(hb + (size_t)i2 * 64);
      ushort4 x3 = *(const ushort4*)(hb + (size_t)i3 * 64);
      a0 = fmaf(w0, b2f(x0.x), a0); a1 = fmaf(w0, b2f(x0.y), a1);
      a2 = fmaf(w0, b2f(x0.z), a2); a3 = fmaf(w0, b2f(x0.w), a3);
      a0 = fmaf(w1, b2f(x1.x), a0); a1 = fmaf(w1, b2f(x1.y), a1);
      a2 = fmaf(w1, b2f(x1.z), a2); a3 = fmaf(w1, b2f(x1.w), a3);
      a0 = fmaf(w2v, b2f(x2.x), a0); a1 = fmaf(w2v, b2f(x2.y), a1);
      a2 = fmaf(w2v, b2f(x2.z), a2); a3 = fmaf(w2v, b2f(x2.w), a3);
      a0 = fmaf(w3v, b2f(x3.x), a0); a1 = fmaf(w3v, b2f(x3.y), a1);
      a2 = fmaf(w3v, b2f(x3.z), a2); a3 = fmaf(w3v, b2f(x3.w), a3);
    }
    for (; s < deg; s++) {
      int i0 = csr_src[row + s];
      float w0 = w[row + s];
      ushort4 x0 = *(const ushort4*)(hb + (size_t)i0 * 64);
      a0 = fmaf(w0, b2f(x0.x), a0); a1 = fmaf(w0, b2f(x0.y), a1);
      a2 = fmaf(w0, b2f(x0.z), a2); a3 = fmaf(w0, b2f(x0.w), a3);
    }
    float vinv = inv[n];
    float4 bb = *(const float4*)(b2 + c0);
    float r0 = fmaf(a0, vinv, bb.x), r1 = fmaf(a1, vinv, bb.y);
    float r2 = fmaf(a2, vinv, bb.z), r3 = fmaf(a3, vinv, bb.w);
    p0 += r0 > 0.f ? r0 : 0.f; p1 += r1 > 0.f ? r1 : 0.f;
    p2 += r2 > 0.f ? r2 : 0.f; p3 += r3 > 0.f ? r3 : 0.f;
  }
  __shared__ float4 sred[4][4][16];
  sred[wv][q][l15] = make_float4(p0, p1, p2, p3);
  __syncthreads();
  if (threadIdx.x < 16) {
    float4 acc = make_float4(0.f, 0.f, 0.f, 0.f);
#pragma unroll
    for (int i = 0; i < 4; i++)
#pragma unroll
      for (int j = 0; j < 4; j++) {
        float4 v = sred[i][j][threadIdx.x];
        acc.x += v.x; acc.y += v.y; acc.z += v.z; acc.w += v.w;
      }
    partial[blockIdx.x * 16 + threadIdx.x] = acc;
  }
}

// ---- reduce per-block pool partials -> pooled[64] (one block) ----
__global__ __launch_bounds__(256) void pool_reduce_kernel(const float4* __restrict__ partial,
    float4* __restrict__ pooled4, int nblocks) {
  int t = threadIdx.x;
  int slot = t & 15, p = t >> 4;  // 16 portions
  float4 acc = make_float4(0.f, 0.f, 0.f, 0.f);
  for (int b = p; b < nblocks; b += 16) {
    float4 v = partial[b * 16 + slot];
    acc.x += v.x; acc.y += v.y; acc.z += v.z; acc.w += v.w;
  }
  __shared__ float4 s[16][16];
  s[p][slot] = acc;
  __syncthreads();
  if (t < 16) {
    float4 a = make_float4(0.f, 0.f, 0.f, 0.f);
#pragma unroll
    for (int i = 0; i < 16; i++) {
      float4 v = s[i][t];
      a.x += v.x; a.y += v.y; a.z += v.z; a.w += v.w;
    }
    pooled4[t] = a;
  }
}

// ---- final fc + log_softmax; single block of 64 threads ----
__global__ void head_kernel(const float* __restrict__ pooled, const float* __restrict__ fc_w,
    const float* __restrict__ fc_b, float* __restrict__ out, float invN) {
  __shared__ float p[64];
  __shared__ float lg[40];
  __shared__ float lse;
  int t = threadIdx.x;
  p[t] = pooled[t] * invN;
  __syncthreads();
  if (t < 40) {
    float s = fc_b[t];
    for (int c = 0; c < 64; c++) s = fmaf(p[c], fc_w[c * 40 + t], s);
    lg[t] = s;
  }
  __syncthreads();
  if (t == 0) {
    float m = -1e30f;
    for (int j = 0; j < 40; j++) m = fmaxf(m, lg[j]);
    float sum = 0.f;
    for (int j = 0; j < 40; j++) sum += expf(lg[j] - m);
    lse = m + logf(sum);
  }
  __syncthreads();
  if (t < 40) out[t] = lg[t] - lse;
}

extern "C" void kernel_launch(void* const* d_in, const int* in_sizes, int n_in,
                              void* d_out, int out_size, void* d_ws, size_t ws_size,
                              hipStream_t stream) {
  const float* x        = (const float*)d_in[0];
  const int*   ei       = (const int*)d_in[1];
  const float* W1       = (const float*)d_in[2];
  const float* att_src1 = (const float*)d_in[3];
  const float* att_dst1 = (const float*)d_in[4];
  const float* b1       = (const float*)d_in[5];
  const float* W2       = (const float*)d_in[6];
  const float* att_src2 = (const float*)d_in[7];
  const float* att_dst2 = (const float*)d_in[8];
  const float* b2       = (const float*)d_in[9];
  const float* fc_w     = (const float*)d_in[10];
  const float* fc_b     = (const float*)d_in[11];
  float* out = (float*)d_out;

  const int N    = in_sizes[0] / 128;  // 50000
  const int E0   = in_sizes[1] / 2;    // 800000
  const int Etot = E0 + N;
  const int NB   = (N + 255) / 256;
  const int AGG2_BLOCKS = 2048;

  char* wsb = (char*)d_ws;
  size_t o = 0;
  auto alloc = [&](size_t bytes) { char* p = wsb + o; o += (bytes + 15) & ~(size_t)15; return p; };
  unsigned short* xb   = (unsigned short*)alloc((size_t)N * 128 * 2);
  unsigned short* w1b  = (unsigned short*)alloc(128 * 256 * 2);
  unsigned short* w2b  = (unsigned short*)alloc(256 * 64 * 2);
  unsigned short* h1   = (unsigned short*)alloc((size_t)N * 256 * 2);  // bf16; reused as h2
  unsigned short* h2   = h1;
  unsigned short* out1 = (unsigned short*)alloc((size_t)N * 256 * 2);  // bf16
  float* as1  = (float*)alloc((size_t)N * 4 * 4);
  float* ad1  = (float*)alloc((size_t)N * 4 * 4);
  float* inv1 = (float*)alloc((size_t)N * 4 * 4);
  float* w1e  = (float*)alloc((size_t)Etot * 4 * 4);
  float* as2  = (float*)alloc((size_t)N * 4);
  float* ad2  = (float*)alloc((size_t)N * 4);
  float* inv2 = (float*)alloc((size_t)N * 4);
  float* w2e  = (float*)alloc((size_t)Etot * 4);
  int* degcur = (int*)alloc((size_t)N * 4);
  int* rowptr = (int*)alloc((size_t)(N + 1) * 4);
  int* bsum   = (int*)alloc(256 * 4);
  int* boff   = (int*)alloc(256 * 4);
  int* csr_src = (int*)alloc((size_t)Etot * 4);
  float4* partial = (float4*)alloc((size_t)AGG2_BLOCKS * 16 * 16);
  float* pooled = (float*)alloc(64 * 4);

  dim3 blk(256);

  // ---- bf16 casts ----
  cast3_kernel<<<512, blk, 0, stream>>>(
      (const float4*)x, (ushort4*)xb, N * 128 / 4,
      (const float4*)W1, (ushort4*)w1b, 128 * 256 / 4,
      (const float4*)W2, (ushort4*)w2b, 256 * 64 / 4);

  // ---- CSR build ----
  deg_init_kernel<<<(N + 255) / 256, blk, 0, stream>>>(degcur, N);
  deg_count_kernel<<<(E0 + 255) / 256, blk, 0, stream>>>(ei, degcur, E0);
  scan_partial_kernel<<<NB, blk, 0, stream>>>(degcur, bsum, N);
  scan_top_kernel<<<1, blk, 0, stream>>>(bsum, boff, rowptr + N, NB);
  scan_final_kernel<<<NB, blk, 0, stream>>>(degcur, boff, rowptr, N);
  hipMemcpyAsync(degcur, rowptr, (size_t)N * sizeof(int), hipMemcpyDeviceToDevice, stream);
  scatter_kernel<<<(Etot + 255) / 256, blk, 0, stream>>>(ei, degcur, csr_src, E0, Etot);

  // ---- layer 1 ----
  gemm_mfma<<<dim3(4, (N + 63) / 64), blk, 0, stream>>>(xb, w1b, h1, N, 128, 256);
  alpha_kernel<4><<<N, blk, 0, stream>>>((const __hip_bfloat16*)h1, att_src1, att_dst1, as1, ad1, N);
  stats1_kernel<<<(N + 3) / 4, blk, 0, stream>>>(rowptr, csr_src, (const float4*)as1,
                                                 (const float4*)ad1, (float4*)w1e,
                                                 (float4*)inv1, N);
  aggr1_kernel<<<(N + 3) / 4, blk, 0, stream>>>(rowptr, csr_src, w1e, inv1,
                                                (const __hip_bfloat16*)h1, b1, out1, N);

  // ---- layer 2 (h2 reuses h1 region; stream-ordered after aggr1) ----
  gemm_mfma<<<dim3(1, (N + 63) / 64), blk, 0, stream>>>(out1, w2b, h2, N, 256, 64);
  alpha_kernel<1><<<(N + 3) / 4, blk, 0, stream>>>((const __hip_bfloat16*)h2, att_src2, att_dst2,
                                                   as2, ad2, N);
  stats2_kernel<<<(N + 3) / 4, blk, 0, stream>>>(rowptr, csr_src, as2, ad2, w2e, inv2, N);
  aggr2_pool_kernel<<<AGG2_BLOCKS, blk, 0, stream>>>(rowptr, csr_src, w2e, inv2, h2, b2,
                                                     partial, N);
  pool_reduce_kernel<<<1, blk, 0, stream>>>(partial, (float4*)pooled, AGG2_BLOCKS);

  // ---- epilogue ----
  head_kernel<<<1, 64, 0, stream>>>(pooled, fc_w, fc_b, out, 1.0f / (float)N);
}

// Round 7
// 401.547 us; speedup vs baseline: 3.3390x; 1.0735x over previous
//
#include <hip/hip_runtime.h>
#include <hip/hip_bf16.h>
#include <math.h>

#define NEG_SLOPE 0.2f

typedef __attribute__((ext_vector_type(8))) short bf16x8;
typedef __attribute__((ext_vector_type(4))) float f32x4;
typedef __attribute__((ext_vector_type(2))) float f32x2_t;

__device__ __forceinline__ float lrelu(float a) { return a >= 0.f ? a : NEG_SLOPE * a; }
__device__ __forceinline__ float b2f(unsigned short u) {
  return __uint_as_float(((unsigned)u) << 16);
}
__device__ __forceinline__ unsigned short f2bu(float v) {
  unsigned u = __float_as_uint(v);
  u += 0x7fffu + ((u >> 16) & 1u);  // RNE
  return (unsigned short)(u >> 16);
}
// fp8 e4m3 (OCP on gfx950) HW conversions
__device__ __forceinline__ unsigned char f2fp8(float v) {
  return (unsigned char)(__builtin_amdgcn_cvt_pk_fp8_f32(v, v, 0, false) & 0xFF);
}
__device__ __forceinline__ void fp8x4_dec(unsigned v, float& a, float& b, float& c, float& d) {
  f32x2_t lo = __builtin_amdgcn_cvt_pk_f32_fp8(v, false);
  f32x2_t hi = __builtin_amdgcn_cvt_pk_f32_fp8(v, true);
  a = lo.x; b = lo.y; c = hi.x; d = hi.y;
}

// ---- fused bf16 cast of x, W1, W2 ----
__global__ __launch_bounds__(256) void cast3_kernel(
    const float4* __restrict__ a0, ushort4* __restrict__ d0, int n0,
    const float4* __restrict__ a1, ushort4* __restrict__ d1, int n1,
    const float4* __restrict__ a2, ushort4* __restrict__ d2, int n2) {
  int total = n0 + n1 + n2;
  for (int i = blockIdx.x * blockDim.x + threadIdx.x; i < total; i += gridDim.x * blockDim.x) {
    const float4* s;
    ushort4* d;
    int j = i;
    if (j < n0) { s = a0; d = d0; }
    else if (j < n0 + n1) { j -= n0; s = a1; d = d1; }
    else { j -= n0 + n1; s = a2; d = d2; }
    float4 v = s[j];
    d[j] = make_ushort4(f2bu(v.x), f2bu(v.y), f2bu(v.z), f2bu(v.w));
  }
}

// ---- bf16 MFMA GEMM, dual output: bf16 C + fp8 C8 ----
__global__ __launch_bounds__(256) void gemm_mfma(const unsigned short* __restrict__ A,
    const unsigned short* __restrict__ B, unsigned short* __restrict__ C,
    unsigned char* __restrict__ C8, int M, int K, int Ncol) {
  __shared__ unsigned short Al[64][40];
  __shared__ unsigned short Bt[64][40];
  const int tid = threadIdx.x;
  const int row0 = blockIdx.y * 64, col0 = blockIdx.x * 64;
  const int lane = tid & 63, wave = tid >> 6;
  const int wm = wave >> 1, wn = wave & 1;
  const int l15 = lane & 15, q = lane >> 4;

  f32x4 acc[2][2] = {};

  const int am = tid >> 2, ac = (tid & 3) * 8;
  const int bk = tid >> 3, bn = (tid & 7) * 8;

  for (int k0 = 0; k0 < K; k0 += 32) {
    ushort4 av0 = make_ushort4(0, 0, 0, 0), av1 = av0;
    if (row0 + am < M) {
      const ushort4* ap = (const ushort4*)(A + (size_t)(row0 + am) * K + k0 + ac);
      av0 = ap[0]; av1 = ap[1];
    }
    *(ushort4*)&Al[am][ac] = av0;
    *(ushort4*)&Al[am][ac + 4] = av1;
    {
      const ushort4* bp = (const ushort4*)(B + (size_t)(k0 + bk) * Ncol + col0 + bn);
      ushort4 b0 = bp[0], b1 = bp[1];
      Bt[bn + 0][bk] = b0.x; Bt[bn + 1][bk] = b0.y;
      Bt[bn + 2][bk] = b0.z; Bt[bn + 3][bk] = b0.w;
      Bt[bn + 4][bk] = b1.x; Bt[bn + 5][bk] = b1.y;
      Bt[bn + 6][bk] = b1.z; Bt[bn + 7][bk] = b1.w;
    }
    __syncthreads();
    bf16x8 af[2], bf[2];
#pragma unroll
    for (int mi = 0; mi < 2; mi++)
      af[mi] = *(const bf16x8*)&Al[wm * 32 + mi * 16 + l15][q * 8];
#pragma unroll
    for (int ni = 0; ni < 2; ni++)
      bf[ni] = *(const bf16x8*)&Bt[wn * 32 + ni * 16 + l15][q * 8];
#pragma unroll
    for (int mi = 0; mi < 2; mi++)
#pragma unroll
      for (int ni = 0; ni < 2; ni++)
        acc[mi][ni] = __builtin_amdgcn_mfma_f32_16x16x32_bf16(af[mi], bf[ni], acc[mi][ni], 0, 0, 0);
    __syncthreads();
  }
#pragma unroll
  for (int mi = 0; mi < 2; mi++) {
#pragma unroll
    for (int r = 0; r < 4; r++) {
      int grow = row0 + wm * 32 + mi * 16 + q * 4 + r;
      if (grow < M) {
#pragma unroll
        for (int ni = 0; ni < 2; ni++) {
          int gcol = col0 + wn * 32 + ni * 16 + l15;
          float v = acc[mi][ni][r];
          C[(size_t)grow * Ncol + gcol] = f2bu(v);
          C8[(size_t)grow * Ncol + gcol] = f2fp8(v);
        }
      }
    }
  }
}

// ---- CSR build ----
__global__ __launch_bounds__(256) void deg_init_kernel(int* __restrict__ deg, int N) {
  int i = blockIdx.x * blockDim.x + threadIdx.x;
  if (i < N) deg[i] = 1;  // self-loop
}

__global__ __launch_bounds__(256) void deg_count_kernel(const int* __restrict__ ei,
    int* __restrict__ deg, int E0) {
  int e = blockIdx.x * blockDim.x + threadIdx.x;
  if (e < E0) atomicAdd(&deg[ei[E0 + e]], 1);
}

__global__ __launch_bounds__(256) void scan_partial_kernel(const int* __restrict__ deg,
    int* __restrict__ bsum, int N) {
  __shared__ int s[256];
  int t = threadIdx.x;
  int i = blockIdx.x * 256 + t;
  s[t] = (i < N) ? deg[i] : 0;
  __syncthreads();
  for (int off = 128; off; off >>= 1) {
    if (t < off) s[t] += s[t + off];
    __syncthreads();
  }
  if (t == 0) bsum[blockIdx.x] = s[0];
}

__global__ __launch_bounds__(256) void scan_top_kernel(const int* __restrict__ bsum,
    int* __restrict__ boff, int* __restrict__ rowptrN, int NB) {
  __shared__ int s[256];
  int t = threadIdx.x;
  int v = (t < NB) ? bsum[t] : 0;
  s[t] = v;
  __syncthreads();
  for (int off = 1; off < 256; off <<= 1) {
    int u = (t >= off) ? s[t - off] : 0;
    __syncthreads();
    s[t] += u;
    __syncthreads();
  }
  if (t < NB) boff[t] = s[t] - v;
  if (t == 255) *rowptrN = s[255];
}

__global__ __launch_bounds__(256) void scan_final_kernel(const int* __restrict__ deg,
    const int* __restrict__ boff, int* __restrict__ rowptr, int N) {
  __shared__ int s[256];
  int t = threadIdx.x;
  int i = blockIdx.x * 256 + t;
  int v = (i < N) ? deg[i] : 0;
  s[t] = v;
  __syncthreads();
  for (int off = 1; off < 256; off <<= 1) {
    int u = (t >= off) ? s[t - off] : 0;
    __syncthreads();
    s[t] += u;
    __syncthreads();
  }
  if (i < N) rowptr[i] = boff[blockIdx.x] + s[t] - v;
}

__global__ __launch_bounds__(256) void scatter_kernel(const int* __restrict__ ei,
    int* __restrict__ cursor, int* __restrict__ csr_src, int E0, int Etot) {
  int e = blockIdx.x * blockDim.x + threadIdx.x;
  if (e >= Etot) return;
  int src, dst;
  if (e < E0) { src = ei[e]; dst = ei[E0 + e]; } else { src = e - E0; dst = src; }
  int pos = atomicAdd(&cursor[dst], 1);
  csr_src[pos] = src;
}

// ---- per-(node,head) attention coefficients (reads bf16 h) ----
template <int H>
__global__ __launch_bounds__(256) void alpha_kernel(const __hip_bfloat16* __restrict__ h,
    const float* __restrict__ att_s, const float* __restrict__ att_d,
    float* __restrict__ as_, float* __restrict__ ad_, int Nn) {
  int wave = (blockIdx.x * blockDim.x + threadIdx.x) >> 6;
  int lane = threadIdx.x & 63;
  if (wave >= Nn * H) return;
  int n = wave / H, hh = wave % H;
  float hv = __bfloat162float(h[(size_t)n * (H * 64) + hh * 64 + lane]);
  float vs = hv * att_s[hh * 64 + lane];
  float vd = hv * att_d[hh * 64 + lane];
  for (int off = 32; off; off >>= 1) {
    vs += __shfl_down(vs, off);
    vd += __shfl_down(vd, off);
  }
  if (lane == 0) { as_[wave] = vs; ad_[wave] = vd; }
}

// ---- layer-1 softmax stats + edge weights ----
__global__ __launch_bounds__(256) void stats1_kernel(const int* __restrict__ rowptr,
    const int* __restrict__ csr_src, const float4* __restrict__ as4,
    const float4* __restrict__ ad4, float4* __restrict__ w4,
    float4* __restrict__ inv4, int Nn) {
  int wave = (blockIdx.x * blockDim.x + threadIdx.x) >> 6;
  int lane = threadIdx.x & 63;
  if (wave >= Nn) return;
  int n = wave;
  int row = rowptr[n], deg = rowptr[n + 1] - row;
  float4 adv = ad4[n];
  float m0 = -1e30f, m1 = -1e30f, m2 = -1e30f, m3 = -1e30f;
  for (int s = lane; s < deg; s += 64) {
    int src = csr_src[row + s];
    float4 a = as4[src];
    m0 = fmaxf(m0, lrelu(a.x + adv.x));
    m1 = fmaxf(m1, lrelu(a.y + adv.y));
    m2 = fmaxf(m2, lrelu(a.z + adv.z));
    m3 = fmaxf(m3, lrelu(a.w + adv.w));
  }
#pragma unroll
  for (int off = 32; off; off >>= 1) {
    m0 = fmaxf(m0, __shfl_xor(m0, off));
    m1 = fmaxf(m1, __shfl_xor(m1, off));
    m2 = fmaxf(m2, __shfl_xor(m2, off));
    m3 = fmaxf(m3, __shfl_xor(m3, off));
  }
  float s0 = 0.f, s1 = 0.f, s2 = 0.f, s3 = 0.f;
  for (int s = lane; s < deg; s += 64) {
    int src = csr_src[row + s];
    float4 a = as4[src];
    float p0 = __expf(lrelu(a.x + adv.x) - m0);
    float p1 = __expf(lrelu(a.y + adv.y) - m1);
    float p2 = __expf(lrelu(a.z + adv.z) - m2);
    float p3 = __expf(lrelu(a.w + adv.w) - m3);
    s0 += p0; s1 += p1; s2 += p2; s3 += p3;
    w4[row + s] = make_float4(p0, p1, p2, p3);
  }
#pragma unroll
  for (int off = 32; off; off >>= 1) {
    s0 += __shfl_xor(s0, off);
    s1 += __shfl_xor(s1, off);
    s2 += __shfl_xor(s2, off);
    s3 += __shfl_xor(s3, off);
  }
  if (lane == 0)
    inv4[n] = make_float4(1.f / (s0 + 1e-16f), 1.f / (s1 + 1e-16f),
                          1.f / (s2 + 1e-16f), 1.f / (s3 + 1e-16f));
}

// ---- layer-2 stats (H=1) ----
__global__ __launch_bounds__(256) void stats2_kernel(const int* __restrict__ rowptr,
    const int* __restrict__ csr_src, const float* __restrict__ as_,
    const float* __restrict__ ad_, float* __restrict__ w, float* __restrict__ inv,
    int Nn) {
  int wave = (blockIdx.x * blockDim.x + threadIdx.x) >> 6;
  int lane = threadIdx.x & 63;
  if (wave >= Nn) return;
  int n = wave;
  int row = rowptr[n], deg = rowptr[n + 1] - row;
  float adv = ad_[n];
  float m = -1e30f;
  for (int s = lane; s < deg; s += 64) m = fmaxf(m, lrelu(as_[csr_src[row + s]] + adv));
#pragma unroll
  for (int off = 32; off; off >>= 1) m = fmaxf(m, __shfl_xor(m, off));
  float sum = 0.f;
  for (int s = lane; s < deg; s += 64) {
    float p = __expf(lrelu(as_[csr_src[row + s]] + adv) - m);
    sum += p;
    w[row + s] = p;
  }
#pragma unroll
  for (int off = 32; off; off >>= 1) sum += __shfl_xor(sum, off);
  if (lane == 0) inv[n] = 1.f / (sum + 1e-16f);
}

// ---- layer-1 aggregate: fp8 gather; one wave per node, lane owns 4 channels ----
__global__ __launch_bounds__(256) void aggr1_kernel(const int* __restrict__ rowptr,
    const int* __restrict__ csr_src, const float* __restrict__ w,
    const float* __restrict__ inv, const unsigned* __restrict__ h1f8,  // [N][64] words
    const float* __restrict__ b1, unsigned short* __restrict__ out1, int Nn) {
  int wv = threadIdx.x >> 6, lane = threadIdx.x & 63;
  int n = blockIdx.x * 4 + wv;
  if (n >= Nn) return;
  int row = rowptr[n], deg = rowptr[n + 1] - row;
  int hh = lane >> 4;
  const unsigned* hb = h1f8 + lane;
  float a0 = 0.f, a1 = 0.f, a2 = 0.f, a3 = 0.f;
  int s = 0;
  for (; s + 8 <= deg; s += 8) {
    int idx[8];
    float wt[8];
    unsigned xv[8];
#pragma unroll
    for (int j = 0; j < 8; j++) idx[j] = csr_src[row + s + j];
#pragma unroll
    for (int j = 0; j < 8; j++) wt[j] = w[(size_t)(row + s + j) * 4 + hh];
#pragma unroll
    for (int j = 0; j < 8; j++) xv[j] = hb[(size_t)idx[j] * 64];
#pragma unroll
    for (int j = 0; j < 8; j++) {
      float c0, c1, c2, c3;
      fp8x4_dec(xv[j], c0, c1, c2, c3);
      a0 = fmaf(wt[j], c0, a0); a1 = fmaf(wt[j], c1, a1);
      a2 = fmaf(wt[j], c2, a2); a3 = fmaf(wt[j], c3, a3);
    }
  }
  if (s + 4 <= deg) {
    int idx[4];
    float wt[4];
    unsigned xv[4];
#pragma unroll
    for (int j = 0; j < 4; j++) idx[j] = csr_src[row + s + j];
#pragma unroll
    for (int j = 0; j < 4; j++) wt[j] = w[(size_t)(row + s + j) * 4 + hh];
#pragma unroll
    for (int j = 0; j < 4; j++) xv[j] = hb[(size_t)idx[j] * 64];
#pragma unroll
    for (int j = 0; j < 4; j++) {
      float c0, c1, c2, c3;
      fp8x4_dec(xv[j], c0, c1, c2, c3);
      a0 = fmaf(wt[j], c0, a0); a1 = fmaf(wt[j], c1, a1);
      a2 = fmaf(wt[j], c2, a2); a3 = fmaf(wt[j], c3, a3);
    }
    s += 4;
  }
  for (; s < deg; s++) {
    int i0 = csr_src[row + s];
    float w0 = w[(size_t)(row + s) * 4 + hh];
    float c0, c1, c2, c3;
    fp8x4_dec(hb[(size_t)i0 * 64], c0, c1, c2, c3);
    a0 = fmaf(w0, c0, a0); a1 = fmaf(w0, c1, a1);
    a2 = fmaf(w0, c2, a2); a3 = fmaf(w0, c3, a3);
  }
  float vinv = inv[n * 4 + hh];
  int c0i = lane * 4;
  float4 bb = *(const float4*)(b1 + c0i);
  float rx = fmaf(a0, vinv, bb.x), ry = fmaf(a1, vinv, bb.y);
  float rz = fmaf(a2, vinv, bb.z), rw = fmaf(a3, vinv, bb.w);
  rx = rx > 0.f ? rx : 0.f; ry = ry > 0.f ? ry : 0.f;
  rz = rz > 0.f ? rz : 0.f; rw = rw > 0.f ? rw : 0.f;
  *(ushort4*)(out1 + (size_t)n * 256 + c0i) =
      make_ushort4(f2bu(rx), f2bu(ry), f2bu(rz), f2bu(rw));
}

// ---- layer-2 aggregate + relu + pool partials (fp8 gather) ----
__global__ __launch_bounds__(256) void aggr2_pool_kernel(const int* __restrict__ rowptr,
    const int* __restrict__ csr_src, const float* __restrict__ w,
    const float* __restrict__ inv, const unsigned* __restrict__ h2f8,  // [N][16] words
    const float* __restrict__ b2, float4* __restrict__ partial, int Nn) {
  int lane = threadIdx.x & 63, wv = threadIdx.x >> 6;
  int q = lane >> 4, l15 = lane & 15;
  int c0 = l15 * 4;
  const unsigned* hb = h2f8 + l15;
  float p0 = 0.f, p1 = 0.f, p2 = 0.f, p3 = 0.f;
  int stream = (blockIdx.x * 4 + wv) * 4 + q;
  int nstreams = gridDim.x * 16;
  for (int n = stream; n < Nn; n += nstreams) {
    int row = rowptr[n], deg = rowptr[n + 1] - row;
    float a0 = 0.f, a1 = 0.f, a2 = 0.f, a3 = 0.f;
    int s = 0;
    for (; s + 4 <= deg; s += 4) {
      int i0 = csr_src[row + s], i1 = csr_src[row + s + 1];
      int i2 = csr_src[row + s + 2], i3 = csr_src[row + s + 3];
      float w0 = w[row + s], w1 = w[row + s + 1];
      float w2v = w[row + s + 2], w3v = w[row + s + 3];
      unsigned x0 = hb[(size_t)i0 * 16];
      unsigned x1 = hb[(size_t)i1 * 16];
      unsigned x2 = hb[(size_t)i2 * 16];
      unsigned x3 = hb[(size_t)i3 * 16];
      float c0f, c1f, c2f, c3f;
      fp8x4_dec(x0, c0f, c1f, c2f, c3f);
      a0 = fmaf(w0, c0f, a0); a1 = fmaf(w0, c1f, a1);
      a2 = fmaf(w0, c2f, a2); a3 = fmaf(w0, c3f, a3);
      fp8x4_dec(x1, c0f, c1f, c2f, c3f);
      a0 = fmaf(w1, c0f, a0); a1 = fmaf(w1, c1f, a1);
      a2 = fmaf(w1, c2f, a2); a3 = fmaf(w1, c3f, a3);
      fp8x4_dec(x2, c0f, c1f, c2f, c3f);
      a0 = fmaf(w2v, c0f, a0); a1 = fmaf(w2v, c1f, a1);
      a2 = fmaf(w2v, c2f, a2); a3 = fmaf(w2v, c3f, a3);
      fp8x4_dec(x3, c0f, c1f, c2f, c3f);
      a0 = fmaf(w3v, c0f, a0); a1 = fmaf(w3v, c1f, a1);
      a2 = fmaf(w3v, c2f, a2); a3 = fmaf(w3v, c3f, a3);
    }
    for (; s < deg; s++) {
      int i0 = csr_src[row + s];
      float w0 = w[row + s];
      float c0f, c1f, c2f, c3f;
      fp8x4_dec(hb[(size_t)i0 * 16], c0f, c1f, c2f, c3f);
      a0 = fmaf(w0, c0f, a0); a1 = fmaf(w0, c1f, a1);
      a2 = fmaf(w0, c2f, a2); a3 = fmaf(w0, c3f, a3);
    }
    float vinv = inv[n];
    float4 bb = *(const float4*)(b2 + c0);
    float r0 = fmaf(a0, vinv, bb.x), r1 = fmaf(a1, vinv, bb.y);
    float r2 = fmaf(a2, vinv, bb.z), r3 = fmaf(a3, vinv, bb.w);
    p0 += r0 > 0.f ? r0 : 0.f; p1 += r1 > 0.f ? r1 : 0.f;
    p2 += r2 > 0.f ? r2 : 0.f; p3 += r3 > 0.f ? r3 : 0.f;
  }
  __shared__ float4 sred[4][4][16];
  sred[wv][q][l15] = make_float4(p0, p1, p2, p3);
  __syncthreads();
  if (threadIdx.x < 16) {
    float4 acc = make_float4(0.f, 0.f, 0.f, 0.f);
#pragma unroll
    for (int i = 0; i < 4; i++)
#pragma unroll
      for (int j = 0; j < 4; j++) {
        float4 v = sred[i][j][threadIdx.x];
        acc.x += v.x; acc.y += v.y; acc.z += v.z; acc.w += v.w;
      }
    partial[blockIdx.x * 16 + threadIdx.x] = acc;
  }
}

// ---- reduce per-block pool partials -> pooled[64] (one block) ----
__global__ __launch_bounds__(256) void pool_reduce_kernel(const float4* __restrict__ partial,
    float4* __restrict__ pooled4, int nblocks) {
  int t = threadIdx.x;
  int slot = t & 15, p = t >> 4;
  float4 acc = make_float4(0.f, 0.f, 0.f, 0.f);
  for (int b = p; b < nblocks; b += 16) {
    float4 v = partial[b * 16 + slot];
    acc.x += v.x; acc.y += v.y; acc.z += v.z; acc.w += v.w;
  }
  __shared__ float4 s[16][16];
  s[p][slot] = acc;
  __syncthreads();
  if (t < 16) {
    float4 a = make_float4(0.f, 0.f, 0.f, 0.f);
#pragma unroll
    for (int i = 0; i < 16; i++) {
      float4 v = s[i][t];
      a.x += v.x; a.y += v.y; a.z += v.z; a.w += v.w;
    }
    pooled4[t] = a;
  }
}

// ---- final fc + log_softmax ----
__global__ void head_kernel(const float* __restrict__ pooled, const float* __restrict__ fc_w,
    const float* __restrict__ fc_b, float* __restrict__ out, float invN) {
  __shared__ float p[64];
  __shared__ float lg[40];
  __shared__ float lse;
  int t = threadIdx.x;
  p[t] = pooled[t] * invN;
  __syncthreads();
  if (t < 40) {
    float s = fc_b[t];
    for (int c = 0; c < 64; c++) s = fmaf(p[c], fc_w[c * 40 + t], s);
    lg[t] = s;
  }
  __syncthreads();
  if (t == 0) {
    float m = -1e30f;
    for (int j = 0; j < 40; j++) m = fmaxf(m, lg[j]);
    float sum = 0.f;
    for (int j = 0; j < 40; j++) sum += expf(lg[j] - m);
    lse = m + logf(sum);
  }
  __syncthreads();
  if (t < 40) out[t] = lg[t] - lse;
}

extern "C" void kernel_launch(void* const* d_in, const int* in_sizes, int n_in,
                              void* d_out, int out_size, void* d_ws, size_t ws_size,
                              hipStream_t stream) {
  const float* x        = (const float*)d_in[0];
  const int*   ei       = (const int*)d_in[1];
  const float* W1       = (const float*)d_in[2];
  const float* att_src1 = (const float*)d_in[3];
  const float* att_dst1 = (const float*)d_in[4];
  const float* b1       = (const float*)d_in[5];
  const float* W2       = (const float*)d_in[6];
  const float* att_src2 = (const float*)d_in[7];
  const float* att_dst2 = (const float*)d_in[8];
  const float* b2       = (const float*)d_in[9];
  const float* fc_w     = (const float*)d_in[10];
  const float* fc_b     = (const float*)d_in[11];
  float* out = (float*)d_out;

  const int N    = in_sizes[0] / 128;  // 50000
  const int E0   = in_sizes[1] / 2;    // 800000
  const int Etot = E0 + N;
  const int NB   = (N + 255) / 256;
  const int AGG2_BLOCKS = 2048;

  char* wsb = (char*)d_ws;
  size_t o = 0;
  auto alloc = [&](size_t bytes) { char* p = wsb + o; o += (bytes + 15) & ~(size_t)15; return p; };
  unsigned short* xb   = (unsigned short*)alloc((size_t)N * 128 * 2);
  unsigned short* w1b  = (unsigned short*)alloc(128 * 256 * 2);
  unsigned short* w2b  = (unsigned short*)alloc(256 * 64 * 2);
  unsigned short* h1b  = (unsigned short*)alloc((size_t)N * 256 * 2);  // bf16; reused as h2 bf16
  unsigned char*  h1f8 = (unsigned char*)alloc((size_t)N * 256);      // fp8; reused as h2 fp8
  unsigned short* out1 = (unsigned short*)alloc((size_t)N * 256 * 2);  // bf16
  float* as1  = (float*)alloc((size_t)N * 4 * 4);
  float* ad1  = (float*)alloc((size_t)N * 4 * 4);
  float* inv1 = (float*)alloc((size_t)N * 4 * 4);
  float* w1e  = (float*)alloc((size_t)Etot * 4 * 4);
  float* as2  = (float*)alloc((size_t)N * 4);
  float* ad2  = (float*)alloc((size_t)N * 4);
  float* inv2 = (float*)alloc((size_t)N * 4);
  float* w2e  = (float*)alloc((size_t)Etot * 4);
  int* degcur = (int*)alloc((size_t)N * 4);
  int* rowptr = (int*)alloc((size_t)(N + 1) * 4);
  int* bsum   = (int*)alloc(256 * 4);
  int* boff   = (int*)alloc(256 * 4);
  int* csr_src = (int*)alloc((size_t)Etot * 4);
  float4* partial = (float4*)alloc((size_t)AGG2_BLOCKS * 16 * 16);
  float* pooled = (float*)alloc(64 * 4);

  dim3 blk(256);

  // ---- bf16 casts ----
  cast3_kernel<<<512, blk, 0, stream>>>(
      (const float4*)x, (ushort4*)xb, N * 128 / 4,
      (const float4*)W1, (ushort4*)w1b, 128 * 256 / 4,
      (const float4*)W2, (ushort4*)w2b, 256 * 64 / 4);

  // ---- CSR build ----
  deg_init_kernel<<<(N + 255) / 256, blk, 0, stream>>>(degcur, N);
  deg_count_kernel<<<(E0 + 255) / 256, blk, 0, stream>>>(ei, degcur, E0);
  scan_partial_kernel<<<NB, blk, 0, stream>>>(degcur, bsum, N);
  scan_top_kernel<<<1, blk, 0, stream>>>(bsum, boff, rowptr + N, NB);
  scan_final_kernel<<<NB, blk, 0, stream>>>(degcur, boff, rowptr, N);
  hipMemcpyAsync(degcur, rowptr, (size_t)N * sizeof(int), hipMemcpyDeviceToDevice, stream);
  scatter_kernel<<<(Etot + 255) / 256, blk, 0, stream>>>(ei, degcur, csr_src, E0, Etot);

  // ---- layer 1 ----
  gemm_mfma<<<dim3(4, (N + 63) / 64), blk, 0, stream>>>(xb, w1b, h1b, h1f8, N, 128, 256);
  alpha_kernel<4><<<N, blk, 0, stream>>>((const __hip_bfloat16*)h1b, att_src1, att_dst1,
                                         as1, ad1, N);
  stats1_kernel<<<(N + 3) / 4, blk, 0, stream>>>(rowptr, csr_src, (const float4*)as1,
                                                 (const float4*)ad1, (float4*)w1e,
                                                 (float4*)inv1, N);
  aggr1_kernel<<<(N + 3) / 4, blk, 0, stream>>>(rowptr, csr_src, w1e, inv1,
                                                (const unsigned*)h1f8, b1, out1, N);

  // ---- layer 2 (h2 reuses h1 buffers; stream-ordered after aggr1) ----
  gemm_mfma<<<dim3(1, (N + 63) / 64), blk, 0, stream>>>(out1, w2b, h1b, h1f8, N, 256, 64);
  alpha_kernel<1><<<(N + 3) / 4, blk, 0, stream>>>((const __hip_bfloat16*)h1b, att_src2, att_dst2,
                                                   as2, ad2, N);
  stats2_kernel<<<(N + 3) / 4, blk, 0, stream>>>(rowptr, csr_src, as2, ad2, w2e, inv2, N);
  aggr2_pool_kernel<<<AGG2_BLOCKS, blk, 0, stream>>>(rowptr, csr_src, w2e, inv2,
                                                     (const unsigned*)h1f8, b2, partial, N);
  pool_reduce_kernel<<<1, blk, 0, stream>>>(partial, (float4*)pooled, AGG2_BLOCKS);

  // ---- epilogue ----
  head_kernel<<<1, 64, 0, stream>>>(pooled, fc_w, fc_b, out, 1.0f / (float)N);
}

// Round 8
// 344.734 us; speedup vs baseline: 3.8892x; 1.1648x over previous
//
#include <hip/hip_runtime.h>
#include <hip/hip_bf16.h>
#include <math.h>

#define NEG_SLOPE 0.2f

typedef __attribute__((ext_vector_type(8))) short bf16x8;
typedef __attribute__((ext_vector_type(4))) float f32x4;
typedef __attribute__((ext_vector_type(2))) float f32x2_t;

__device__ __forceinline__ float lrelu(float a) { return a >= 0.f ? a : NEG_SLOPE * a; }
__device__ __forceinline__ float b2f(unsigned short u) {
  return __uint_as_float(((unsigned)u) << 16);
}
__device__ __forceinline__ unsigned short f2bu(float v) {
  unsigned u = __float_as_uint(v);
  u += 0x7fffu + ((u >> 16) & 1u);  // RNE
  return (unsigned short)(u >> 16);
}
// fp8 e4m3 (OCP on gfx950) HW conversions
__device__ __forceinline__ unsigned char f2fp8(float v) {
  return (unsigned char)(__builtin_amdgcn_cvt_pk_fp8_f32(v, v, 0, false) & 0xFF);
}
__device__ __forceinline__ void fp8x4_dec(unsigned v, float& a, float& b, float& c, float& d) {
  f32x2_t lo = __builtin_amdgcn_cvt_pk_f32_fp8(v, false);
  f32x2_t hi = __builtin_amdgcn_cvt_pk_f32_fp8(v, true);
  a = lo.x; b = lo.y; c = hi.x; d = hi.y;
}

// ---- fused bf16 cast of x, W1, W2 ----
__global__ __launch_bounds__(256) void cast3_kernel(
    const float4* __restrict__ a0, ushort4* __restrict__ d0, int n0,
    const float4* __restrict__ a1, ushort4* __restrict__ d1, int n1,
    const float4* __restrict__ a2, ushort4* __restrict__ d2, int n2) {
  int total = n0 + n1 + n2;
  for (int i = blockIdx.x * blockDim.x + threadIdx.x; i < total; i += gridDim.x * blockDim.x) {
    const float4* s;
    ushort4* d;
    int j = i;
    if (j < n0) { s = a0; d = d0; }
    else if (j < n0 + n1) { j -= n0; s = a1; d = d1; }
    else { j -= n0 + n1; s = a2; d = d2; }
    float4 v = s[j];
    d[j] = make_ushort4(f2bu(v.x), f2bu(v.y), f2bu(v.z), f2bu(v.w));
  }
}

// ---- bf16 MFMA GEMM, dual output: bf16 C + fp8 C8 ----
__global__ __launch_bounds__(256) void gemm_mfma(const unsigned short* __restrict__ A,
    const unsigned short* __restrict__ B, unsigned short* __restrict__ C,
    unsigned char* __restrict__ C8, int M, int K, int Ncol) {
  __shared__ unsigned short Al[64][40];
  __shared__ unsigned short Bt[64][40];
  const int tid = threadIdx.x;
  const int row0 = blockIdx.y * 64, col0 = blockIdx.x * 64;
  const int lane = tid & 63, wave = tid >> 6;
  const int wm = wave >> 1, wn = wave & 1;
  const int l15 = lane & 15, q = lane >> 4;

  f32x4 acc[2][2] = {};

  const int am = tid >> 2, ac = (tid & 3) * 8;
  const int bk = tid >> 3, bn = (tid & 7) * 8;

  for (int k0 = 0; k0 < K; k0 += 32) {
    ushort4 av0 = make_ushort4(0, 0, 0, 0), av1 = av0;
    if (row0 + am < M) {
      const ushort4* ap = (const ushort4*)(A + (size_t)(row0 + am) * K + k0 + ac);
      av0 = ap[0]; av1 = ap[1];
    }
    *(ushort4*)&Al[am][ac] = av0;
    *(ushort4*)&Al[am][ac + 4] = av1;
    {
      const ushort4* bp = (const ushort4*)(B + (size_t)(k0 + bk) * Ncol + col0 + bn);
      ushort4 b0 = bp[0], b1 = bp[1];
      Bt[bn + 0][bk] = b0.x; Bt[bn + 1][bk] = b0.y;
      Bt[bn + 2][bk] = b0.z; Bt[bn + 3][bk] = b0.w;
      Bt[bn + 4][bk] = b1.x; Bt[bn + 5][bk] = b1.y;
      Bt[bn + 6][bk] = b1.z; Bt[bn + 7][bk] = b1.w;
    }
    __syncthreads();
    bf16x8 af[2], bf[2];
#pragma unroll
    for (int mi = 0; mi < 2; mi++)
      af[mi] = *(const bf16x8*)&Al[wm * 32 + mi * 16 + l15][q * 8];
#pragma unroll
    for (int ni = 0; ni < 2; ni++)
      bf[ni] = *(const bf16x8*)&Bt[wn * 32 + ni * 16 + l15][q * 8];
#pragma unroll
    for (int mi = 0; mi < 2; mi++)
#pragma unroll
      for (int ni = 0; ni < 2; ni++)
        acc[mi][ni] = __builtin_amdgcn_mfma_f32_16x16x32_bf16(af[mi], bf[ni], acc[mi][ni], 0, 0, 0);
    __syncthreads();
  }
#pragma unroll
  for (int mi = 0; mi < 2; mi++) {
#pragma unroll
    for (int r = 0; r < 4; r++) {
      int grow = row0 + wm * 32 + mi * 16 + q * 4 + r;
      if (grow < M) {
#pragma unroll
        for (int ni = 0; ni < 2; ni++) {
          int gcol = col0 + wn * 32 + ni * 16 + l15;
          float v = acc[mi][ni][r];
          C[(size_t)grow * Ncol + gcol] = f2bu(v);
          C8[(size_t)grow * Ncol + gcol] = f2fp8(v);
        }
      }
    }
  }
}

// ---- CSR build via 2-level bucketed counting sort (bucket = dst>>8) ----
// A1: global bucket histogram (LDS-privatized)
__global__ __launch_bounds__(256) void bucket_hist_kernel(const int* __restrict__ ei,
    int* __restrict__ bhist, int E0, int Etot, int NBUCK) {
  __shared__ int h[256];
  int t = threadIdx.x;
  h[t] = 0;
  __syncthreads();
  for (int e = blockIdx.x * 256 + t; e < Etot; e += gridDim.x * 256) {
    int dst = (e < E0) ? ei[E0 + e] : (e - E0);
    atomicAdd(&h[dst >> 8], 1);
  }
  __syncthreads();
  if (t < NBUCK && h[t]) atomicAdd(&bhist[t], h[t]);
}

// A2: scan buckets -> bucketOff[NBUCK+1], cursor init, rowptr[N]=Etot
__global__ __launch_bounds__(256) void bucket_scan_kernel(const int* __restrict__ bhist,
    int* __restrict__ bucketOff, int* __restrict__ cursor, int* __restrict__ rowptrN,
    int NBUCK, int Etot) {
  __shared__ int s[256];
  int t = threadIdx.x;
  int v = (t < NBUCK) ? bhist[t] : 0;
  s[t] = v;
  __syncthreads();
  for (int off = 1; off < 256; off <<= 1) {
    int u = (t >= off) ? s[t - off] : 0;
    __syncthreads();
    s[t] += u;
    __syncthreads();
  }
  int excl = s[t] - v;
  if (t < NBUCK) { bucketOff[t] = excl; cursor[t] = excl; }
  if (t == 0) { bucketOff[NBUCK] = Etot; *rowptrN = Etot; }
}

// A3: scatter (src,dst) pairs into bucket regions; per-block reservation
#define CHUNK 4096
__global__ __launch_bounds__(256) void bucket_scatter_kernel(const int* __restrict__ ei,
    int* __restrict__ cursor, int2* __restrict__ pairs, int E0, int Etot, int NBUCK) {
  __shared__ int2 stage[CHUNK];
  __shared__ int h[256];
  __shared__ int base[256];
  int t = threadIdx.x;
  int e0 = blockIdx.x * CHUNK;
  h[t] = 0;
  __syncthreads();
  int cnt = Etot - e0;
  if (cnt > CHUNK) cnt = CHUNK;
  for (int i = t; i < cnt; i += 256) {
    int e = e0 + i;
    int s, d;
    if (e < E0) { s = ei[e]; d = ei[E0 + e]; } else { s = d = e - E0; }
    stage[i] = make_int2(s, d);
    atomicAdd(&h[d >> 8], 1);
  }
  __syncthreads();
  if (t < NBUCK && h[t]) base[t] = atomicAdd(&cursor[t], h[t]);
  __syncthreads();
  for (int i = t; i < cnt; i += 256) {
    int2 p = stage[i];
    int b = p.y >> 8;
    int pos = atomicAdd(&base[b], 1);
    pairs[pos] = p;
  }
}

// B: per-bucket fine CSR (one block per bucket; dst range = 256 nodes)
__global__ __launch_bounds__(256) void csr_build_kernel(const int2* __restrict__ pairs,
    const int* __restrict__ bucketOff, int* __restrict__ rowptr, int* __restrict__ csr_src,
    int N) {
  int b = blockIdx.x, t = threadIdx.x;
  int base = bucketOff[b], cnt = bucketOff[b + 1] - base;
  int n0 = b << 8;
  __shared__ int h[256];
  __shared__ int s[256];
  __shared__ int ex[256];
  h[t] = 0;
  __syncthreads();
  for (int i = t; i < cnt; i += 256) atomicAdd(&h[pairs[base + i].y - n0], 1);
  __syncthreads();
  int v = h[t];
  s[t] = v;
  __syncthreads();
  for (int off = 1; off < 256; off <<= 1) {
    int u = (t >= off) ? s[t - off] : 0;
    __syncthreads();
    s[t] += u;
    __syncthreads();
  }
  ex[t] = s[t] - v;
  if (n0 + t < N) rowptr[n0 + t] = base + ex[t];
  __syncthreads();
  for (int i = t; i < cnt; i += 256) {
    int2 p = pairs[base + i];
    int pos = atomicAdd(&ex[p.y - n0], 1);
    csr_src[base + pos] = p.x;
  }
}

// ---- per-(node,head) attention coefficients (reads bf16 h) ----
template <int H>
__global__ __launch_bounds__(256) void alpha_kernel(const __hip_bfloat16* __restrict__ h,
    const float* __restrict__ att_s, const float* __restrict__ att_d,
    float* __restrict__ as_, float* __restrict__ ad_, int Nn) {
  int wave = (blockIdx.x * blockDim.x + threadIdx.x) >> 6;
  int lane = threadIdx.x & 63;
  if (wave >= Nn * H) return;
  int n = wave / H, hh = wave % H;
  float hv = __bfloat162float(h[(size_t)n * (H * 64) + hh * 64 + lane]);
  float vs = hv * att_s[hh * 64 + lane];
  float vd = hv * att_d[hh * 64 + lane];
  for (int off = 32; off; off >>= 1) {
    vs += __shfl_down(vs, off);
    vd += __shfl_down(vd, off);
  }
  if (lane == 0) { as_[wave] = vs; ad_[wave] = vd; }
}

// ---- layer-1 softmax stats + edge weights ----
__global__ __launch_bounds__(256) void stats1_kernel(const int* __restrict__ rowptr,
    const int* __restrict__ csr_src, const float4* __restrict__ as4,
    const float4* __restrict__ ad4, float4* __restrict__ w4,
    float4* __restrict__ inv4, int Nn) {
  int wave = (blockIdx.x * blockDim.x + threadIdx.x) >> 6;
  int lane = threadIdx.x & 63;
  if (wave >= Nn) return;
  int n = wave;
  int row = rowptr[n], deg = rowptr[n + 1] - row;
  float4 adv = ad4[n];
  float m0 = -1e30f, m1 = -1e30f, m2 = -1e30f, m3 = -1e30f;
  for (int s = lane; s < deg; s += 64) {
    int src = csr_src[row + s];
    float4 a = as4[src];
    m0 = fmaxf(m0, lrelu(a.x + adv.x));
    m1 = fmaxf(m1, lrelu(a.y + adv.y));
    m2 = fmaxf(m2, lrelu(a.z + adv.z));
    m3 = fmaxf(m3, lrelu(a.w + adv.w));
  }
#pragma unroll
  for (int off = 32; off; off >>= 1) {
    m0 = fmaxf(m0, __shfl_xor(m0, off));
    m1 = fmaxf(m1, __shfl_xor(m1, off));
    m2 = fmaxf(m2, __shfl_xor(m2, off));
    m3 = fmaxf(m3, __shfl_xor(m3, off));
  }
  float s0 = 0.f, s1 = 0.f, s2 = 0.f, s3 = 0.f;
  for (int s = lane; s < deg; s += 64) {
    int src = csr_src[row + s];
    float4 a = as4[src];
    float p0 = __expf(lrelu(a.x + adv.x) - m0);
    float p1 = __expf(lrelu(a.y + adv.y) - m1);
    float p2 = __expf(lrelu(a.z + adv.z) - m2);
    float p3 = __expf(lrelu(a.w + adv.w) - m3);
    s0 += p0; s1 += p1; s2 += p2; s3 += p3;
    w4[row + s] = make_float4(p0, p1, p2, p3);
  }
#pragma unroll
  for (int off = 32; off; off >>= 1) {
    s0 += __shfl_xor(s0, off);
    s1 += __shfl_xor(s1, off);
    s2 += __shfl_xor(s2, off);
    s3 += __shfl_xor(s3, off);
  }
  if (lane == 0)
    inv4[n] = make_float4(1.f / (s0 + 1e-16f), 1.f / (s1 + 1e-16f),
                          1.f / (s2 + 1e-16f), 1.f / (s3 + 1e-16f));
}

// ---- layer-2 stats (H=1) ----
__global__ __launch_bounds__(256) void stats2_kernel(const int* __restrict__ rowptr,
    const int* __restrict__ csr_src, const float* __restrict__ as_,
    const float* __restrict__ ad_, float* __restrict__ w, float* __restrict__ inv,
    int Nn) {
  int wave = (blockIdx.x * blockDim.x + threadIdx.x) >> 6;
  int lane = threadIdx.x & 63;
  if (wave >= Nn) return;
  int n = wave;
  int row = rowptr[n], deg = rowptr[n + 1] - row;
  float adv = ad_[n];
  float m = -1e30f;
  for (int s = lane; s < deg; s += 64) m = fmaxf(m, lrelu(as_[csr_src[row + s]] + adv));
#pragma unroll
  for (int off = 32; off; off >>= 1) m = fmaxf(m, __shfl_xor(m, off));
  float sum = 0.f;
  for (int s = lane; s < deg; s += 64) {
    float p = __expf(lrelu(as_[csr_src[row + s]] + adv) - m);
    sum += p;
    w[row + s] = p;
  }
#pragma unroll
  for (int off = 32; off; off >>= 1) sum += __shfl_xor(sum, off);
  if (lane == 0) inv[n] = 1.f / (sum + 1e-16f);
}

// ---- layer-1 aggregate: fp8 gather; one wave per node, lane owns 4 channels ----
__global__ __launch_bounds__(256) void aggr1_kernel(const int* __restrict__ rowptr,
    const int* __restrict__ csr_src, const float* __restrict__ w,
    const float* __restrict__ inv, const unsigned* __restrict__ h1f8,  // [N][64] words
    const float* __restrict__ b1, unsigned short* __restrict__ out1, int Nn) {
  int wv = threadIdx.x >> 6, lane = threadIdx.x & 63;
  int n = blockIdx.x * 4 + wv;
  if (n >= Nn) return;
  int row = rowptr[n], deg = rowptr[n + 1] - row;
  int hh = lane >> 4;
  const unsigned* hb = h1f8 + lane;
  float a0 = 0.f, a1 = 0.f, a2 = 0.f, a3 = 0.f;
  int s = 0;
  for (; s + 8 <= deg; s += 8) {
    int idx[8];
    float wt[8];
    unsigned xv[8];
#pragma unroll
    for (int j = 0; j < 8; j++) idx[j] = csr_src[row + s + j];
#pragma unroll
    for (int j = 0; j < 8; j++) wt[j] = w[(size_t)(row + s + j) * 4 + hh];
#pragma unroll
    for (int j = 0; j < 8; j++) xv[j] = hb[(size_t)idx[j] * 64];
#pragma unroll
    for (int j = 0; j < 8; j++) {
      float c0, c1, c2, c3;
      fp8x4_dec(xv[j], c0, c1, c2, c3);
      a0 = fmaf(wt[j], c0, a0); a1 = fmaf(wt[j], c1, a1);
      a2 = fmaf(wt[j], c2, a2); a3 = fmaf(wt[j], c3, a3);
    }
  }
  if (s + 4 <= deg) {
    int idx[4];
    float wt[4];
    unsigned xv[4];
#pragma unroll
    for (int j = 0; j < 4; j++) idx[j] = csr_src[row + s + j];
#pragma unroll
    for (int j = 0; j < 4; j++) wt[j] = w[(size_t)(row + s + j) * 4 + hh];
#pragma unroll
    for (int j = 0; j < 4; j++) xv[j] = hb[(size_t)idx[j] * 64];
#pragma unroll
    for (int j = 0; j < 4; j++) {
      float c0, c1, c2, c3;
      fp8x4_dec(xv[j], c0, c1, c2, c3);
      a0 = fmaf(wt[j], c0, a0); a1 = fmaf(wt[j], c1, a1);
      a2 = fmaf(wt[j], c2, a2); a3 = fmaf(wt[j], c3, a3);
    }
    s += 4;
  }
  for (; s < deg; s++) {
    int i0 = csr_src[row + s];
    float w0 = w[(size_t)(row + s) * 4 + hh];
    float c0, c1, c2, c3;
    fp8x4_dec(hb[(size_t)i0 * 64], c0, c1, c2, c3);
    a0 = fmaf(w0, c0, a0); a1 = fmaf(w0, c1, a1);
    a2 = fmaf(w0, c2, a2); a3 = fmaf(w0, c3, a3);
  }
  float vinv = inv[n * 4 + hh];
  int c0i = lane * 4;
  float4 bb = *(const float4*)(b1 + c0i);
  float rx = fmaf(a0, vinv, bb.x), ry = fmaf(a1, vinv, bb.y);
  float rz = fmaf(a2, vinv, bb.z), rw = fmaf(a3, vinv, bb.w);
  rx = rx > 0.f ? rx : 0.f; ry = ry > 0.f ? ry : 0.f;
  rz = rz > 0.f ? rz : 0.f; rw = rw > 0.f ? rw : 0.f;
  *(ushort4*)(out1 + (size_t)n * 256 + c0i) =
      make_ushort4(f2bu(rx), f2bu(ry), f2bu(rz), f2bu(rw));
}

// ---- layer-2 aggregate + relu + pool partials (fp8 gather) ----
__global__ __launch_bounds__(256) void aggr2_pool_kernel(const int* __restrict__ rowptr,
    const int* __restrict__ csr_src, const float* __restrict__ w,
    const float* __restrict__ inv, const unsigned* __restrict__ h2f8,  // [N][16] words
    const float* __restrict__ b2, float4* __restrict__ partial, int Nn) {
  int lane = threadIdx.x & 63, wv = threadIdx.x >> 6;
  int q = lane >> 4, l15 = lane & 15;
  int c0 = l15 * 4;
  const unsigned* hb = h2f8 + l15;
  float p0 = 0.f, p1 = 0.f, p2 = 0.f, p3 = 0.f;
  int stream = (blockIdx.x * 4 + wv) * 4 + q;
  int nstreams = gridDim.x * 16;
  for (int n = stream; n < Nn; n += nstreams) {
    int row = rowptr[n], deg = rowptr[n + 1] - row;
    float a0 = 0.f, a1 = 0.f, a2 = 0.f, a3 = 0.f;
    int s = 0;
    for (; s + 4 <= deg; s += 4) {
      int i0 = csr_src[row + s], i1 = csr_src[row + s + 1];
      int i2 = csr_src[row + s + 2], i3 = csr_src[row + s + 3];
      float w0 = w[row + s], w1 = w[row + s + 1];
      float w2v = w[row + s + 2], w3v = w[row + s + 3];
      unsigned x0 = hb[(size_t)i0 * 16];
      unsigned x1 = hb[(size_t)i1 * 16];
      unsigned x2 = hb[(size_t)i2 * 16];
      unsigned x3 = hb[(size_t)i3 * 16];
      float c0f, c1f, c2f, c3f;
      fp8x4_dec(x0, c0f, c1f, c2f, c3f);
      a0 = fmaf(w0, c0f, a0); a1 = fmaf(w0, c1f, a1);
      a2 = fmaf(w0, c2f, a2); a3 = fmaf(w0, c3f, a3);
      fp8x4_dec(x1, c0f, c1f, c2f, c3f);
      a0 = fmaf(w1, c0f, a0); a1 = fmaf(w1, c1f, a1);
      a2 = fmaf(w1, c2f, a2); a3 = fmaf(w1, c3f, a3);
      fp8x4_dec(x2, c0f, c1f, c2f, c3f);
      a0 = fmaf(w2v, c0f, a0); a1 = fmaf(w2v, c1f, a1);
      a2 = fmaf(w2v, c2f, a2); a3 = fmaf(w2v, c3f, a3);
      fp8x4_dec(x3, c0f, c1f, c2f, c3f);
      a0 = fmaf(w3v, c0f, a0); a1 = fmaf(w3v, c1f, a1);
      a2 = fmaf(w3v, c2f, a2); a3 = fmaf(w3v, c3f, a3);
    }
    for (; s < deg; s++) {
      int i0 = csr_src[row + s];
      float w0 = w[row + s];
      float c0f, c1f, c2f, c3f;
      fp8x4_dec(hb[(size_t)i0 * 16], c0f, c1f, c2f, c3f);
      a0 = fmaf(w0, c0f, a0); a1 = fmaf(w0, c1f, a1);
      a2 = fmaf(w0, c2f, a2); a3 = fmaf(w0, c3f, a3);
    }
    float vinv = inv[n];
    float4 bb = *(const float4*)(b2 + c0);
    float r0 = fmaf(a0, vinv, bb.x), r1 = fmaf(a1, vinv, bb.y);
    float r2 = fmaf(a2, vinv, bb.z), r3 = fmaf(a3, vinv, bb.w);
    p0 += r0 > 0.f ? r0 : 0.f; p1 += r1 > 0.f ? r1 : 0.f;
    p2 += r2 > 0.f ? r2 : 0.f; p3 += r3 > 0.f ? r3 : 0.f;
  }
  __shared__ float4 sred[4][4][16];
  sred[wv][q][l15] = make_float4(p0, p1, p2, p3);
  __syncthreads();
  if (threadIdx.x < 16) {
    float4 acc = make_float4(0.f, 0.f, 0.f, 0.f);
#pragma unroll
    for (int i = 0; i < 4; i++)
#pragma unroll
      for (int j = 0; j < 4; j++) {
        float4 v = sred[i][j][threadIdx.x];
        acc.x += v.x; acc.y += v.y; acc.z += v.z; acc.w += v.w;
      }
    partial[blockIdx.x * 16 + threadIdx.x] = acc;
  }
}

// ---- reduce per-block pool partials -> pooled[64] (one block) ----
__global__ __launch_bounds__(256) void pool_reduce_kernel(const float4* __restrict__ partial,
    float4* __restrict__ pooled4, int nblocks) {
  int t = threadIdx.x;
  int slot = t & 15, p = t >> 4;
  float4 acc = make_float4(0.f, 0.f, 0.f, 0.f);
  for (int b = p; b < nblocks; b += 16) {
    float4 v = partial[b * 16 + slot];
    acc.x += v.x; acc.y += v.y; acc.z += v.z; acc.w += v.w;
  }
  __shared__ float4 s[16][16];
  s[p][slot] = acc;
  __syncthreads();
  if (t < 16) {
    float4 a = make_float4(0.f, 0.f, 0.f, 0.f);
#pragma unroll
    for (int i = 0; i < 16; i++) {
      float4 v = s[i][t];
      a.x += v.x; a.y += v.y; a.z += v.z; a.w += v.w;
    }
    pooled4[t] = a;
  }
}

// ---- final fc + log_softmax ----
__global__ void head_kernel(const float* __restrict__ pooled, const float* __restrict__ fc_w,
    const float* __restrict__ fc_b, float* __restrict__ out, float invN) {
  __shared__ float p[64];
  __shared__ float lg[40];
  __shared__ float lse;
  int t = threadIdx.x;
  p[t] = pooled[t] * invN;
  __syncthreads();
  if (t < 40) {
    float s = fc_b[t];
    for (int c = 0; c < 64; c++) s = fmaf(p[c], fc_w[c * 40 + t], s);
    lg[t] = s;
  }
  __syncthreads();
  if (t == 0) {
    float m = -1e30f;
    for (int j = 0; j < 40; j++) m = fmaxf(m, lg[j]);
    float sum = 0.f;
    for (int j = 0; j < 40; j++) sum += expf(lg[j] - m);
    lse = m + logf(sum);
  }
  __syncthreads();
  if (t < 40) out[t] = lg[t] - lse;
}

extern "C" void kernel_launch(void* const* d_in, const int* in_sizes, int n_in,
                              void* d_out, int out_size, void* d_ws, size_t ws_size,
                              hipStream_t stream) {
  const float* x        = (const float*)d_in[0];
  const int*   ei       = (const int*)d_in[1];
  const float* W1       = (const float*)d_in[2];
  const float* att_src1 = (const float*)d_in[3];
  const float* att_dst1 = (const float*)d_in[4];
  const float* b1       = (const float*)d_in[5];
  const float* W2       = (const float*)d_in[6];
  const float* att_src2 = (const float*)d_in[7];
  const float* att_dst2 = (const float*)d_in[8];
  const float* b2       = (const float*)d_in[9];
  const float* fc_w     = (const float*)d_in[10];
  const float* fc_b     = (const float*)d_in[11];
  float* out = (float*)d_out;

  const int N    = in_sizes[0] / 128;  // 50000
  const int E0   = in_sizes[1] / 2;    // 800000
  const int Etot = E0 + N;
  const int NBUCK = (N + 255) >> 8;    // 196 coarse dst-buckets
  const int NCH  = (Etot + CHUNK - 1) / CHUNK;
  const int AGG2_BLOCKS = 2048;

  char* wsb = (char*)d_ws;
  size_t o = 0;
  auto alloc = [&](size_t bytes) { char* p = wsb + o; o += (bytes + 15) & ~(size_t)15; return p; };
  unsigned short* xb   = (unsigned short*)alloc((size_t)N * 128 * 2);
  unsigned short* w1b  = (unsigned short*)alloc(128 * 256 * 2);
  unsigned short* w2b  = (unsigned short*)alloc(256 * 64 * 2);
  unsigned short* h1b  = (unsigned short*)alloc((size_t)N * 256 * 2);  // bf16; reused as h2 bf16
  unsigned char*  h1f8 = (unsigned char*)alloc((size_t)N * 256);      // fp8; reused as h2 fp8
  unsigned short* out1 = (unsigned short*)alloc((size_t)N * 256 * 2);  // bf16
  float* as1  = (float*)alloc((size_t)N * 4 * 4);
  float* ad1  = (float*)alloc((size_t)N * 4 * 4);
  float* inv1 = (float*)alloc((size_t)N * 4 * 4);
  float* w1e  = (float*)alloc((size_t)Etot * 4 * 4);
  float* as2  = (float*)alloc((size_t)N * 4);
  float* ad2  = (float*)alloc((size_t)N * 4);
  float* inv2 = (float*)alloc((size_t)N * 4);
  float* w2e  = (float*)alloc((size_t)Etot * 4);
  int* rowptr = (int*)alloc((size_t)(N + 1) * 4);
  int* bhist  = (int*)alloc(256 * 4);
  int* bucketOff = (int*)alloc(257 * 4);
  int* cursor = (int*)alloc(256 * 4);
  int2* pairs = (int2*)alloc((size_t)Etot * 8);
  int* csr_src = (int*)alloc((size_t)Etot * 4);
  float4* partial = (float4*)alloc((size_t)AGG2_BLOCKS * 16 * 16);
  float* pooled = (float*)alloc(64 * 4);

  dim3 blk(256);

  // ---- bf16 casts ----
  cast3_kernel<<<512, blk, 0, stream>>>(
      (const float4*)x, (ushort4*)xb, N * 128 / 4,
      (const float4*)W1, (ushort4*)w1b, 128 * 256 / 4,
      (const float4*)W2, (ushort4*)w2b, 256 * 64 / 4);

  // ---- CSR build (bucketed counting sort) ----
  hipMemsetAsync(bhist, 0, 256 * sizeof(int), stream);
  bucket_hist_kernel<<<256, blk, 0, stream>>>(ei, bhist, E0, Etot, NBUCK);
  bucket_scan_kernel<<<1, blk, 0, stream>>>(bhist, bucketOff, cursor, rowptr + N, NBUCK, Etot);
  bucket_scatter_kernel<<<NCH, blk, 0, stream>>>(ei, cursor, pairs, E0, Etot, NBUCK);
  csr_build_kernel<<<NBUCK, blk, 0, stream>>>(pairs, bucketOff, rowptr, csr_src, N);

  // ---- layer 1 ----
  gemm_mfma<<<dim3(4, (N + 63) / 64), blk, 0, stream>>>(xb, w1b, h1b, h1f8, N, 128, 256);
  alpha_kernel<4><<<N, blk, 0, stream>>>((const __hip_bfloat16*)h1b, att_src1, att_dst1,
                                         as1, ad1, N);
  stats1_kernel<<<(N + 3) / 4, blk, 0, stream>>>(rowptr, csr_src, (const float4*)as1,
                                                 (const float4*)ad1, (float4*)w1e,
                                                 (float4*)inv1, N);
  aggr1_kernel<<<(N + 3) / 4, blk, 0, stream>>>(rowptr, csr_src, w1e, inv1,
                                                (const unsigned*)h1f8, b1, out1, N);

  // ---- layer 2 (h2 reuses h1 buffers; stream-ordered after aggr1) ----
  gemm_mfma<<<dim3(1, (N + 63) / 64), blk, 0, stream>>>(out1, w2b, h1b, h1f8, N, 256, 64);
  alpha_kernel<1><<<(N + 3) / 4, blk, 0, stream>>>((const __hip_bfloat16*)h1b, att_src2, att_dst2,
                                                   as2, ad2, N);
  stats2_kernel<<<(N + 3) / 4, blk, 0, stream>>>(rowptr, csr_src, as2, ad2, w2e, inv2, N);
  aggr2_pool_kernel<<<AGG2_BLOCKS, blk, 0, stream>>>(rowptr, csr_src, w2e, inv2,
                                                     (const unsigned*)h1f8, b2, partial, N);
  pool_reduce_kernel<<<1, blk, 0, stream>>>(partial, (float4*)pooled, AGG2_BLOCKS);

  // ---- epilogue ----
  head_kernel<<<1, 64, 0, stream>>>(pooled, fc_w, fc_b, out, 1.0f / (float)N);
}

// Round 9
// 286.994 us; speedup vs baseline: 4.6717x; 1.2012x over previous
//
#include <hip/hip_runtime.h>
#include <hip/hip_bf16.h>
#include <math.h>

#define NEG_SLOPE 0.2f

typedef __attribute__((ext_vector_type(8))) short bf16x8;
typedef __attribute__((ext_vector_type(4))) float f32x4;
typedef __attribute__((ext_vector_type(2))) float f32x2_t;

__device__ __forceinline__ float lrelu(float a) { return a >= 0.f ? a : NEG_SLOPE * a; }
__device__ __forceinline__ unsigned short f2bu(float v) {
  unsigned u = __float_as_uint(v);
  u += 0x7fffu + ((u >> 16) & 1u);  // RNE
  return (unsigned short)(u >> 16);
}
// fp8 e4m3 (OCP on gfx950) HW conversions
__device__ __forceinline__ unsigned char f2fp8(float v) {
  return (unsigned char)(__builtin_amdgcn_cvt_pk_fp8_f32(v, v, 0, false) & 0xFF);
}
__device__ __forceinline__ void fp8x4_dec(unsigned v, float& a, float& b, float& c, float& d) {
  f32x2_t lo = __builtin_amdgcn_cvt_pk_f32_fp8(v, false);
  f32x2_t hi = __builtin_amdgcn_cvt_pk_f32_fp8(v, true);
  a = lo.x; b = lo.y; c = hi.x; d = hi.y;
}

// ---- fused bf16 cast of x, W1, W2 ----
__global__ __launch_bounds__(256) void cast3_kernel(
    const float4* __restrict__ a0, ushort4* __restrict__ d0, int n0,
    const float4* __restrict__ a1, ushort4* __restrict__ d1, int n1,
    const float4* __restrict__ a2, ushort4* __restrict__ d2, int n2) {
  int total = n0 + n1 + n2;
  for (int i = blockIdx.x * blockDim.x + threadIdx.x; i < total; i += gridDim.x * blockDim.x) {
    const float4* s;
    ushort4* d;
    int j = i;
    if (j < n0) { s = a0; d = d0; }
    else if (j < n0 + n1) { j -= n0; s = a1; d = d1; }
    else { j -= n0 + n1; s = a2; d = d2; }
    float4 v = s[j];
    d[j] = make_ushort4(f2bu(v.x), f2bu(v.y), f2bu(v.z), f2bu(v.w));
  }
}

// ---- bf16 MFMA GEMM, fp8 output only ----
__global__ __launch_bounds__(256) void gemm_mfma(const unsigned short* __restrict__ A,
    const unsigned short* __restrict__ B, unsigned char* __restrict__ C8,
    int M, int K, int Ncol) {
  __shared__ unsigned short Al[64][40];
  __shared__ unsigned short Bt[64][40];
  const int tid = threadIdx.x;
  const int row0 = blockIdx.y * 64, col0 = blockIdx.x * 64;
  const int lane = tid & 63, wave = tid >> 6;
  const int wm = wave >> 1, wn = wave & 1;
  const int l15 = lane & 15, q = lane >> 4;

  f32x4 acc[2][2] = {};

  const int am = tid >> 2, ac = (tid & 3) * 8;
  const int bk = tid >> 3, bn = (tid & 7) * 8;

  for (int k0 = 0; k0 < K; k0 += 32) {
    ushort4 av0 = make_ushort4(0, 0, 0, 0), av1 = av0;
    if (row0 + am < M) {
      const ushort4* ap = (const ushort4*)(A + (size_t)(row0 + am) * K + k0 + ac);
      av0 = ap[0]; av1 = ap[1];
    }
    *(ushort4*)&Al[am][ac] = av0;
    *(ushort4*)&Al[am][ac + 4] = av1;
    {
      const ushort4* bp = (const ushort4*)(B + (size_t)(k0 + bk) * Ncol + col0 + bn);
      ushort4 b0 = bp[0], b1 = bp[1];
      Bt[bn + 0][bk] = b0.x; Bt[bn + 1][bk] = b0.y;
      Bt[bn + 2][bk] = b0.z; Bt[bn + 3][bk] = b0.w;
      Bt[bn + 4][bk] = b1.x; Bt[bn + 5][bk] = b1.y;
      Bt[bn + 6][bk] = b1.z; Bt[bn + 7][bk] = b1.w;
    }
    __syncthreads();
    bf16x8 af[2], bf[2];
#pragma unroll
    for (int mi = 0; mi < 2; mi++)
      af[mi] = *(const bf16x8*)&Al[wm * 32 + mi * 16 + l15][q * 8];
#pragma unroll
    for (int ni = 0; ni < 2; ni++)
      bf[ni] = *(const bf16x8*)&Bt[wn * 32 + ni * 16 + l15][q * 8];
#pragma unroll
    for (int mi = 0; mi < 2; mi++)
#pragma unroll
      for (int ni = 0; ni < 2; ni++)
        acc[mi][ni] = __builtin_amdgcn_mfma_f32_16x16x32_bf16(af[mi], bf[ni], acc[mi][ni], 0, 0, 0);
    __syncthreads();
  }
#pragma unroll
  for (int mi = 0; mi < 2; mi++) {
#pragma unroll
    for (int r = 0; r < 4; r++) {
      int grow = row0 + wm * 32 + mi * 16 + q * 4 + r;
      if (grow < M) {
#pragma unroll
        for (int ni = 0; ni < 2; ni++) {
          int gcol = col0 + wn * 32 + ni * 16 + l15;
          C8[(size_t)grow * Ncol + gcol] = f2fp8(acc[mi][ni][r]);
        }
      }
    }
  }
}

// ---- CSR build via 2-level bucketed counting sort (bucket = dst>>8) ----
__global__ __launch_bounds__(256) void bucket_hist_kernel(const int* __restrict__ ei,
    int* __restrict__ bhist, int E0, int Etot, int NBUCK) {
  __shared__ int h[256];
  int t = threadIdx.x;
  h[t] = 0;
  __syncthreads();
  for (int e = blockIdx.x * 256 + t; e < Etot; e += gridDim.x * 256) {
    int dst = (e < E0) ? ei[E0 + e] : (e - E0);
    atomicAdd(&h[dst >> 8], 1);
  }
  __syncthreads();
  if (t < NBUCK && h[t]) atomicAdd(&bhist[t], h[t]);
}

__global__ __launch_bounds__(256) void bucket_scan_kernel(const int* __restrict__ bhist,
    int* __restrict__ bucketOff, int* __restrict__ cursor, int* __restrict__ rowptrN,
    int NBUCK, int Etot) {
  __shared__ int s[256];
  int t = threadIdx.x;
  int v = (t < NBUCK) ? bhist[t] : 0;
  s[t] = v;
  __syncthreads();
  for (int off = 1; off < 256; off <<= 1) {
    int u = (t >= off) ? s[t - off] : 0;
    __syncthreads();
    s[t] += u;
    __syncthreads();
  }
  int excl = s[t] - v;
  if (t < NBUCK) { bucketOff[t] = excl; cursor[t] = excl; }
  if (t == 0) { bucketOff[NBUCK] = Etot; *rowptrN = Etot; }
}

// A3: scatter packed (src<<8 | dst&255) into bucket regions (4B per edge)
#define CHUNK 4096
__global__ __launch_bounds__(256) void bucket_scatter_kernel(const int* __restrict__ ei,
    int* __restrict__ cursor, int* __restrict__ pairs, int E0, int Etot, int NBUCK) {
  __shared__ int2 stage[CHUNK];  // {packed, bucket}
  __shared__ int h[256];
  __shared__ int base[256];
  int t = threadIdx.x;
  int e0 = blockIdx.x * CHUNK;
  h[t] = 0;
  __syncthreads();
  int cnt = Etot - e0;
  if (cnt > CHUNK) cnt = CHUNK;
  for (int i = t; i < cnt; i += 256) {
    int e = e0 + i;
    int s, d;
    if (e < E0) { s = ei[e]; d = ei[E0 + e]; } else { s = d = e - E0; }
    stage[i] = make_int2((s << 8) | (d & 255), d >> 8);
    atomicAdd(&h[d >> 8], 1);
  }
  __syncthreads();
  if (t < NBUCK && h[t]) base[t] = atomicAdd(&cursor[t], h[t]);
  __syncthreads();
  for (int i = t; i < cnt; i += 256) {
    int2 p = stage[i];
    int pos = atomicAdd(&base[p.y], 1);
    pairs[pos] = p.x;
  }
}

// B: per-bucket fine CSR
__global__ __launch_bounds__(256) void csr_build_kernel(const int* __restrict__ pairs,
    const int* __restrict__ bucketOff, int* __restrict__ rowptr, int* __restrict__ csr_src,
    int N) {
  int b = blockIdx.x, t = threadIdx.x;
  int base = bucketOff[b], cnt = bucketOff[b + 1] - base;
  int n0 = b << 8;
  __shared__ int h[256];
  __shared__ int s[256];
  __shared__ int ex[256];
  h[t] = 0;
  __syncthreads();
  for (int i = t; i < cnt; i += 256) atomicAdd(&h[pairs[base + i] & 255], 1);
  __syncthreads();
  int v = h[t];
  s[t] = v;
  __syncthreads();
  for (int off = 1; off < 256; off <<= 1) {
    int u = (t >= off) ? s[t - off] : 0;
    __syncthreads();
    s[t] += u;
    __syncthreads();
  }
  ex[t] = s[t] - v;
  if (n0 + t < N) rowptr[n0 + t] = base + ex[t];
  __syncthreads();
  for (int i = t; i < cnt; i += 256) {
    int p = pairs[base + i];
    int pos = atomicAdd(&ex[p & 255], 1);
    csr_src[base + pos] = ((unsigned)p) >> 8;
  }
}

// ---- layer-1 attention coefficients from fp8 h; one wave per node ----
__global__ __launch_bounds__(256) void alpha1_kernel(const unsigned* __restrict__ h1f8,
    const float* __restrict__ att_s, const float* __restrict__ att_d,
    float* __restrict__ as_, float* __restrict__ ad_, int Nn) {
  int wave = (blockIdx.x * blockDim.x + threadIdx.x) >> 6;
  int lane = threadIdx.x & 63;
  if (wave >= Nn) return;
  int n = wave;
  float c0, c1, c2, c3;
  fp8x4_dec(h1f8[(size_t)n * 64 + lane], c0, c1, c2, c3);
  int ci = lane * 4;
  float vs = c0 * att_s[ci] + c1 * att_s[ci + 1] + c2 * att_s[ci + 2] + c3 * att_s[ci + 3];
  float vd = c0 * att_d[ci] + c1 * att_d[ci + 1] + c2 * att_d[ci + 2] + c3 * att_d[ci + 3];
#pragma unroll
  for (int off = 1; off < 16; off <<= 1) {
    vs += __shfl_xor(vs, off);
    vd += __shfl_xor(vd, off);
  }
  if ((lane & 15) == 0) {
    as_[n * 4 + (lane >> 4)] = vs;
    ad_[n * 4 + (lane >> 4)] = vd;
  }
}

// ---- layer-2 attention coefficients from fp8 h; quarter-wave per node ----
__global__ __launch_bounds__(256) void alpha2_kernel(const unsigned* __restrict__ h2f8,
    const float* __restrict__ att_s, const float* __restrict__ att_d,
    float* __restrict__ as_, float* __restrict__ ad_, int Nn) {
  int qid = (blockIdx.x * blockDim.x + threadIdx.x) >> 4;
  int l15 = threadIdx.x & 15;
  if (qid >= Nn) return;
  float c0, c1, c2, c3;
  fp8x4_dec(h2f8[(size_t)qid * 16 + l15], c0, c1, c2, c3);
  int ci = l15 * 4;
  float vs = c0 * att_s[ci] + c1 * att_s[ci + 1] + c2 * att_s[ci + 2] + c3 * att_s[ci + 3];
  float vd = c0 * att_d[ci] + c1 * att_d[ci + 1] + c2 * att_d[ci + 2] + c3 * att_d[ci + 3];
#pragma unroll
  for (int off = 1; off < 16; off <<= 1) {
    vs += __shfl_xor(vs, off);
    vd += __shfl_xor(vd, off);
  }
  if (l15 == 0) { as_[qid] = vs; ad_[qid] = vd; }
}

// ---- layer-1 aggregate, fused softmax (no max shift): one wave per node ----
__global__ __launch_bounds__(256) void aggr1_kernel(const int* __restrict__ rowptr,
    const int* __restrict__ csr_src, const float* __restrict__ as_,
    const float* __restrict__ ad_, const unsigned* __restrict__ h1f8,
    const float* __restrict__ b1, unsigned short* __restrict__ out1, int Nn) {
  int wv = threadIdx.x >> 6, lane = threadIdx.x & 63;
  int n = blockIdx.x * 4 + wv;
  if (n >= Nn) return;
  int row = rowptr[n], deg = rowptr[n + 1] - row;
  int hh = lane >> 4;
  float adv = ad_[n * 4 + hh];
  const unsigned* hb = h1f8 + lane;
  float a0 = 0.f, a1 = 0.f, a2 = 0.f, a3 = 0.f, wsum = 0.f;
  int s = 0;
  for (; s + 4 <= deg; s += 4) {
    int idx[4];
    float al[4];
    unsigned xv[4];
#pragma unroll
    for (int j = 0; j < 4; j++) idx[j] = csr_src[row + s + j];
#pragma unroll
    for (int j = 0; j < 4; j++) al[j] = as_[idx[j] * 4 + hh];
#pragma unroll
    for (int j = 0; j < 4; j++) xv[j] = hb[(size_t)idx[j] * 64];
#pragma unroll
    for (int j = 0; j < 4; j++) {
      float w = __expf(lrelu(al[j] + adv));
      wsum += w;
      float c0, c1, c2, c3;
      fp8x4_dec(xv[j], c0, c1, c2, c3);
      a0 = fmaf(w, c0, a0); a1 = fmaf(w, c1, a1);
      a2 = fmaf(w, c2, a2); a3 = fmaf(w, c3, a3);
    }
  }
  for (; s < deg; s++) {
    int i0 = csr_src[row + s];
    float w = __expf(lrelu(as_[i0 * 4 + hh] + adv));
    wsum += w;
    float c0, c1, c2, c3;
    fp8x4_dec(hb[(size_t)i0 * 64], c0, c1, c2, c3);
    a0 = fmaf(w, c0, a0); a1 = fmaf(w, c1, a1);
    a2 = fmaf(w, c2, a2); a3 = fmaf(w, c3, a3);
  }
  float vinv = 1.f / wsum;
  int c0i = lane * 4;
  float4 bb = *(const float4*)(b1 + c0i);
  float rx = fmaf(a0, vinv, bb.x), ry = fmaf(a1, vinv, bb.y);
  float rz = fmaf(a2, vinv, bb.z), rw = fmaf(a3, vinv, bb.w);
  rx = rx > 0.f ? rx : 0.f; ry = ry > 0.f ? ry : 0.f;
  rz = rz > 0.f ? rz : 0.f; rw = rw > 0.f ? rw : 0.f;
  *(ushort4*)(out1 + (size_t)n * 256 + c0i) =
      make_ushort4(f2bu(rx), f2bu(ry), f2bu(rz), f2bu(rw));
}

// ---- layer-2 aggregate + relu + pool partials, fused softmax ----
__global__ __launch_bounds__(256) void aggr2_pool_kernel(const int* __restrict__ rowptr,
    const int* __restrict__ csr_src, const float* __restrict__ as_,
    const float* __restrict__ ad_, const unsigned* __restrict__ h2f8,
    const float* __restrict__ b2, float4* __restrict__ partial, int Nn) {
  int lane = threadIdx.x & 63, wv = threadIdx.x >> 6;
  int q = lane >> 4, l15 = lane & 15;
  int c0 = l15 * 4;
  const unsigned* hb = h2f8 + l15;
  float p0 = 0.f, p1 = 0.f, p2 = 0.f, p3 = 0.f;
  int stream = (blockIdx.x * 4 + wv) * 4 + q;
  int nstreams = gridDim.x * 16;
  for (int n = stream; n < Nn; n += nstreams) {
    int row = rowptr[n], deg = rowptr[n + 1] - row;
    float adv = ad_[n];
    float a0 = 0.f, a1 = 0.f, a2 = 0.f, a3 = 0.f, wsum = 0.f;
    int s = 0;
    for (; s + 4 <= deg; s += 4) {
      int idx[4];
      float al[4];
      unsigned xv[4];
#pragma unroll
      for (int j = 0; j < 4; j++) idx[j] = csr_src[row + s + j];
#pragma unroll
      for (int j = 0; j < 4; j++) al[j] = as_[idx[j]];
#pragma unroll
      for (int j = 0; j < 4; j++) xv[j] = hb[(size_t)idx[j] * 16];
#pragma unroll
      for (int j = 0; j < 4; j++) {
        float w = __expf(lrelu(al[j] + adv));
        wsum += w;
        float c0f, c1f, c2f, c3f;
        fp8x4_dec(xv[j], c0f, c1f, c2f, c3f);
        a0 = fmaf(w, c0f, a0); a1 = fmaf(w, c1f, a1);
        a2 = fmaf(w, c2f, a2); a3 = fmaf(w, c3f, a3);
      }
    }
    for (; s < deg; s++) {
      int i0 = csr_src[row + s];
      float w = __expf(lrelu(as_[i0] + adv));
      wsum += w;
      float c0f, c1f, c2f, c3f;
      fp8x4_dec(hb[(size_t)i0 * 16], c0f, c1f, c2f, c3f);
      a0 = fmaf(w, c0f, a0); a1 = fmaf(w, c1f, a1);
      a2 = fmaf(w, c2f, a2); a3 = fmaf(w, c3f, a3);
    }
    float vinv = 1.f / wsum;
    float4 bb = *(const float4*)(b2 + c0);
    float r0 = fmaf(a0, vinv, bb.x), r1 = fmaf(a1, vinv, bb.y);
    float r2 = fmaf(a2, vinv, bb.z), r3 = fmaf(a3, vinv, bb.w);
    p0 += r0 > 0.f ? r0 : 0.f; p1 += r1 > 0.f ? r1 : 0.f;
    p2 += r2 > 0.f ? r2 : 0.f; p3 += r3 > 0.f ? r3 : 0.f;
  }
  __shared__ float4 sred[4][4][16];
  sred[wv][q][l15] = make_float4(p0, p1, p2, p3);
  __syncthreads();
  if (threadIdx.x < 16) {
    float4 acc = make_float4(0.f, 0.f, 0.f, 0.f);
#pragma unroll
    for (int i = 0; i < 4; i++)
#pragma unroll
      for (int j = 0; j < 4; j++) {
        float4 v = sred[i][j][threadIdx.x];
        acc.x += v.x; acc.y += v.y; acc.z += v.z; acc.w += v.w;
      }
    partial[blockIdx.x * 16 + threadIdx.x] = acc;
  }
}

// ---- reduce per-block pool partials -> pooled[64] (one block) ----
__global__ __launch_bounds__(256) void pool_reduce_kernel(const float4* __restrict__ partial,
    float4* __restrict__ pooled4, int nblocks) {
  int t = threadIdx.x;
  int slot = t & 15, p = t >> 4;
  float4 acc = make_float4(0.f, 0.f, 0.f, 0.f);
  for (int b = p; b < nblocks; b += 16) {
    float4 v = partial[b * 16 + slot];
    acc.x += v.x; acc.y += v.y; acc.z += v.z; acc.w += v.w;
  }
  __shared__ float4 s[16][16];
  s[p][slot] = acc;
  __syncthreads();
  if (t < 16) {
    float4 a = make_float4(0.f, 0.f, 0.f, 0.f);
#pragma unroll
    for (int i = 0; i < 16; i++) {
      float4 v = s[i][t];
      a.x += v.x; a.y += v.y; a.z += v.z; a.w += v.w;
    }
    pooled4[t] = a;
  }
}

// ---- final fc + log_softmax ----
__global__ void head_kernel(const float* __restrict__ pooled, const float* __restrict__ fc_w,
    const float* __restrict__ fc_b, float* __restrict__ out, float invN) {
  __shared__ float p[64];
  __shared__ float lg[40];
  __shared__ float lse;
  int t = threadIdx.x;
  p[t] = pooled[t] * invN;
  __syncthreads();
  if (t < 40) {
    float s = fc_b[t];
    for (int c = 0; c < 64; c++) s = fmaf(p[c], fc_w[c * 40 + t], s);
    lg[t] = s;
  }
  __syncthreads();
  if (t == 0) {
    float m = -1e30f;
    for (int j = 0; j < 40; j++) m = fmaxf(m, lg[j]);
    float sum = 0.f;
    for (int j = 0; j < 40; j++) sum += expf(lg[j] - m);
    lse = m + logf(sum);
  }
  __syncthreads();
  if (t < 40) out[t] = lg[t] - lse;
}

extern "C" void kernel_launch(void* const* d_in, const int* in_sizes, int n_in,
                              void* d_out, int out_size, void* d_ws, size_t ws_size,
                              hipStream_t stream) {
  const float* x        = (const float*)d_in[0];
  const int*   ei       = (const int*)d_in[1];
  const float* W1       = (const float*)d_in[2];
  const float* att_src1 = (const float*)d_in[3];
  const float* att_dst1 = (const float*)d_in[4];
  const float* b1       = (const float*)d_in[5];
  const float* W2       = (const float*)d_in[6];
  const float* att_src2 = (const float*)d_in[7];
  const float* att_dst2 = (const float*)d_in[8];
  const float* b2       = (const float*)d_in[9];
  const float* fc_w     = (const float*)d_in[10];
  const float* fc_b     = (const float*)d_in[11];
  float* out = (float*)d_out;

  const int N    = in_sizes[0] / 128;  // 50000
  const int E0   = in_sizes[1] / 2;    // 800000
  const int Etot = E0 + N;
  const int NBUCK = (N + 255) >> 8;
  const int NCH  = (Etot + CHUNK - 1) / CHUNK;
  const int AGG2_BLOCKS = 2048;

  char* wsb = (char*)d_ws;
  size_t o = 0;
  auto alloc = [&](size_t bytes) { char* p = wsb + o; o += (bytes + 15) & ~(size_t)15; return p; };
  unsigned short* xb   = (unsigned short*)alloc((size_t)N * 128 * 2);
  unsigned short* w1b  = (unsigned short*)alloc(128 * 256 * 2);
  unsigned short* w2b  = (unsigned short*)alloc(256 * 64 * 2);
  unsigned char*  h1f8 = (unsigned char*)alloc((size_t)N * 256);      // fp8; reused as h2 fp8
  unsigned short* out1 = (unsigned short*)alloc((size_t)N * 256 * 2);  // bf16
  float* as1  = (float*)alloc((size_t)N * 4 * 4);
  float* ad1  = (float*)alloc((size_t)N * 4 * 4);
  float* as2  = (float*)alloc((size_t)N * 4);
  float* ad2  = (float*)alloc((size_t)N * 4);
  int* rowptr = (int*)alloc((size_t)(N + 1) * 4);
  int* bhist  = (int*)alloc(256 * 4);
  int* bucketOff = (int*)alloc(257 * 4);
  int* cursor = (int*)alloc(256 * 4);
  int* pairs  = (int*)alloc((size_t)Etot * 4);
  int* csr_src = (int*)alloc((size_t)Etot * 4);
  float4* partial = (float4*)alloc((size_t)AGG2_BLOCKS * 16 * 16);
  float* pooled = (float*)alloc(64 * 4);

  dim3 blk(256);

  // ---- bf16 casts ----
  cast3_kernel<<<512, blk, 0, stream>>>(
      (const float4*)x, (ushort4*)xb, N * 128 / 4,
      (const float4*)W1, (ushort4*)w1b, 128 * 256 / 4,
      (const float4*)W2, (ushort4*)w2b, 256 * 64 / 4);

  // ---- CSR build (bucketed counting sort, packed pairs) ----
  hipMemsetAsync(bhist, 0, 256 * sizeof(int), stream);
  bucket_hist_kernel<<<256, blk, 0, stream>>>(ei, bhist, E0, Etot, NBUCK);
  bucket_scan_kernel<<<1, blk, 0, stream>>>(bhist, bucketOff, cursor, rowptr + N, NBUCK, Etot);
  bucket_scatter_kernel<<<NCH, blk, 0, stream>>>(ei, cursor, pairs, E0, Etot, NBUCK);
  csr_build_kernel<<<NBUCK, blk, 0, stream>>>(pairs, bucketOff, rowptr, csr_src, N);

  // ---- layer 1 ----
  gemm_mfma<<<dim3(4, (N + 63) / 64), blk, 0, stream>>>(xb, w1b, h1f8, N, 128, 256);
  alpha1_kernel<<<(N + 3) / 4, blk, 0, stream>>>((const unsigned*)h1f8, att_src1, att_dst1,
                                                 as1, ad1, N);
  aggr1_kernel<<<(N + 3) / 4, blk, 0, stream>>>(rowptr, csr_src, as1, ad1,
                                                (const unsigned*)h1f8, b1, out1, N);

  // ---- layer 2 (h2 reuses h1f8; stream-ordered after aggr1) ----
  gemm_mfma<<<dim3(1, (N + 63) / 64), blk, 0, stream>>>(out1, w2b, h1f8, N, 256, 64);
  alpha2_kernel<<<(N + 15) / 16, blk, 0, stream>>>((const unsigned*)h1f8, att_src2, att_dst2,
                                                   as2, ad2, N);
  aggr2_pool_kernel<<<AGG2_BLOCKS, blk, 0, stream>>>(rowptr, csr_src, as2, ad2,
                                                     (const unsigned*)h1f8, b2, partial, N);
  pool_reduce_kernel<<<1, blk, 0, stream>>>(partial, (float4*)pooled, AGG2_BLOCKS);

  // ---- epilogue ----
  head_kernel<<<1, 64, 0, stream>>>(pooled, fc_w, fc_b, out, 1.0f / (float)N);
}